// Round 1
// baseline (5374.500 us; speedup 1.0000x reference)
//
#include <hip/hip_runtime.h>
#include <math.h>

// Problem sizes
// B=16, L=1024, DIN=64, H=256, N=64, TEMB=128, NB=6; chunk T=64, C=16

__device__ __forceinline__ void ld4(const float* p, float* d) {
  float4 v = *reinterpret_cast<const float4*>(p);
  d[0] = v.x; d[1] = v.y; d[2] = v.z; d[3] = v.w;
}

// ---------------- t-embedding MLP:  tv[b,h] ----------------
__global__ __launch_bounds__(256) void k_temb(
    const float* __restrict__ t, const float* __restrict__ Wt1, const float* __restrict__ bt1,
    const float* __restrict__ Wt2, const float* __restrict__ bt2, float* __restrict__ tv) {
  int b = blockIdx.x, tid = threadIdx.x;
  __shared__ float emb[128];
  __shared__ float tv1[256];
  if (tid < 128) {
    int j = tid & 63;
    float f = expf(-logf(10000.f) / 63.f * (float)j);
    float a = t[b] * f;
    emb[tid] = (tid < 64) ? sinf(a) : cosf(a);
  }
  __syncthreads();
  float acc = bt1[tid];
  for (int k = 0; k < 128; k++) acc = fmaf(emb[k], Wt1[k * 256 + tid], acc);
  tv1[tid] = acc / (1.f + expf(-acc));
  __syncthreads();
  float acc2 = bt2[tid];
  for (int k = 0; k < 256; k++) acc2 = fmaf(tv1[k], Wt2[k * 256 + tid], acc2);
  tv[b * 256 + tid] = acc2 / (1.f + expf(-acc2));
}

// ---------------- tt_all[i,b,h] = tv[b]@tW[i] + tb[i] ----------------
__global__ __launch_bounds__(256) void k_tt(
    const float* __restrict__ tv, const float* __restrict__ tW, const float* __restrict__ tb,
    float* __restrict__ tt_all) {
  int i = blockIdx.x, b = blockIdx.y, h = threadIdx.x;
  __shared__ float s[256];
  s[h] = tv[b * 256 + h];
  __syncthreads();
  const float* W = tW + i * 256 * 256;
  float acc = tb[i * 256 + h];
  for (int k = 0; k < 256; k++) acc = fmaf(s[k], W[k * 256 + h], acc);
  tt_all[(i * 16 + b) * 256 + h] = acc;
}

// ---------------- input proj: x[b,h,l] = relu(input@W_in + b_in), transposed ----------------
__global__ __launch_bounds__(256) void k_in(
    const float* __restrict__ inp, const float* __restrict__ W, const float* __restrict__ bias,
    float* __restrict__ x) {
  int lt = blockIdx.x, b = blockIdx.y, h = threadIdx.x;
  __shared__ float si[64][68];
  int l0 = lt * 64;
  for (int rep = 0; rep < 16; rep++) {
    int idx = rep * 256 + h;
    int l = idx >> 6, d = idx & 63;
    si[l][d] = inp[(size_t)(b * 1024 + l0 + l) * 64 + d];
  }
  float wc[64];
  #pragma unroll
  for (int d = 0; d < 64; d++) wc[d] = W[d * 256 + h];
  float bh = bias[h];
  __syncthreads();
  float* xp = x + (size_t)(b * 256 + h) * 1024 + l0;
  for (int l4 = 0; l4 < 16; l4++) {
    float4 o;
    float* op = &o.x;
    #pragma unroll
    for (int j = 0; j < 4; j++) {
      int l = l4 * 4 + j;
      float a = bh;
      #pragma unroll
      for (int d4 = 0; d4 < 16; d4++) {
        float4 v = *reinterpret_cast<const float4*>(&si[l][d4 * 4]);
        a = fmaf(v.x, wc[d4 * 4 + 0], a);
        a = fmaf(v.y, wc[d4 * 4 + 1], a);
        a = fmaf(v.z, wc[d4 * 4 + 2], a);
        a = fmaf(v.w, wc[d4 * 4 + 3], a);
      }
      op[j] = fmaxf(a, 0.f);
    }
    *reinterpret_cast<float4*>(xp + l4 * 4) = o;
  }
}

// ---------------- per-mode tables: w, w^64, dC (all blocks) ----------------
__global__ __launch_bounds__(256) void k_tab(
    const float* __restrict__ log_dt, const float* __restrict__ A_log_re, const float* __restrict__ A_im,
    const float* __restrict__ C_re, const float* __restrict__ C_im,
    float* __restrict__ wtab, float* __restrict__ wTtab, float* __restrict__ dCtab) {
  int idx = blockIdx.x * 256 + threadIdx.x;  // over NB*H*N = 98304
  int i = idx / (256 * 64);
  int rem = idx % (256 * 64);
  int h = rem >> 6, n = rem & 63;
  float dt = expf(log_dt[i * 256 + h]);
  float Ar = -expf(A_log_re[idx]);
  float Ai = A_im[idx];
  float ar = dt * Ar, ai = dt * Ai;
  float ea = expf(ar);
  float wr = ea * cosf(ai), wi = ea * sinf(ai);
  float pr = wr, pi = wi;
  #pragma unroll
  for (int s = 0; s < 6; s++) { float nr = pr * pr - pi * pi; float ni = 2.f * pr * pi; pr = nr; pi = ni; }
  float den = Ar * Ar + Ai * Ai;
  float qr = ((wr - 1.f) * Ar + wi * Ai) / den;
  float qi = (wi * Ar - (wr - 1.f) * Ai) / den;
  wtab[idx * 2] = wr; wtab[idx * 2 + 1] = wi;
  wTtab[idx * 2] = pr; wTtab[idx * 2 + 1] = pi;
  #pragma unroll
  for (int s = 0; s < 2; s++) {
    float cr = C_re[((size_t)(i * 2 + s) * 256 + h) * 64 + n];
    float ci = C_im[((size_t)(i * 2 + s) * 256 + h) * 64 + n];
    dCtab[(((size_t)(i * 2 + s) * 256 + h) * 64 + n) * 2]     = cr * qr - ci * qi;
    dCtab[(((size_t)(i * 2 + s) * 256 + h) * 64 + n) * 2 + 1] = cr * qi + ci * qr;
  }
}

// ---------------- Pcar[h][nr][t] = {Re, -Im}(w^t),  t=0..63 (per net-block i) ----------------
__global__ __launch_bounds__(256) void k_pcar(const float* __restrict__ wtab, float* __restrict__ Pcar, int i) {
  int idx = blockIdx.x * 256 + threadIdx.x;  // h*64+n
  int h = idx >> 6, n = idx & 63;
  int gi = (i * 256 + h) * 64 + n;
  float wr = wtab[gi * 2], wi = wtab[gi * 2 + 1];
  float pr = 1.f, pi = 0.f;
  float* rowR = Pcar + (size_t)(h * 128 + 2 * n) * 64;
  float* rowI = Pcar + (size_t)(h * 128 + 2 * n + 1) * 64;
  for (int t4 = 0; t4 < 16; t4++) {
    float rr[4], ii[4];
    #pragma unroll
    for (int j = 0; j < 4; j++) {
      rr[j] = pr; ii[j] = -pi;
      float nr2 = pr * wr - pi * wi, ni2 = pr * wi + pi * wr;
      pr = nr2; pi = ni2;
    }
    *reinterpret_cast<float4*>(rowR + t4 * 4) = make_float4(rr[0], rr[1], rr[2], rr[3]);
    *reinterpret_cast<float4*>(rowI + t4 * 4) = make_float4(ii[0], ii[1], ii[2], ii[3]);
  }
}

// ---------------- Ktap[s][h][j] = 2 Re(sum_n dC_s w^j) ----------------
__global__ __launch_bounds__(256) void k_ktap(
    const float* __restrict__ dCtab, const float* __restrict__ Pcar, float* __restrict__ Ktap, int i) {
  int idx = blockIdx.x * 256 + threadIdx.x;  // (s*256+h)*64+j, 32768
  int j = idx & 63;
  int sh = idx >> 6;
  int h = sh & 255, s = sh >> 8;
  const float* dc = dCtab + ((size_t)(i * 2 + s) * 256 + h) * 128;
  const float* P = Pcar + (size_t)h * 128 * 64;
  float acc = 0.f;
  for (int n = 0; n < 64; n++) {
    acc = fmaf(dc[2 * n],     P[(2 * n) * 64 + j],     acc);
    acc = fmaf(dc[2 * n + 1], P[(2 * n + 1) * 64 + j], acc);
  }
  Ktap[idx] = 2.f * acc;
}

// ---------------- LayerNorm over H with +tt, x[B,H,L] -> zn[B,H,L] ----------------
__global__ __launch_bounds__(256) void k_ln(
    const float* __restrict__ x, const float* __restrict__ tt_all,
    const float* __restrict__ g, const float* __restrict__ bta, float* __restrict__ zn, int i) {
  int ct = blockIdx.x, b = blockIdx.y, tid = threadIdx.x;
  __shared__ float tile[64][257];
  __shared__ float stt[256];
  __shared__ float red[8][64];
  __shared__ float mu_s[64], rs_s[64];
  stt[tid] = tt_all[(i * 16 + b) * 256 + tid];
  __syncthreads();
  int l0 = ct * 64;
  const float* xb = x + (size_t)(b * 256) * 1024 + l0;
  for (int rep = 0; rep < 16; rep++) {
    int idx = rep * 256 + tid;
    int h = idx >> 4;
    int l4 = (idx & 15) * 4;
    float4 v = *reinterpret_cast<const float4*>(xb + (size_t)h * 1024 + l4);
    float a = stt[h];
    tile[l4][h] = v.x + a; tile[l4 + 1][h] = v.y + a; tile[l4 + 2][h] = v.z + a; tile[l4 + 3][h] = v.w + a;
  }
  __syncthreads();
  int l = tid & 63, part = tid >> 6;
  float s1 = 0.f, s2 = 0.f;
  for (int k = 0; k < 64; k++) {
    float v = tile[l][part * 64 + k];
    s1 += v; s2 = fmaf(v, v, s2);
  }
  red[part][l] = s1; red[4 + part][l] = s2;
  __syncthreads();
  if (tid < 64) {
    float a = red[0][tid] + red[1][tid] + red[2][tid] + red[3][tid];
    float q = red[4][tid] + red[5][tid] + red[6][tid] + red[7][tid];
    float mu = a * (1.f / 256.f);
    float var = q * (1.f / 256.f) - mu * mu;
    mu_s[tid] = mu;
    rs_s[tid] = rsqrtf(var + 1e-5f);
  }
  __syncthreads();
  float* zb = zn + (size_t)(b * 256) * 1024 + l0;
  for (int rep = 0; rep < 16; rep++) {
    int idx = rep * 256 + tid;
    int h = idx >> 4;
    int l4 = (idx & 15) * 4;
    float gg = g[i * 256 + h], bb2 = bta[i * 256 + h];
    float4 o;
    o.x = (tile[l4][h]     - mu_s[l4])     * rs_s[l4]     * gg + bb2;
    o.y = (tile[l4 + 1][h] - mu_s[l4 + 1]) * rs_s[l4 + 1] * gg + bb2;
    o.z = (tile[l4 + 2][h] - mu_s[l4 + 2]) * rs_s[l4 + 2] * gg + bb2;
    o.w = (tile[l4 + 3][h] - mu_s[l4 + 3]) * rs_s[l4 + 3] * gg + bb2;
    *reinterpret_cast<float4*>(zb + (size_t)h * 1024 + l4) = o;
  }
}

// ---------------- Horner per-chunk B_loc: Bl[dir][(b,h)][c][2n{+1}] ----------------
__global__ __launch_bounds__(128) void k_bloc(
    const float* __restrict__ zn, const float* __restrict__ wtab, float* __restrict__ Bl, int i) {
  int bh = blockIdx.x;  // b*256+h
  int h = bh & 255;
  int tid = threadIdx.x;
  int n = tid & 63, dir = tid >> 6;
  __shared__ float srow[1024];
  const float* zr = zn + (size_t)bh * 1024;
  for (int r = 0; r < 2; r++) {
    int idx = (r * 128 + tid) * 4;
    *reinterpret_cast<float4*>(srow + idx) = *reinterpret_cast<const float4*>(zr + idx);
  }
  int gi = (i * 256 + h) * 64 + n;
  float wr = wtab[gi * 2], wi = wtab[gi * 2 + 1];
  __syncthreads();
  const float4* s4p = reinterpret_cast<const float4*>(srow);
  float* base = Bl + ((size_t)dir * 4096 + bh) * 2048 + 2 * n;
  for (int c = 0; c < 16; c++) {
    float br = 0.f, bi = 0.f;
    if (dir == 0) {
      for (int tg = 0; tg < 16; tg++) {
        float4 v = s4p[c * 16 + tg];
        float t0;
        t0 = fmaf(br, wr, fmaf(-bi, wi, v.x)); bi = fmaf(br, wi, bi * wr); br = t0;
        t0 = fmaf(br, wr, fmaf(-bi, wi, v.y)); bi = fmaf(br, wi, bi * wr); br = t0;
        t0 = fmaf(br, wr, fmaf(-bi, wi, v.z)); bi = fmaf(br, wi, bi * wr); br = t0;
        t0 = fmaf(br, wr, fmaf(-bi, wi, v.w)); bi = fmaf(br, wi, bi * wr); br = t0;
      }
    } else {
      for (int tg = 15; tg >= 0; tg--) {
        float4 v = s4p[c * 16 + tg];
        float t0;
        t0 = fmaf(br, wr, fmaf(-bi, wi, v.w)); bi = fmaf(br, wi, bi * wr); br = t0;
        t0 = fmaf(br, wr, fmaf(-bi, wi, v.z)); bi = fmaf(br, wi, bi * wr); br = t0;
        t0 = fmaf(br, wr, fmaf(-bi, wi, v.y)); bi = fmaf(br, wi, bi * wr); br = t0;
        t0 = fmaf(br, wr, fmaf(-bi, wi, v.x)); bi = fmaf(br, wi, bi * wr); br = t0;
      }
    }
    *reinterpret_cast<float2*>(base + c * 128) = make_float2(br, bi);
  }
}

// ---------------- chunk scan; in-place replace B_loc with S' (carry coefficient) ----------------
__global__ __launch_bounds__(256) void k_scan(
    float* __restrict__ Bl, const float* __restrict__ wtab, const float* __restrict__ wTtab,
    const float* __restrict__ dCtab, int i) {
  int gid = blockIdx.x * 256 + threadIdx.x;  // 2*16*256*64
  int dir = gid >> 18;
  int r = gid & 262143;
  int b = r >> 14;
  int r2 = r & 16383;
  int h = r2 >> 6, n = r2 & 63;
  int gi = (i * 256 + h) * 64 + n;
  float wTr = wTtab[gi * 2], wTi = wTtab[gi * 2 + 1];
  float dcr = dCtab[((size_t)(i * 2 + dir) * 256 + h) * 128 + 2 * n];
  float dci = dCtab[((size_t)(i * 2 + dir) * 256 + h) * 128 + 2 * n + 1];
  float mr, mi;
  if (dir == 0) {  // fold w: S'_f = 2*dC0*w*S_enter
    float wr = wtab[gi * 2], wi = wtab[gi * 2 + 1];
    mr = 2.f * (dcr * wr - dci * wi); mi = 2.f * (dcr * wi + dci * wr);
  } else {
    mr = 2.f * dcr; mi = 2.f * dci;
  }
  size_t base = ((size_t)dir * 4096 + b * 256 + h) * 2048 + 2 * n;
  float sr = 0.f, si = 0.f;
  if (dir == 0) {
    for (int c = 0; c < 16; c++) {
      float2* p = reinterpret_cast<float2*>(Bl + base + c * 128);
      float2 v = *p;
      *p = make_float2(mr * sr - mi * si, mr * si + mi * sr);
      float nr2 = fmaf(wTr, sr, fmaf(-wTi, si, v.x));
      float ni2 = fmaf(wTr, si, fmaf(wTi, sr, v.y));
      sr = nr2; si = ni2;
    }
  } else {
    for (int c = 15; c >= 0; c--) {
      float2* p = reinterpret_cast<float2*>(Bl + base + c * 128);
      float2 v = *p;
      *p = make_float2(mr * sr - mi * si, mr * si + mi * sr);
      float nr2 = fmaf(wTr, sr, fmaf(-wTi, si, v.x));
      float ni2 = fmaf(wTr, si, fmaf(wTi, sr, v.y));
      sr = nr2; si = ni2;
    }
  }
}

// ---------------- apply: y = carry + local-Toeplitz + zn*Dp, gelu -> yg ----------------
__global__ __launch_bounds__(256, 1) void k_apply(
    const float* __restrict__ zn, const float* __restrict__ Bl, const float* __restrict__ Pcar,
    const float* __restrict__ Ktap, const float* __restrict__ Dp, float* __restrict__ yg, int i) {
  int h = blockIdx.x;
  int b0 = blockIdx.y * 4;
  int tid = threadIdx.x;
  __shared__ float S[64][324];  // [row=(bb,c)][0:128 S'f | 128:256 S'b | 256:320 zn]
  __shared__ float P[256][68];  // [0:128 Pcar | 128:192 Toe0 | 192:256 Toe1]
  for (int dir = 0; dir < 2; dir++) {
    const float* src = Bl + (size_t)dir * 4096 * 2048;
    for (int rep = 0; rep < 8; rep++) {
      int idx = rep * 256 + tid;  // 2048
      int row = idx >> 5;
      int k4 = (idx & 31) * 4;
      int bb = row >> 4, c = row & 15;
      float4 v = *reinterpret_cast<const float4*>(src + ((size_t)((b0 + bb) * 256 + h)) * 2048 + c * 128 + k4);
      *reinterpret_cast<float4*>(&S[row][dir * 128 + k4]) = v;
    }
  }
  for (int rep = 0; rep < 4; rep++) {
    int idx = rep * 256 + tid;  // 1024
    int row = idx >> 4;
    int t4 = (idx & 15) * 4;
    int bb = row >> 4, c = row & 15;
    float4 v = *reinterpret_cast<const float4*>(zn + ((size_t)((b0 + bb) * 256 + h)) * 1024 + c * 64 + t4);
    *reinterpret_cast<float4*>(&S[row][256 + t4]) = v;
  }
  for (int rep = 0; rep < 8; rep++) {
    int idx = rep * 256 + tid;  // 2048
    int nr = idx >> 4;
    int t4 = (idx & 15) * 4;
    float4 v = *reinterpret_cast<const float4*>(Pcar + ((size_t)(h * 128 + nr)) * 64 + t4);
    *reinterpret_cast<float4*>(&P[nr][t4]) = v;
  }
  for (int rep = 0; rep < 16; rep++) {
    int idx = rep * 256 + tid;  // 4096
    int tp = idx >> 6, t = idx & 63;
    P[128 + tp][t] = (t >= tp) ? Ktap[(0 * 256 + h) * 64 + (t - tp)] : 0.f;
    P[192 + tp][t] = (tp > t) ? Ktap[(1 * 256 + h) * 64 + (tp - t - 1)] : 0.f;
  }
  __syncthreads();

  int rg = tid >> 4, tc = tid & 15;
  float acc[4][4];
  #pragma unroll
  for (int r = 0; r < 4; r++)
    #pragma unroll
    for (int j = 0; j < 4; j++) acc[r][j] = 0.f;

  // fwd carry: S'f (cols 0:128) x Pcar rows
  for (int k4 = 0; k4 < 32; k4++) {
    float sf[4][4], pf[4][4];
    #pragma unroll
    for (int r = 0; r < 4; r++) ld4(&S[rg * 4 + r][k4 * 4], sf[r]);
    #pragma unroll
    for (int kk = 0; kk < 4; kk++) ld4(&P[k4 * 4 + kk][tc * 4], pf[kk]);
    #pragma unroll
    for (int r = 0; r < 4; r++)
      #pragma unroll
      for (int kk = 0; kk < 4; kk++)
        #pragma unroll
        for (int j = 0; j < 4; j++) acc[r][j] = fmaf(sf[r][kk], pf[kk][j], acc[r][j]);
  }
  // bwd carry: S'b (cols 128:256) x Pcar rows with reversed t
  for (int k4 = 0; k4 < 32; k4++) {
    float sf[4][4], pf[4][4];
    #pragma unroll
    for (int r = 0; r < 4; r++) ld4(&S[rg * 4 + r][128 + k4 * 4], sf[r]);
    #pragma unroll
    for (int kk = 0; kk < 4; kk++) ld4(&P[k4 * 4 + kk][60 - tc * 4], pf[kk]);
    #pragma unroll
    for (int r = 0; r < 4; r++)
      #pragma unroll
      for (int kk = 0; kk < 4; kk++)
        #pragma unroll
        for (int j = 0; j < 4; j++) acc[r][j] = fmaf(sf[r][kk], pf[kk][3 - j], acc[r][j]);
  }
  // fwd local: zn (cols 256:320) x Toe0 rows
  for (int k4 = 0; k4 < 16; k4++) {
    float sf[4][4], pf[4][4];
    #pragma unroll
    for (int r = 0; r < 4; r++) ld4(&S[rg * 4 + r][256 + k4 * 4], sf[r]);
    #pragma unroll
    for (int kk = 0; kk < 4; kk++) ld4(&P[128 + k4 * 4 + kk][tc * 4], pf[kk]);
    #pragma unroll
    for (int r = 0; r < 4; r++)
      #pragma unroll
      for (int kk = 0; kk < 4; kk++)
        #pragma unroll
        for (int j = 0; j < 4; j++) acc[r][j] = fmaf(sf[r][kk], pf[kk][j], acc[r][j]);
  }
  // bwd local: zn x Toe1 rows
  for (int k4 = 0; k4 < 16; k4++) {
    float sf[4][4], pf[4][4];
    #pragma unroll
    for (int r = 0; r < 4; r++) ld4(&S[rg * 4 + r][256 + k4 * 4], sf[r]);
    #pragma unroll
    for (int kk = 0; kk < 4; kk++) ld4(&P[192 + k4 * 4 + kk][tc * 4], pf[kk]);
    #pragma unroll
    for (int r = 0; r < 4; r++)
      #pragma unroll
      for (int kk = 0; kk < 4; kk++)
        #pragma unroll
        for (int j = 0; j < 4; j++) acc[r][j] = fmaf(sf[r][kk], pf[kk][j], acc[r][j]);
  }

  float dp = Dp[i * 256 + h];
  #pragma unroll
  for (int r = 0; r < 4; r++) {
    int row = rg * 4 + r;
    int bb = row >> 4, c = row & 15;
    float4 o;
    float* op = &o.x;
    #pragma unroll
    for (int j = 0; j < 4; j++) {
      float z = S[row][256 + tc * 4 + j];
      float v = fmaf(z, dp, acc[r][j]);
      op[j] = 0.5f * v * (1.f + erff(v * 0.70710678118f));
    }
    *reinterpret_cast<float4*>(yg + ((size_t)((b0 + bb) * 256 + h)) * 1024 + c * 64 + tc * 4) = o;
  }
}

// ---------------- generic H x H GEMM over [B,H,L] with fused epilogues ----------------
// out[b,o,l] = EPI( sum_k W[o,k]*act[b,k,l] + bias[o] )
// EPI 0: g = tanh(u)*sigmoid(u), u = acc+bias + x + tt   (aux1=x, aux2=tt row base)
// EPI 1: out = acc+bias + aux1 (x residual, in-place)
// EPI 2: out = acc+bias + aux1 (skips accumulate, in-place)
// EPI 3: out = relu(acc+bias)
template <int EPI, bool WT>
__global__ __launch_bounds__(256) void k_mm(
    const float* __restrict__ W, const float* __restrict__ bias, const float* __restrict__ act,
    float* __restrict__ out, const float* __restrict__ aux1, const float* __restrict__ aux2) {
  int lt = blockIdx.x, ot = blockIdx.y, b = blockIdx.z;
  int tid = threadIdx.x;
  __shared__ float sw[32][65];
  __shared__ float sb[32][132];
  int l0 = lt * 128, o0 = ot * 64;
  float acc[4][8];
  #pragma unroll
  for (int r = 0; r < 4; r++)
    #pragma unroll
    for (int c2 = 0; c2 < 8; c2++) acc[r][c2] = 0.f;
  const float* actb = act + (size_t)(b * 256) * 1024;
  int of = (tid >> 4) * 4;
  int lf = (tid & 15) * 4;
  for (int kc = 0; kc < 256; kc += 32) {
    if (!WT) {
      for (int rep = 0; rep < 8; rep++) {
        int idx = rep * 256 + tid;  // 2048
        int oo = idx >> 5, kk = idx & 31;
        sw[kk][oo] = W[(size_t)(o0 + oo) * 256 + kc + kk];
      }
    } else {
      for (int rep = 0; rep < 8; rep++) {
        int idx = rep * 256 + tid;
        int kk2 = idx >> 6, oo = idx & 63;
        sw[kk2][oo] = W[(size_t)(kc + kk2) * 256 + o0 + oo];
      }
    }
    for (int rep = 0; rep < 4; rep++) {
      int idx = rep * 256 + tid;  // 1024 quads
      int kk = idx >> 5;
      int l4 = (idx & 31) * 4;
      float4 v = *reinterpret_cast<const float4*>(actb + (size_t)(kc + kk) * 1024 + l0 + l4);
      *reinterpret_cast<float4*>(&sb[kk][l4]) = v;
    }
    __syncthreads();
    for (int kk = 0; kk < 32; kk++) {
      float wf[4], bf[8];
      #pragma unroll
      for (int j = 0; j < 4; j++) wf[j] = sw[kk][of + j];
      float4 v1 = *reinterpret_cast<const float4*>(&sb[kk][lf]);
      float4 v2 = *reinterpret_cast<const float4*>(&sb[kk][64 + lf]);
      bf[0] = v1.x; bf[1] = v1.y; bf[2] = v1.z; bf[3] = v1.w;
      bf[4] = v2.x; bf[5] = v2.y; bf[6] = v2.z; bf[7] = v2.w;
      #pragma unroll
      for (int r = 0; r < 4; r++)
        #pragma unroll
        for (int c2 = 0; c2 < 8; c2++) acc[r][c2] = fmaf(wf[r], bf[c2], acc[r][c2]);
    }
    __syncthreads();
  }
  #pragma unroll
  for (int r = 0; r < 4; r++) {
    int o = o0 + of + r;
    float bs = bias[o];
    #pragma unroll
    for (int half = 0; half < 2; half++) {
      size_t idx = (size_t)(b * 256 + o) * 1024 + l0 + half * 64 + lf;
      float4 ov;
      float* op = &ov.x;
      #pragma unroll
      for (int j = 0; j < 4; j++) {
        float a = acc[r][half * 4 + j] + bs;
        if constexpr (EPI == 0) {
          float u = a + aux1[idx + j] + aux2[b * 256 + o];
          op[j] = tanhf(u) * (1.f / (1.f + expf(-u)));
        } else if constexpr (EPI == 1 || EPI == 2) {
          op[j] = a + aux1[idx + j];
        } else {
          op[j] = fmaxf(a, 0.f);
        }
      }
      *reinterpret_cast<float4*>(out + idx) = ov;
    }
  }
}

// ---------------- final: out[b,l,d] = h1[b,:,l]@Wo2 + bo2 + input ----------------
__global__ __launch_bounds__(256) void k_out(
    const float* __restrict__ h1, const float* __restrict__ Wo2, const float* __restrict__ bo2,
    const float* __restrict__ inp, float* __restrict__ outp) {
  int lt = blockIdx.x, b = blockIdx.y, tid = threadIdx.x;
  __shared__ float sa[32][132];
  __shared__ float sw2[32][68];
  int l0 = lt * 128;
  float acc[4][8];
  #pragma unroll
  for (int r = 0; r < 4; r++)
    #pragma unroll
    for (int c2 = 0; c2 < 8; c2++) acc[r][c2] = 0.f;
  int df = (tid & 7) * 8;
  int lf = (tid >> 3) * 4;
  for (int kc = 0; kc < 256; kc += 32) {
    for (int rep = 0; rep < 4; rep++) {
      int idx = rep * 256 + tid;
      int kk = idx >> 5;
      int l4 = (idx & 31) * 4;
      float4 v = *reinterpret_cast<const float4*>(h1 + (size_t)(b * 256 + kc + kk) * 1024 + l0 + l4);
      *reinterpret_cast<float4*>(&sa[kk][l4]) = v;
    }
    for (int rep = 0; rep < 8; rep++) {
      int idx = rep * 256 + tid;
      int kk = idx >> 6, d = idx & 63;
      sw2[kk][d] = Wo2[(size_t)(kc + kk) * 64 + d];
    }
    __syncthreads();
    for (int kk = 0; kk < 32; kk++) {
      float4 av = *reinterpret_cast<const float4*>(&sa[kk][lf]);
      float4 w1 = *reinterpret_cast<const float4*>(&sw2[kk][df]);
      float4 w2 = *reinterpret_cast<const float4*>(&sw2[kk][df + 4]);
      float avv[4] = {av.x, av.y, av.z, av.w};
      float wv[8] = {w1.x, w1.y, w1.z, w1.w, w2.x, w2.y, w2.z, w2.w};
      #pragma unroll
      for (int r = 0; r < 4; r++)
        #pragma unroll
        for (int c2 = 0; c2 < 8; c2++) acc[r][c2] = fmaf(avv[r], wv[c2], acc[r][c2]);
    }
    __syncthreads();
  }
  float bv[8];
  #pragma unroll
  for (int c2 = 0; c2 < 8; c2++) bv[c2] = bo2[df + c2];
  #pragma unroll
  for (int r = 0; r < 4; r++) {
    size_t base = (size_t)(b * 1024 + l0 + lf + r) * 64 + df;
    float4 i1 = *reinterpret_cast<const float4*>(inp + base);
    float4 i2 = *reinterpret_cast<const float4*>(inp + base + 4);
    float4 o1 = make_float4(acc[r][0] + bv[0] + i1.x, acc[r][1] + bv[1] + i1.y,
                            acc[r][2] + bv[2] + i1.z, acc[r][3] + bv[3] + i1.w);
    float4 o2 = make_float4(acc[r][4] + bv[4] + i2.x, acc[r][5] + bv[5] + i2.y,
                            acc[r][6] + bv[6] + i2.z, acc[r][7] + bv[7] + i2.w);
    *reinterpret_cast<float4*>(outp + base) = o1;
    *reinterpret_cast<float4*>(outp + base + 4) = o2;
  }
}

extern "C" void kernel_launch(void* const* d_in, const int* in_sizes, int n_in,
                              void* d_out, int out_size, void* d_ws, size_t ws_size,
                              hipStream_t stream) {
  const float* input   = (const float*)d_in[0];
  const float* t       = (const float*)d_in[1];
  const float* W_in    = (const float*)d_in[2];
  const float* b_in    = (const float*)d_in[3];
  const float* Wt1     = (const float*)d_in[4];
  const float* bt1     = (const float*)d_in[5];
  const float* Wt2     = (const float*)d_in[6];
  const float* bt2     = (const float*)d_in[7];
  const float* ln_g    = (const float*)d_in[8];
  const float* ln_b    = (const float*)d_in[9];
  const float* log_dt  = (const float*)d_in[10];
  const float* A_log_re= (const float*)d_in[11];
  const float* A_im    = (const float*)d_in[12];
  const float* C_re    = (const float*)d_in[13];
  const float* C_im    = (const float*)d_in[14];
  const float* Dp      = (const float*)d_in[15];
  const float* s4W     = (const float*)d_in[16];
  const float* s4b     = (const float*)d_in[17];
  const float* tW      = (const float*)d_in[18];
  const float* tb      = (const float*)d_in[19];
  const float* c1W     = (const float*)d_in[20];
  const float* c1b     = (const float*)d_in[21];
  const float* c2W     = (const float*)d_in[22];
  const float* c2b     = (const float*)d_in[23];
  const float* Wo1     = (const float*)d_in[24];
  const float* bo1     = (const float*)d_in[25];
  const float* Wo2     = (const float*)d_in[26];
  const float* bo2     = (const float*)d_in[27];

  float* ws = (float*)d_ws;
  size_t off = 0;
  float* x      = ws + off; off += 4194304;   // [B,H,L]
  float* zn     = ws + off; off += 4194304;   // [B,H,L]  (reused as g after apply)
  float* yg     = ws + off; off += 4194304;   // [B,H,L]  (reused as h1 at the end)
  float* skips  = ws + off; off += 4194304;   // [B,H,L]
  float* tv     = ws + off; off += 4096;
  float* tt_all = ws + off; off += 24576;
  float* wtab   = ws + off; off += 196608;
  float* wTtab  = ws + off; off += 196608;
  float* dCtab  = ws + off; off += 393216;
  float* Pcar   = ws + off; off += 2097152;   // [H][128][64]
  float* Ktap   = ws + off; off += 32768;     // [2][H][64]
  float* Bl     = ws + off; off += 16777216;  // [2][B*H][16][128]

  hipMemsetAsync(skips, 0, 4194304 * sizeof(float), stream);
  k_temb<<<16, 256, 0, stream>>>(t, Wt1, bt1, Wt2, bt2, tv);
  k_tt<<<dim3(6, 16), 256, 0, stream>>>(tv, tW, tb, tt_all);
  k_in<<<dim3(16, 16), 256, 0, stream>>>(input, W_in, b_in, x);
  k_tab<<<384, 256, 0, stream>>>(log_dt, A_log_re, A_im, C_re, C_im, wtab, wTtab, dCtab);

  for (int i = 0; i < 6; i++) {
    k_ln<<<dim3(16, 16), 256, 0, stream>>>(x, tt_all, ln_g, ln_b, zn, i);
    k_pcar<<<64, 256, 0, stream>>>(wtab, Pcar, i);
    k_ktap<<<128, 256, 0, stream>>>(dCtab, Pcar, Ktap, i);
    k_bloc<<<4096, 128, 0, stream>>>(zn, wtab, Bl, i);
    k_scan<<<2048, 256, 0, stream>>>(Bl, wtab, wTtab, dCtab, i);
    k_apply<<<dim3(256, 4), 256, 0, stream>>>(zn, Bl, Pcar, Ktap, Dp, yg, i);
    // s4 matmul + residual(z) + gate -> g (stored in zn buffer; zn no longer needed)
    k_mm<0, false><<<dim3(8, 4, 16), 256, 0, stream>>>(s4W + (size_t)i * 65536, s4b + i * 256, yg, zn,
                                                       x, tt_all + i * 4096);
    // x = c1W@g + c1b + x (in place)
    k_mm<1, false><<<dim3(8, 4, 16), 256, 0, stream>>>(c1W + (size_t)i * 65536, c1b + i * 256, zn, x,
                                                       x, nullptr);
    // skips += c2W@g + c2b (in place)
    k_mm<2, false><<<dim3(8, 4, 16), 256, 0, stream>>>(c2W + (size_t)i * 65536, c2b + i * 256, zn, skips,
                                                       skips, nullptr);
  }
  // h1 = relu(Wo1^T-contract over h of skips) in [B,H,L]
  k_mm<3, true><<<dim3(8, 4, 16), 256, 0, stream>>>(Wo1, bo1, skips, yg, nullptr, nullptr);
  k_out<<<dim3(8, 16), 256, 0, stream>>>(yg, Wo2, bo2, input, (float*)d_out);
}

// Round 3
// 1799.296 us; speedup vs baseline: 2.9870x; 2.9870x over previous
//
#include <hip/hip_runtime.h>
#include <math.h>

// Problem sizes
// B=16, L=1024, DIN=64, H=256, N=64, TEMB=128, NB=6; chunk T=64, C=16

typedef __attribute__((ext_vector_type(8))) short bf16x8;
typedef __attribute__((ext_vector_type(4))) float f32x4;

__device__ __forceinline__ short f2bf(float f) {
  unsigned u = __builtin_bit_cast(unsigned, f);
  unsigned r = (u + 0x7FFFu + ((u >> 16) & 1u)) >> 16;
  return (short)r;
}

// ---------------- t-embedding MLP:  tv[b,h] ----------------
__global__ __launch_bounds__(256) void k_temb(
    const float* __restrict__ t, const float* __restrict__ Wt1, const float* __restrict__ bt1,
    const float* __restrict__ Wt2, const float* __restrict__ bt2, float* __restrict__ tv) {
  int b = blockIdx.x, tid = threadIdx.x;
  __shared__ float emb[128];
  __shared__ float tv1[256];
  if (tid < 128) {
    int j = tid & 63;
    float f = expf(-logf(10000.f) / 63.f * (float)j);
    float a = t[b] * f;
    emb[tid] = (tid < 64) ? sinf(a) : cosf(a);
  }
  __syncthreads();
  float acc = bt1[tid];
  for (int k = 0; k < 128; k++) acc = fmaf(emb[k], Wt1[k * 256 + tid], acc);
  tv1[tid] = acc / (1.f + expf(-acc));
  __syncthreads();
  float acc2 = bt2[tid];
  for (int k = 0; k < 256; k++) acc2 = fmaf(tv1[k], Wt2[k * 256 + tid], acc2);
  tv[b * 256 + tid] = acc2 / (1.f + expf(-acc2));
}

// ---------------- tt_all[i,b,h] = tv[b]@tW[i] + tb[i] ----------------
__global__ __launch_bounds__(256) void k_tt(
    const float* __restrict__ tv, const float* __restrict__ tW, const float* __restrict__ tb,
    float* __restrict__ tt_all) {
  int i = blockIdx.x, b = blockIdx.y, h = threadIdx.x;
  __shared__ float s[256];
  s[h] = tv[b * 256 + h];
  __syncthreads();
  const float* W = tW + i * 256 * 256;
  float acc = tb[i * 256 + h];
  for (int k = 0; k < 256; k++) acc = fmaf(s[k], W[k * 256 + h], acc);
  tt_all[(i * 16 + b) * 256 + h] = acc;
}

// ---------------- input proj: x[b,h,l] = relu(input@W_in + b_in), transposed ----------------
__global__ __launch_bounds__(256) void k_in(
    const float* __restrict__ inp, const float* __restrict__ W, const float* __restrict__ bias,
    float* __restrict__ x) {
  int lt = blockIdx.x, b = blockIdx.y, h = threadIdx.x;
  __shared__ float si[64][68];
  int l0 = lt * 64;
  for (int rep = 0; rep < 16; rep++) {
    int idx = rep * 256 + h;
    int l = idx >> 6, d = idx & 63;
    si[l][d] = inp[(size_t)(b * 1024 + l0 + l) * 64 + d];
  }
  float wc[64];
  #pragma unroll
  for (int d = 0; d < 64; d++) wc[d] = W[d * 256 + h];
  float bh = bias[h];
  __syncthreads();
  float* xp = x + (size_t)(b * 256 + h) * 1024 + l0;
  for (int l4 = 0; l4 < 16; l4++) {
    float4 o;
    float* op = &o.x;
    #pragma unroll
    for (int j = 0; j < 4; j++) {
      int l = l4 * 4 + j;
      float a = bh;
      #pragma unroll
      for (int d4 = 0; d4 < 16; d4++) {
        float4 v = *reinterpret_cast<const float4*>(&si[l][d4 * 4]);
        a = fmaf(v.x, wc[d4 * 4 + 0], a);
        a = fmaf(v.y, wc[d4 * 4 + 1], a);
        a = fmaf(v.z, wc[d4 * 4 + 2], a);
        a = fmaf(v.w, wc[d4 * 4 + 3], a);
      }
      op[j] = fmaxf(a, 0.f);
    }
    *reinterpret_cast<float4*>(xp + l4 * 4) = o;
  }
}

// ---------------- per-mode tables: w, w^64, dC (all blocks) ----------------
__global__ __launch_bounds__(256) void k_tab(
    const float* __restrict__ log_dt, const float* __restrict__ A_log_re, const float* __restrict__ A_im,
    const float* __restrict__ C_re, const float* __restrict__ C_im,
    float* __restrict__ wtab, float* __restrict__ wTtab, float* __restrict__ dCtab) {
  int idx = blockIdx.x * 256 + threadIdx.x;  // over NB*H*N = 98304
  int i = idx / (256 * 64);
  int rem = idx % (256 * 64);
  int h = rem >> 6, n = rem & 63;
  float dt = expf(log_dt[i * 256 + h]);
  float Ar = -expf(A_log_re[idx]);
  float Ai = A_im[idx];
  float ar = dt * Ar, ai = dt * Ai;
  float ea = expf(ar);
  float wr = ea * cosf(ai), wi = ea * sinf(ai);
  float pr = wr, pi = wi;
  #pragma unroll
  for (int s = 0; s < 6; s++) { float nr = pr * pr - pi * pi; float ni = 2.f * pr * pi; pr = nr; pi = ni; }
  float den = Ar * Ar + Ai * Ai;
  float qr = ((wr - 1.f) * Ar + wi * Ai) / den;
  float qi = (wi * Ar - (wr - 1.f) * Ai) / den;
  wtab[idx * 2] = wr; wtab[idx * 2 + 1] = wi;
  wTtab[idx * 2] = pr; wTtab[idx * 2 + 1] = pi;
  #pragma unroll
  for (int s = 0; s < 2; s++) {
    float cr = C_re[((size_t)(i * 2 + s) * 256 + h) * 64 + n];
    float ci = C_im[((size_t)(i * 2 + s) * 256 + h) * 64 + n];
    dCtab[(((size_t)(i * 2 + s) * 256 + h) * 64 + n) * 2]     = cr * qr - ci * qi;
    dCtab[(((size_t)(i * 2 + s) * 256 + h) * 64 + n) * 2 + 1] = cr * qi + ci * qr;
  }
}

// ---------------- Pt[h][t][2n{+1}] = {Re, -Im}(w^t),  t=0..63 (per net-block i) ----------------
__global__ __launch_bounds__(256) void k_pcar(const float* __restrict__ wtab, float* __restrict__ Pt, int i) {
  int idx = blockIdx.x * 256 + threadIdx.x;  // h*64+n
  int h = idx >> 6, n = idx & 63;
  int gi = (i * 256 + h) * 64 + n;
  float wr = wtab[gi * 2], wi = wtab[gi * 2 + 1];
  float pr = 1.f, pi = 0.f;
  float* base = Pt + (size_t)h * 8192 + 2 * n;
  for (int t = 0; t < 64; t++) {
    *reinterpret_cast<float2*>(base + t * 128) = make_float2(pr, -pi);
    float nr2 = pr * wr - pi * wi, ni2 = pr * wi + pi * wr;
    pr = nr2; pi = ni2;
  }
}

// ---------------- Ktap[s][h][j] = 2 Re(sum_n dC_s w^j) ----------------
__global__ __launch_bounds__(256) void k_ktap(
    const float* __restrict__ dCtab, const float* __restrict__ Pt, float* __restrict__ Ktap, int i) {
  int idx = blockIdx.x * 256 + threadIdx.x;  // (s*256+h)*64+j, 32768
  int j = idx & 63;
  int sh = idx >> 6;
  int h = sh & 255, s = sh >> 8;
  const float* dc = dCtab + ((size_t)(i * 2 + s) * 256 + h) * 128;
  const float* P = Pt + (size_t)h * 8192 + j * 128;
  float acc = 0.f;
  for (int q = 0; q < 32; q++) {
    float4 d = *reinterpret_cast<const float4*>(dc + q * 4);
    float4 p = *reinterpret_cast<const float4*>(P + q * 4);
    acc = fmaf(d.x, p.x, fmaf(d.y, p.y, fmaf(d.z, p.z, fmaf(d.w, p.w, acc))));
  }
  Ktap[idx] = 2.f * acc;
}

// ---------------- LayerNorm over H with +tt, x[B,H,L] -> zn[B,H,L] ----------------
__global__ __launch_bounds__(256) void k_ln(
    const float* __restrict__ x, const float* __restrict__ tt_all,
    const float* __restrict__ g, const float* __restrict__ bta, float* __restrict__ zn, int i) {
  int ct = blockIdx.x, b = blockIdx.y, tid = threadIdx.x;
  __shared__ float tile[64][257];
  __shared__ float stt[256];
  __shared__ float red[8][64];
  __shared__ float mu_s[64], rs_s[64];
  stt[tid] = tt_all[(i * 16 + b) * 256 + tid];
  __syncthreads();
  int l0 = ct * 64;
  const float* xb = x + (size_t)(b * 256) * 1024 + l0;
  for (int rep = 0; rep < 16; rep++) {
    int idx = rep * 256 + tid;
    int h = idx >> 4;
    int l4 = (idx & 15) * 4;
    float4 v = *reinterpret_cast<const float4*>(xb + (size_t)h * 1024 + l4);
    float a = stt[h];
    tile[l4][h] = v.x + a; tile[l4 + 1][h] = v.y + a; tile[l4 + 2][h] = v.z + a; tile[l4 + 3][h] = v.w + a;
  }
  __syncthreads();
  int l = tid & 63, part = tid >> 6;
  float s1 = 0.f, s2 = 0.f;
  for (int k = 0; k < 64; k++) {
    float v = tile[l][part * 64 + k];
    s1 += v; s2 = fmaf(v, v, s2);
  }
  red[part][l] = s1; red[4 + part][l] = s2;
  __syncthreads();
  if (tid < 64) {
    float a = red[0][tid] + red[1][tid] + red[2][tid] + red[3][tid];
    float q = red[4][tid] + red[5][tid] + red[6][tid] + red[7][tid];
    float mu = a * (1.f / 256.f);
    float var = q * (1.f / 256.f) - mu * mu;
    mu_s[tid] = mu;
    rs_s[tid] = rsqrtf(var + 1e-5f);
  }
  __syncthreads();
  float* zb = zn + (size_t)(b * 256) * 1024 + l0;
  for (int rep = 0; rep < 16; rep++) {
    int idx = rep * 256 + tid;
    int h = idx >> 4;
    int l4 = (idx & 15) * 4;
    float gg = g[i * 256 + h], bb2 = bta[i * 256 + h];
    float4 o;
    o.x = (tile[l4][h]     - mu_s[l4])     * rs_s[l4]     * gg + bb2;
    o.y = (tile[l4 + 1][h] - mu_s[l4 + 1]) * rs_s[l4 + 1] * gg + bb2;
    o.z = (tile[l4 + 2][h] - mu_s[l4 + 2]) * rs_s[l4 + 2] * gg + bb2;
    o.w = (tile[l4 + 3][h] - mu_s[l4 + 3]) * rs_s[l4 + 3] * gg + bb2;
    *reinterpret_cast<float4*>(zb + (size_t)h * 1024 + l4) = o;
  }
}

// ---------------- Horner per-chunk B_loc: Bl[dir][(b,h)][c][2n{+1}] ----------------
__global__ __launch_bounds__(128) void k_bloc(
    const float* __restrict__ zn, const float* __restrict__ wtab, float* __restrict__ Bl, int i) {
  int bh = blockIdx.x;  // b*256+h
  int h = bh & 255;
  int tid = threadIdx.x;
  int n = tid & 63, dir = tid >> 6;
  __shared__ float srow[1024];
  const float* zr = zn + (size_t)bh * 1024;
  for (int r = 0; r < 2; r++) {
    int idx = (r * 128 + tid) * 4;
    *reinterpret_cast<float4*>(srow + idx) = *reinterpret_cast<const float4*>(zr + idx);
  }
  int gi = (i * 256 + h) * 64 + n;
  float wr = wtab[gi * 2], wi = wtab[gi * 2 + 1];
  __syncthreads();
  const float4* s4p = reinterpret_cast<const float4*>(srow);
  float* base = Bl + ((size_t)dir * 4096 + bh) * 2048 + 2 * n;
  for (int c = 0; c < 16; c++) {
    float br = 0.f, bi = 0.f;
    if (dir == 0) {
      for (int tg = 0; tg < 16; tg++) {
        float4 v = s4p[c * 16 + tg];
        float t0;
        t0 = fmaf(br, wr, fmaf(-bi, wi, v.x)); bi = fmaf(br, wi, bi * wr); br = t0;
        t0 = fmaf(br, wr, fmaf(-bi, wi, v.y)); bi = fmaf(br, wi, bi * wr); br = t0;
        t0 = fmaf(br, wr, fmaf(-bi, wi, v.z)); bi = fmaf(br, wi, bi * wr); br = t0;
        t0 = fmaf(br, wr, fmaf(-bi, wi, v.w)); bi = fmaf(br, wi, bi * wr); br = t0;
      }
    } else {
      for (int tg = 15; tg >= 0; tg--) {
        float4 v = s4p[c * 16 + tg];
        float t0;
        t0 = fmaf(br, wr, fmaf(-bi, wi, v.w)); bi = fmaf(br, wi, bi * wr); br = t0;
        t0 = fmaf(br, wr, fmaf(-bi, wi, v.z)); bi = fmaf(br, wi, bi * wr); br = t0;
        t0 = fmaf(br, wr, fmaf(-bi, wi, v.y)); bi = fmaf(br, wi, bi * wr); br = t0;
        t0 = fmaf(br, wr, fmaf(-bi, wi, v.x)); bi = fmaf(br, wi, bi * wr); br = t0;
      }
    }
    *reinterpret_cast<float2*>(base + c * 128) = make_float2(br, bi);
  }
}

// ---------------- chunk scan; in-place replace B_loc with S' (carry coefficient) ----------------
__global__ __launch_bounds__(256) void k_scan(
    float* __restrict__ Bl, const float* __restrict__ wtab, const float* __restrict__ wTtab,
    const float* __restrict__ dCtab, int i) {
  int gid = blockIdx.x * 256 + threadIdx.x;  // 2*16*256*64
  int dir = gid >> 18;
  int r = gid & 262143;
  int b = r >> 14;
  int r2 = r & 16383;
  int h = r2 >> 6, n = r2 & 63;
  int gi = (i * 256 + h) * 64 + n;
  float wTr = wTtab[gi * 2], wTi = wTtab[gi * 2 + 1];
  float dcr = dCtab[((size_t)(i * 2 + dir) * 256 + h) * 128 + 2 * n];
  float dci = dCtab[((size_t)(i * 2 + dir) * 256 + h) * 128 + 2 * n + 1];
  float mr, mi;
  if (dir == 0) {  // fold w: S'_f = 2*dC0*w*S_enter
    float wr = wtab[gi * 2], wi = wtab[gi * 2 + 1];
    mr = 2.f * (dcr * wr - dci * wi); mi = 2.f * (dcr * wi + dci * wr);
  } else {
    mr = 2.f * dcr; mi = 2.f * dci;
  }
  size_t base = ((size_t)dir * 4096 + b * 256 + h) * 2048 + 2 * n;
  float sr = 0.f, si = 0.f;
  if (dir == 0) {
    for (int c = 0; c < 16; c++) {
      float2* p = reinterpret_cast<float2*>(Bl + base + c * 128);
      float2 v = *p;
      *p = make_float2(mr * sr - mi * si, mr * si + mi * sr);
      float nr2 = fmaf(wTr, sr, fmaf(-wTi, si, v.x));
      float ni2 = fmaf(wTr, si, fmaf(wTi, sr, v.y));
      sr = nr2; si = ni2;
    }
  } else {
    for (int c = 15; c >= 0; c--) {
      float2* p = reinterpret_cast<float2*>(Bl + base + c * 128);
      float2 v = *p;
      *p = make_float2(mr * sr - mi * si, mr * si + mi * sr);
      float nr2 = fmaf(wTr, sr, fmaf(-wTi, si, v.x));
      float ni2 = fmaf(wTr, si, fmaf(wTi, sr, v.y));
      sr = nr2; si = ni2;
    }
  }
}

// ---------------- apply (MFMA): y = carry + local-Toeplitz + zn*Dp, gelu -> yg ----------------
// Per h: C[rows=(b,c)][t] = A[rows][K=320] x B[320][64], A = [S'f | S'b | zn_chunk],
// B = [Pf | Pb(rev t) | Toe01]. bf16 inputs, fp32 accumulate.
__global__ __launch_bounds__(512) void k_apply(
    const float* __restrict__ zn, const float* __restrict__ Bl, const float* __restrict__ Pt,
    const float* __restrict__ Ktap, const float* __restrict__ Dp, float* __restrict__ yg, int i) {
  int h = blockIdx.x;
  int tid = threadIdx.x;
  __shared__ short Blds[64][344];  // [t][k], bf16, padded (688B rows: 16B aligned, 2-way banks)
  __shared__ float k0s[64], k1s[64];
  if (tid < 64) k0s[tid] = Ktap[(0 * 256 + h) * 64 + tid];
  else if (tid < 128) k1s[tid - 64] = Ktap[(1 * 256 + h) * 64 + (tid - 64)];
  __syncthreads();
  // Build B in LDS: Blds[t][k] = B[k][t]
  {
    int trow = tid >> 6, klane = tid & 63;
    const float* Pth = Pt + (size_t)h * 8192;
    #pragma unroll
    for (int ti = 0; ti < 8; ti++) {
      int t = ti * 8 + trow;
      #pragma unroll
      for (int kc = 0; kc < 5; kc++) {
        int k = kc * 64 + klane;
        float v;
        if (kc < 2)      v = Pth[t * 128 + k];                 // fwd carry basis
        else if (kc < 4) v = Pth[(63 - t) * 128 + (k - 128)];  // bwd carry basis (reversed t)
        else {
          int tp = klane;                                      // combined Toeplitz
          v = (t >= tp) ? k0s[t - tp] : k1s[tp - t - 1];
        }
        Blds[t][k] = f2bf(v);
      }
    }
  }
  __syncthreads();

  int wid = tid >> 6, lane = tid & 63;
  int b = blockIdx.y * 8 + wid;          // one batch per wave
  int c = lane & 15, kq = lane >> 4;     // A row / k-octet; c also = B/C column index
  const float* pa0 = Bl + ((size_t)(b * 256 + h)) * 2048 + c * 128 + kq * 8;
  const float* pa1 = pa0 + (size_t)4096 * 2048;
  const float* pzn = zn + ((size_t)(b * 256 + h)) * 1024 + c * 64 + kq * 8;

  f32x4 acc[4];
  #pragma unroll
  for (int nt = 0; nt < 4; nt++) acc[nt] = (f32x4){0.f, 0.f, 0.f, 0.f};

  #pragma unroll
  for (int ks = 0; ks < 10; ks++) {
    const float* src = (ks < 4) ? (pa0 + ks * 32) : (ks < 8) ? (pa1 + (ks - 4) * 32) : (pzn + (ks - 8) * 32);
    float4 lo = *reinterpret_cast<const float4*>(src);
    float4 hi = *reinterpret_cast<const float4*>(src + 4);
    bf16x8 af;
    af[0] = f2bf(lo.x); af[1] = f2bf(lo.y); af[2] = f2bf(lo.z); af[3] = f2bf(lo.w);
    af[4] = f2bf(hi.x); af[5] = f2bf(hi.y); af[6] = f2bf(hi.z); af[7] = f2bf(hi.w);
    #pragma unroll
    for (int nt = 0; nt < 4; nt++) {
      bf16x8 bfv = *reinterpret_cast<const bf16x8*>(&Blds[nt * 16 + c][ks * 32 + kq * 8]);
      acc[nt] = __builtin_amdgcn_mfma_f32_16x16x32_bf16(af, bfv, acc[nt], 0, 0, 0);
    }
  }

  float dp = Dp[i * 256 + h];
  size_t obase = (size_t)(b * 256 + h) * 1024;
  #pragma unroll
  for (int nt = 0; nt < 4; nt++) {
    #pragma unroll
    for (int r = 0; r < 4; r++) {
      int m = kq * 4 + r;                 // chunk index (C/D row)
      int t = nt * 16 + c;                // within-chunk time (C/D col)
      size_t idx = obase + (size_t)m * 64 + t;
      float z = zn[idx];
      float v = fmaf(z, dp, acc[nt][r]);
      yg[idx] = 0.5f * v * (1.f + erff(v * 0.70710678118f));
    }
  }
}

// ---------------- generic H x H GEMM over [B,H,L] with fused epilogues ----------------
// out[b,o,l] = EPI( sum_k W[o,k]*act[b,k,l] + bias[o] )
// EPI 0: g = tanh(u)*sigmoid(u), u = acc+bias + x + tt   (aux1=x, aux2=tt row base)
// EPI 1: out = acc+bias + aux1 (x residual, in-place)
// EPI 2: out = acc+bias + aux1 (skips accumulate, in-place)
// EPI 3: out = relu(acc+bias)
template <int EPI, bool WT>
__global__ __launch_bounds__(256) void k_mm(
    const float* __restrict__ W, const float* __restrict__ bias, const float* __restrict__ act,
    float* __restrict__ out, const float* __restrict__ aux1, const float* __restrict__ aux2) {
  int lt = blockIdx.x, ot = blockIdx.y, b = blockIdx.z;
  int tid = threadIdx.x;
  __shared__ float sw[32][65];
  __shared__ float sb[32][132];
  int l0 = lt * 128, o0 = ot * 64;
  float acc[4][8];
  #pragma unroll
  for (int r = 0; r < 4; r++)
    #pragma unroll
    for (int c2 = 0; c2 < 8; c2++) acc[r][c2] = 0.f;
  const float* actb = act + (size_t)(b * 256) * 1024;
  int of = (tid >> 4) * 4;
  int lf = (tid & 15) * 4;
  for (int kc = 0; kc < 256; kc += 32) {
    if (!WT) {
      for (int rep = 0; rep < 8; rep++) {
        int idx = rep * 256 + tid;  // 2048
        int oo = idx >> 5, kk = idx & 31;
        sw[kk][oo] = W[(size_t)(o0 + oo) * 256 + kc + kk];
      }
    } else {
      for (int rep = 0; rep < 8; rep++) {
        int idx = rep * 256 + tid;
        int kk2 = idx >> 6, oo = idx & 63;
        sw[kk2][oo] = W[(size_t)(kc + kk2) * 256 + o0 + oo];
      }
    }
    for (int rep = 0; rep < 4; rep++) {
      int idx = rep * 256 + tid;  // 1024 quads
      int kk = idx >> 5;
      int l4 = (idx & 31) * 4;
      float4 v = *reinterpret_cast<const float4*>(actb + (size_t)(kc + kk) * 1024 + l0 + l4);
      *reinterpret_cast<float4*>(&sb[kk][l4]) = v;
    }
    __syncthreads();
    for (int kk = 0; kk < 32; kk++) {
      float wf[4], bf[8];
      #pragma unroll
      for (int j = 0; j < 4; j++) wf[j] = sw[kk][of + j];
      float4 v1 = *reinterpret_cast<const float4*>(&sb[kk][lf]);
      float4 v2 = *reinterpret_cast<const float4*>(&sb[kk][64 + lf]);
      bf[0] = v1.x; bf[1] = v1.y; bf[2] = v1.z; bf[3] = v1.w;
      bf[4] = v2.x; bf[5] = v2.y; bf[6] = v2.z; bf[7] = v2.w;
      #pragma unroll
      for (int r = 0; r < 4; r++)
        #pragma unroll
        for (int c2 = 0; c2 < 8; c2++) acc[r][c2] = fmaf(wf[r], bf[c2], acc[r][c2]);
    }
    __syncthreads();
  }
  #pragma unroll
  for (int r = 0; r < 4; r++) {
    int o = o0 + of + r;
    float bs = bias[o];
    #pragma unroll
    for (int half = 0; half < 2; half++) {
      size_t idx = (size_t)(b * 256 + o) * 1024 + l0 + half * 64 + lf;
      float4 ov;
      float* op = &ov.x;
      #pragma unroll
      for (int j = 0; j < 4; j++) {
        float a = acc[r][half * 4 + j] + bs;
        if constexpr (EPI == 0) {
          float u = a + aux1[idx + j] + aux2[b * 256 + o];
          op[j] = tanhf(u) * (1.f / (1.f + expf(-u)));
        } else if constexpr (EPI == 1 || EPI == 2) {
          op[j] = a + aux1[idx + j];
        } else {
          op[j] = fmaxf(a, 0.f);
        }
      }
      *reinterpret_cast<float4*>(out + idx) = ov;
    }
  }
}

// ---------------- final: out[b,l,d] = h1[b,:,l]@Wo2 + bo2 + input ----------------
__global__ __launch_bounds__(256) void k_out(
    const float* __restrict__ h1, const float* __restrict__ Wo2, const float* __restrict__ bo2,
    const float* __restrict__ inp, float* __restrict__ outp) {
  int lt = blockIdx.x, b = blockIdx.y, tid = threadIdx.x;
  __shared__ float sa[32][132];
  __shared__ float sw2[32][68];
  int l0 = lt * 128;
  float acc[4][8];
  #pragma unroll
  for (int r = 0; r < 4; r++)
    #pragma unroll
    for (int c2 = 0; c2 < 8; c2++) acc[r][c2] = 0.f;
  int df = (tid & 7) * 8;
  int lf = (tid >> 3) * 4;
  for (int kc = 0; kc < 256; kc += 32) {
    for (int rep = 0; rep < 4; rep++) {
      int idx = rep * 256 + tid;
      int kk = idx >> 5;
      int l4 = (idx & 31) * 4;
      float4 v = *reinterpret_cast<const float4*>(h1 + (size_t)(b * 256 + kc + kk) * 1024 + l0 + l4);
      *reinterpret_cast<float4*>(&sa[kk][l4]) = v;
    }
    for (int rep = 0; rep < 8; rep++) {
      int idx = rep * 256 + tid;
      int kk = idx >> 6, d = idx & 63;
      sw2[kk][d] = Wo2[(size_t)(kc + kk) * 64 + d];
    }
    __syncthreads();
    for (int kk = 0; kk < 32; kk++) {
      float4 av = *reinterpret_cast<const float4*>(&sa[kk][lf]);
      float4 w1 = *reinterpret_cast<const float4*>(&sw2[kk][df]);
      float4 w2 = *reinterpret_cast<const float4*>(&sw2[kk][df + 4]);
      float avv[4] = {av.x, av.y, av.z, av.w};
      float wv[8] = {w1.x, w1.y, w1.z, w1.w, w2.x, w2.y, w2.z, w2.w};
      #pragma unroll
      for (int r = 0; r < 4; r++)
        #pragma unroll
        for (int c2 = 0; c2 < 8; c2++) acc[r][c2] = fmaf(avv[r], wv[c2], acc[r][c2]);
    }
    __syncthreads();
  }
  float bv[8];
  #pragma unroll
  for (int c2 = 0; c2 < 8; c2++) bv[c2] = bo2[df + c2];
  #pragma unroll
  for (int r = 0; r < 4; r++) {
    size_t base = (size_t)(b * 1024 + l0 + lf + r) * 64 + df;
    float4 i1 = *reinterpret_cast<const float4*>(inp + base);
    float4 i2 = *reinterpret_cast<const float4*>(inp + base + 4);
    float4 o1 = make_float4(acc[r][0] + bv[0] + i1.x, acc[r][1] + bv[1] + i1.y,
                            acc[r][2] + bv[2] + i1.z, acc[r][3] + bv[3] + i1.w);
    float4 o2 = make_float4(acc[r][4] + bv[4] + i2.x, acc[r][5] + bv[5] + i2.y,
                            acc[r][6] + bv[6] + i2.z, acc[r][7] + bv[7] + i2.w);
    *reinterpret_cast<float4*>(outp + base) = o1;
    *reinterpret_cast<float4*>(outp + base + 4) = o2;
  }
}

extern "C" void kernel_launch(void* const* d_in, const int* in_sizes, int n_in,
                              void* d_out, int out_size, void* d_ws, size_t ws_size,
                              hipStream_t stream) {
  const float* input   = (const float*)d_in[0];
  const float* t       = (const float*)d_in[1];
  const float* W_in    = (const float*)d_in[2];
  const float* b_in    = (const float*)d_in[3];
  const float* Wt1     = (const float*)d_in[4];
  const float* bt1     = (const float*)d_in[5];
  const float* Wt2     = (const float*)d_in[6];
  const float* bt2     = (const float*)d_in[7];
  const float* ln_g    = (const float*)d_in[8];
  const float* ln_b    = (const float*)d_in[9];
  const float* log_dt  = (const float*)d_in[10];
  const float* A_log_re= (const float*)d_in[11];
  const float* A_im    = (const float*)d_in[12];
  const float* C_re    = (const float*)d_in[13];
  const float* C_im    = (const float*)d_in[14];
  const float* Dp      = (const float*)d_in[15];
  const float* s4W     = (const float*)d_in[16];
  const float* s4b     = (const float*)d_in[17];
  const float* tW      = (const float*)d_in[18];
  const float* tb      = (const float*)d_in[19];
  const float* c1W     = (const float*)d_in[20];
  const float* c1b     = (const float*)d_in[21];
  const float* c2W     = (const float*)d_in[22];
  const float* c2b     = (const float*)d_in[23];
  const float* Wo1     = (const float*)d_in[24];
  const float* bo1     = (const float*)d_in[25];
  const float* Wo2     = (const float*)d_in[26];
  const float* bo2     = (const float*)d_in[27];

  float* ws = (float*)d_ws;
  size_t off = 0;
  float* x      = ws + off; off += 4194304;   // [B,H,L]
  float* zn     = ws + off; off += 4194304;   // [B,H,L]  (reused as g after apply)
  float* yg     = ws + off; off += 4194304;   // [B,H,L]  (reused as h1 at the end)
  float* skips  = ws + off; off += 4194304;   // [B,H,L]
  float* tv     = ws + off; off += 4096;
  float* tt_all = ws + off; off += 24576;
  float* wtab   = ws + off; off += 196608;
  float* wTtab  = ws + off; off += 196608;
  float* dCtab  = ws + off; off += 393216;
  float* Pt     = ws + off; off += 2097152;   // [H][64 t][128]  (transposed Pcar)
  float* Ktap   = ws + off; off += 32768;     // [2][H][64]
  float* Bl     = ws + off; off += 16777216;  // [2][B*H][16][128]

  hipMemsetAsync(skips, 0, 4194304 * sizeof(float), stream);
  k_temb<<<16, 256, 0, stream>>>(t, Wt1, bt1, Wt2, bt2, tv);
  k_tt<<<dim3(6, 16), 256, 0, stream>>>(tv, tW, tb, tt_all);
  k_in<<<dim3(16, 16), 256, 0, stream>>>(input, W_in, b_in, x);
  k_tab<<<384, 256, 0, stream>>>(log_dt, A_log_re, A_im, C_re, C_im, wtab, wTtab, dCtab);

  for (int i = 0; i < 6; i++) {
    k_ln<<<dim3(16, 16), 256, 0, stream>>>(x, tt_all, ln_g, ln_b, zn, i);
    k_pcar<<<64, 256, 0, stream>>>(wtab, Pt, i);
    k_ktap<<<128, 256, 0, stream>>>(dCtab, Pt, Ktap, i);
    k_bloc<<<4096, 128, 0, stream>>>(zn, wtab, Bl, i);
    k_scan<<<2048, 256, 0, stream>>>(Bl, wtab, wTtab, dCtab, i);
    k_apply<<<dim3(256, 2), 512, 0, stream>>>(zn, Bl, Pt, Ktap, Dp, yg, i);
    // s4 matmul + residual(z) + gate -> g (stored in zn buffer; zn no longer needed)
    k_mm<0, false><<<dim3(8, 4, 16), 256, 0, stream>>>(s4W + (size_t)i * 65536, s4b + i * 256, yg, zn,
                                                       x, tt_all + i * 4096);
    // x = c1W@g + c1b + x (in place)
    k_mm<1, false><<<dim3(8, 4, 16), 256, 0, stream>>>(c1W + (size_t)i * 65536, c1b + i * 256, zn, x,
                                                       x, nullptr);
    // skips += c2W@g + c2b (in place)
    k_mm<2, false><<<dim3(8, 4, 16), 256, 0, stream>>>(c2W + (size_t)i * 65536, c2b + i * 256, zn, skips,
                                                       skips, nullptr);
  }
  // h1 = relu(Wo1^T-contract over h of skips) in [B,H,L]
  k_mm<3, true><<<dim3(8, 4, 16), 256, 0, stream>>>(Wo1, bo1, skips, yg, nullptr, nullptr);
  k_out<<<dim3(8, 16), 256, 0, stream>>>(yg, Wo2, bo2, input, (float*)d_out);
}

// Round 4
// 1060.176 us; speedup vs baseline: 5.0694x; 1.6972x over previous
//
#include <hip/hip_runtime.h>
#include <math.h>

// Problem sizes
// B=16, L=1024, DIN=64, H=256, N=64, TEMB=128, NB=6; chunk T=64, C=16

typedef __attribute__((ext_vector_type(8))) short bf16x8;
typedef __attribute__((ext_vector_type(4))) float f32x4;

__device__ __forceinline__ short f2bf(float f) {
  unsigned u = __builtin_bit_cast(unsigned, f);
  unsigned r = (u + 0x7FFFu + ((u >> 16) & 1u)) >> 16;
  return (short)r;
}

// ---------------- t-embedding MLP:  tv[b,h] ----------------
__global__ __launch_bounds__(256) void k_temb(
    const float* __restrict__ t, const float* __restrict__ Wt1, const float* __restrict__ bt1,
    const float* __restrict__ Wt2, const float* __restrict__ bt2, float* __restrict__ tv) {
  int b = blockIdx.x, tid = threadIdx.x;
  __shared__ float emb[128];
  __shared__ float tv1[256];
  if (tid < 128) {
    int j = tid & 63;
    float f = expf(-logf(10000.f) / 63.f * (float)j);
    float a = t[b] * f;
    emb[tid] = (tid < 64) ? sinf(a) : cosf(a);
  }
  __syncthreads();
  float acc = bt1[tid];
  for (int k = 0; k < 128; k++) acc = fmaf(emb[k], Wt1[k * 256 + tid], acc);
  tv1[tid] = acc / (1.f + expf(-acc));
  __syncthreads();
  float acc2 = bt2[tid];
  for (int k = 0; k < 256; k++) acc2 = fmaf(tv1[k], Wt2[k * 256 + tid], acc2);
  tv[b * 256 + tid] = acc2 / (1.f + expf(-acc2));
}

// ---------------- tt_all[i,b,h] = tv[b]@tW[i] + tb[i] ----------------
__global__ __launch_bounds__(256) void k_tt(
    const float* __restrict__ tv, const float* __restrict__ tW, const float* __restrict__ tb,
    float* __restrict__ tt_all) {
  int i = blockIdx.x, b = blockIdx.y, h = threadIdx.x;
  __shared__ float s[256];
  s[h] = tv[b * 256 + h];
  __syncthreads();
  const float* W = tW + i * 256 * 256;
  float acc = tb[i * 256 + h];
  for (int k = 0; k < 256; k++) acc = fmaf(s[k], W[k * 256 + h], acc);
  tt_all[(i * 16 + b) * 256 + h] = acc;
}

// ---------------- input proj: x[b,h,l] = relu(input@W_in + b_in), transposed ----------------
__global__ __launch_bounds__(256) void k_in(
    const float* __restrict__ inp, const float* __restrict__ W, const float* __restrict__ bias,
    float* __restrict__ x) {
  int lt = blockIdx.x, b = blockIdx.y, h = threadIdx.x;
  __shared__ float si[64][68];
  int l0 = lt * 64;
  for (int rep = 0; rep < 16; rep++) {
    int idx = rep * 256 + h;
    int l = idx >> 6, d = idx & 63;
    si[l][d] = inp[(size_t)(b * 1024 + l0 + l) * 64 + d];
  }
  float wc[64];
  #pragma unroll
  for (int d = 0; d < 64; d++) wc[d] = W[d * 256 + h];
  float bh = bias[h];
  __syncthreads();
  float* xp = x + (size_t)(b * 256 + h) * 1024 + l0;
  for (int l4 = 0; l4 < 16; l4++) {
    float4 o;
    float* op = &o.x;
    #pragma unroll
    for (int j = 0; j < 4; j++) {
      int l = l4 * 4 + j;
      float a = bh;
      #pragma unroll
      for (int d4 = 0; d4 < 16; d4++) {
        float4 v = *reinterpret_cast<const float4*>(&si[l][d4 * 4]);
        a = fmaf(v.x, wc[d4 * 4 + 0], a);
        a = fmaf(v.y, wc[d4 * 4 + 1], a);
        a = fmaf(v.z, wc[d4 * 4 + 2], a);
        a = fmaf(v.w, wc[d4 * 4 + 3], a);
      }
      op[j] = fmaxf(a, 0.f);
    }
    *reinterpret_cast<float4*>(xp + l4 * 4) = o;
  }
}

// ---------------- per-mode tables: w, w^64, dC (all blocks) ----------------
__global__ __launch_bounds__(256) void k_tab(
    const float* __restrict__ log_dt, const float* __restrict__ A_log_re, const float* __restrict__ A_im,
    const float* __restrict__ C_re, const float* __restrict__ C_im,
    float* __restrict__ wtab, float* __restrict__ wTtab, float* __restrict__ dCtab) {
  int idx = blockIdx.x * 256 + threadIdx.x;  // over NB*H*N = 98304
  int i = idx / (256 * 64);
  int rem = idx % (256 * 64);
  int h = rem >> 6, n = rem & 63;
  float dt = expf(log_dt[i * 256 + h]);
  float Ar = -expf(A_log_re[idx]);
  float Ai = A_im[idx];
  float ar = dt * Ar, ai = dt * Ai;
  float ea = expf(ar);
  float wr = ea * cosf(ai), wi = ea * sinf(ai);
  float pr = wr, pi = wi;
  #pragma unroll
  for (int s = 0; s < 6; s++) { float nr = pr * pr - pi * pi; float ni = 2.f * pr * pi; pr = nr; pi = ni; }
  float den = Ar * Ar + Ai * Ai;
  float qr = ((wr - 1.f) * Ar + wi * Ai) / den;
  float qi = (wi * Ar - (wr - 1.f) * Ai) / den;
  wtab[idx * 2] = wr; wtab[idx * 2 + 1] = wi;
  wTtab[idx * 2] = pr; wTtab[idx * 2 + 1] = pi;
  #pragma unroll
  for (int s = 0; s < 2; s++) {
    float cr = C_re[((size_t)(i * 2 + s) * 256 + h) * 64 + n];
    float ci = C_im[((size_t)(i * 2 + s) * 256 + h) * 64 + n];
    dCtab[(((size_t)(i * 2 + s) * 256 + h) * 64 + n) * 2]     = cr * qr - ci * qi;
    dCtab[(((size_t)(i * 2 + s) * 256 + h) * 64 + n) * 2 + 1] = cr * qi + ci * qr;
  }
}

// ---------------- weight prep: bf16 conversions ----------------
// s4Wbf [6][256][256]; c12Wbf [6][512][256] (c1 rows then c2 rows); Wo1T [256][256] (transposed)
__global__ __launch_bounds__(256) void k_prep(
    const float* __restrict__ s4W, const float* __restrict__ c1W, const float* __restrict__ c2W,
    const float* __restrict__ Wo1,
    unsigned short* __restrict__ s4Wbf, unsigned short* __restrict__ c12Wbf, unsigned short* __restrict__ Wo1T) {
  int idx = blockIdx.x * 256 + threadIdx.x;  // 4864*256 = 1245184
  if (idx < 393216) {
    s4Wbf[idx] = (unsigned short)f2bf(s4W[idx]);
  } else if (idx < 393216 + 786432) {
    int j = idx - 393216;
    int i = j / 131072, r = j % 131072;
    int o2 = r >> 8, k = r & 255;
    float v = (o2 < 256) ? c1W[(size_t)i * 65536 + o2 * 256 + k]
                         : c2W[(size_t)i * 65536 + (o2 - 256) * 256 + k];
    c12Wbf[j] = (unsigned short)f2bf(v);
  } else {
    int j = idx - 1179648;  // < 65536
    int o = j >> 8, k = j & 255;
    Wo1T[j] = (unsigned short)f2bf(Wo1[k * 256 + o]);
  }
}

// ---------------- skips fp32 -> bf16 ----------------
__global__ __launch_bounds__(256) void k_conv(const float* __restrict__ src, unsigned short* __restrict__ dst) {
  int idx = (blockIdx.x * 256 + threadIdx.x) * 8;
  float4 v0 = *reinterpret_cast<const float4*>(src + idx);
  float4 v1 = *reinterpret_cast<const float4*>(src + idx + 4);
  ushort4 a = make_ushort4((unsigned short)f2bf(v0.x), (unsigned short)f2bf(v0.y),
                           (unsigned short)f2bf(v0.z), (unsigned short)f2bf(v0.w));
  ushort4 b = make_ushort4((unsigned short)f2bf(v1.x), (unsigned short)f2bf(v1.y),
                           (unsigned short)f2bf(v1.z), (unsigned short)f2bf(v1.w));
  *reinterpret_cast<ushort4*>(dst + idx) = a;
  *reinterpret_cast<ushort4*>(dst + idx + 4) = b;
}

// ---------------- Pt[h][t][2n{+1}] = {Re, -Im}(w^t),  t=0..63 (per net-block i) ----------------
__global__ __launch_bounds__(256) void k_pcar(const float* __restrict__ wtab, float* __restrict__ Pt, int i) {
  int idx = blockIdx.x * 256 + threadIdx.x;  // h*64+n
  int h = idx >> 6, n = idx & 63;
  int gi = (i * 256 + h) * 64 + n;
  float wr = wtab[gi * 2], wi = wtab[gi * 2 + 1];
  float pr = 1.f, pi = 0.f;
  float* base = Pt + (size_t)h * 8192 + 2 * n;
  for (int t = 0; t < 64; t++) {
    *reinterpret_cast<float2*>(base + t * 128) = make_float2(pr, -pi);
    float nr2 = pr * wr - pi * wi, ni2 = pr * wi + pi * wr;
    pr = nr2; pi = ni2;
  }
}

// ---------------- Ktap[s][h][j] = 2 Re(sum_n dC_s w^j) ----------------
__global__ __launch_bounds__(256) void k_ktap(
    const float* __restrict__ dCtab, const float* __restrict__ Pt, float* __restrict__ Ktap, int i) {
  int idx = blockIdx.x * 256 + threadIdx.x;  // (s*256+h)*64+j, 32768
  int j = idx & 63;
  int sh = idx >> 6;
  int h = sh & 255, s = sh >> 8;
  const float* dc = dCtab + ((size_t)(i * 2 + s) * 256 + h) * 128;
  const float* P = Pt + (size_t)h * 8192 + j * 128;
  float acc = 0.f;
  for (int q = 0; q < 32; q++) {
    float4 d = *reinterpret_cast<const float4*>(dc + q * 4);
    float4 p = *reinterpret_cast<const float4*>(P + q * 4);
    acc = fmaf(d.x, p.x, fmaf(d.y, p.y, fmaf(d.z, p.z, fmaf(d.w, p.w, acc))));
  }
  Ktap[idx] = 2.f * acc;
}

// ---------------- LayerNorm over H with +tt, x[B,H,L] -> zn[B,H,L] ----------------
__global__ __launch_bounds__(256) void k_ln(
    const float* __restrict__ x, const float* __restrict__ tt_all,
    const float* __restrict__ g, const float* __restrict__ bta, float* __restrict__ zn, int i) {
  int ct = blockIdx.x, b = blockIdx.y, tid = threadIdx.x;
  __shared__ float tile[64][257];
  __shared__ float stt[256];
  __shared__ float red[8][64];
  __shared__ float mu_s[64], rs_s[64];
  stt[tid] = tt_all[(i * 16 + b) * 256 + tid];
  __syncthreads();
  int l0 = ct * 64;
  const float* xb = x + (size_t)(b * 256) * 1024 + l0;
  for (int rep = 0; rep < 16; rep++) {
    int idx = rep * 256 + tid;
    int h = idx >> 4;
    int l4 = (idx & 15) * 4;
    float4 v = *reinterpret_cast<const float4*>(xb + (size_t)h * 1024 + l4);
    float a = stt[h];
    tile[l4][h] = v.x + a; tile[l4 + 1][h] = v.y + a; tile[l4 + 2][h] = v.z + a; tile[l4 + 3][h] = v.w + a;
  }
  __syncthreads();
  int l = tid & 63, part = tid >> 6;
  float s1 = 0.f, s2 = 0.f;
  for (int k = 0; k < 64; k++) {
    float v = tile[l][part * 64 + k];
    s1 += v; s2 = fmaf(v, v, s2);
  }
  red[part][l] = s1; red[4 + part][l] = s2;
  __syncthreads();
  if (tid < 64) {
    float a = red[0][tid] + red[1][tid] + red[2][tid] + red[3][tid];
    float q = red[4][tid] + red[5][tid] + red[6][tid] + red[7][tid];
    float mu = a * (1.f / 256.f);
    float var = q * (1.f / 256.f) - mu * mu;
    mu_s[tid] = mu;
    rs_s[tid] = rsqrtf(var + 1e-5f);
  }
  __syncthreads();
  float* zb = zn + (size_t)(b * 256) * 1024 + l0;
  for (int rep = 0; rep < 16; rep++) {
    int idx = rep * 256 + tid;
    int h = idx >> 4;
    int l4 = (idx & 15) * 4;
    float gg = g[i * 256 + h], bb2 = bta[i * 256 + h];
    float4 o;
    o.x = (tile[l4][h]     - mu_s[l4])     * rs_s[l4]     * gg + bb2;
    o.y = (tile[l4 + 1][h] - mu_s[l4 + 1]) * rs_s[l4 + 1] * gg + bb2;
    o.z = (tile[l4 + 2][h] - mu_s[l4 + 2]) * rs_s[l4 + 2] * gg + bb2;
    o.w = (tile[l4 + 3][h] - mu_s[l4 + 3]) * rs_s[l4 + 3] * gg + bb2;
    *reinterpret_cast<float4*>(zb + (size_t)h * 1024 + l4) = o;
  }
}

// ---------------- Horner per-chunk B_loc: Bl[dir][(b,h)][c][2n{+1}] ----------------
__global__ __launch_bounds__(128) void k_bloc(
    const float* __restrict__ zn, const float* __restrict__ wtab, float* __restrict__ Bl, int i) {
  int bh = blockIdx.x;  // b*256+h
  int h = bh & 255;
  int tid = threadIdx.x;
  int n = tid & 63, dir = tid >> 6;
  __shared__ float srow[1024];
  const float* zr = zn + (size_t)bh * 1024;
  for (int r = 0; r < 2; r++) {
    int idx = (r * 128 + tid) * 4;
    *reinterpret_cast<float4*>(srow + idx) = *reinterpret_cast<const float4*>(zr + idx);
  }
  int gi = (i * 256 + h) * 64 + n;
  float wr = wtab[gi * 2], wi = wtab[gi * 2 + 1];
  __syncthreads();
  const float4* s4p = reinterpret_cast<const float4*>(srow);
  float* base = Bl + ((size_t)dir * 4096 + bh) * 2048 + 2 * n;
  for (int c = 0; c < 16; c++) {
    float br = 0.f, bi = 0.f;
    if (dir == 0) {
      for (int tg = 0; tg < 16; tg++) {
        float4 v = s4p[c * 16 + tg];
        float t0;
        t0 = fmaf(br, wr, fmaf(-bi, wi, v.x)); bi = fmaf(br, wi, bi * wr); br = t0;
        t0 = fmaf(br, wr, fmaf(-bi, wi, v.y)); bi = fmaf(br, wi, bi * wr); br = t0;
        t0 = fmaf(br, wr, fmaf(-bi, wi, v.z)); bi = fmaf(br, wi, bi * wr); br = t0;
        t0 = fmaf(br, wr, fmaf(-bi, wi, v.w)); bi = fmaf(br, wi, bi * wr); br = t0;
      }
    } else {
      for (int tg = 15; tg >= 0; tg--) {
        float4 v = s4p[c * 16 + tg];
        float t0;
        t0 = fmaf(br, wr, fmaf(-bi, wi, v.w)); bi = fmaf(br, wi, bi * wr); br = t0;
        t0 = fmaf(br, wr, fmaf(-bi, wi, v.z)); bi = fmaf(br, wi, bi * wr); br = t0;
        t0 = fmaf(br, wr, fmaf(-bi, wi, v.y)); bi = fmaf(br, wi, bi * wr); br = t0;
        t0 = fmaf(br, wr, fmaf(-bi, wi, v.x)); bi = fmaf(br, wi, bi * wr); br = t0;
      }
    }
    *reinterpret_cast<float2*>(base + c * 128) = make_float2(br, bi);
  }
}

// ---------------- chunk scan; in-place replace B_loc with S' (carry coefficient) ----------------
__global__ __launch_bounds__(256) void k_scan(
    float* __restrict__ Bl, const float* __restrict__ wtab, const float* __restrict__ wTtab,
    const float* __restrict__ dCtab, int i) {
  int gid = blockIdx.x * 256 + threadIdx.x;  // 2*16*256*64
  int dir = gid >> 18;
  int r = gid & 262143;
  int b = r >> 14;
  int r2 = r & 16383;
  int h = r2 >> 6, n = r2 & 63;
  int gi = (i * 256 + h) * 64 + n;
  float wTr = wTtab[gi * 2], wTi = wTtab[gi * 2 + 1];
  float dcr = dCtab[((size_t)(i * 2 + dir) * 256 + h) * 128 + 2 * n];
  float dci = dCtab[((size_t)(i * 2 + dir) * 256 + h) * 128 + 2 * n + 1];
  float mr, mi;
  if (dir == 0) {  // fold w: S'_f = 2*dC0*w*S_enter
    float wr = wtab[gi * 2], wi = wtab[gi * 2 + 1];
    mr = 2.f * (dcr * wr - dci * wi); mi = 2.f * (dcr * wi + dci * wr);
  } else {
    mr = 2.f * dcr; mi = 2.f * dci;
  }
  size_t base = ((size_t)dir * 4096 + b * 256 + h) * 2048 + 2 * n;
  float sr = 0.f, si = 0.f;
  if (dir == 0) {
    for (int c = 0; c < 16; c++) {
      float2* p = reinterpret_cast<float2*>(Bl + base + c * 128);
      float2 v = *p;
      *p = make_float2(mr * sr - mi * si, mr * si + mi * sr);
      float nr2 = fmaf(wTr, sr, fmaf(-wTi, si, v.x));
      float ni2 = fmaf(wTr, si, fmaf(wTi, sr, v.y));
      sr = nr2; si = ni2;
    }
  } else {
    for (int c = 15; c >= 0; c--) {
      float2* p = reinterpret_cast<float2*>(Bl + base + c * 128);
      float2 v = *p;
      *p = make_float2(mr * sr - mi * si, mr * si + mi * sr);
      float nr2 = fmaf(wTr, sr, fmaf(-wTi, si, v.x));
      float ni2 = fmaf(wTr, si, fmaf(wTi, sr, v.y));
      sr = nr2; si = ni2;
    }
  }
}

// ---------------- apply (MFMA): y = carry + local-Toeplitz + zn*Dp, gelu -> yg_bf (bf16) ----------------
__global__ __launch_bounds__(512) void k_apply(
    const float* __restrict__ zn, const float* __restrict__ Bl, const float* __restrict__ Pt,
    const float* __restrict__ Ktap, const float* __restrict__ Dp, unsigned short* __restrict__ ygbf, int i) {
  int h = blockIdx.x;
  int tid = threadIdx.x;
  __shared__ short Blds[64][344];
  __shared__ float k0s[64], k1s[64];
  if (tid < 64) k0s[tid] = Ktap[(0 * 256 + h) * 64 + tid];
  else if (tid < 128) k1s[tid - 64] = Ktap[(1 * 256 + h) * 64 + (tid - 64)];
  __syncthreads();
  {
    int trow = tid >> 6, klane = tid & 63;
    const float* Pth = Pt + (size_t)h * 8192;
    #pragma unroll
    for (int ti = 0; ti < 8; ti++) {
      int t = ti * 8 + trow;
      #pragma unroll
      for (int kc = 0; kc < 5; kc++) {
        int k = kc * 64 + klane;
        float v;
        if (kc < 2)      v = Pth[t * 128 + k];
        else if (kc < 4) v = Pth[(63 - t) * 128 + (k - 128)];
        else {
          int tp = klane;
          v = (t >= tp) ? k0s[t - tp] : k1s[tp - t - 1];
        }
        Blds[t][k] = f2bf(v);
      }
    }
  }
  __syncthreads();

  int wid = tid >> 6, lane = tid & 63;
  int b = blockIdx.y * 8 + wid;
  int c = lane & 15, kq = lane >> 4;
  const float* pa0 = Bl + ((size_t)(b * 256 + h)) * 2048 + c * 128 + kq * 8;
  const float* pa1 = pa0 + (size_t)4096 * 2048;
  const float* pzn = zn + ((size_t)(b * 256 + h)) * 1024 + c * 64 + kq * 8;

  f32x4 acc[4];
  #pragma unroll
  for (int nt = 0; nt < 4; nt++) acc[nt] = (f32x4){0.f, 0.f, 0.f, 0.f};

  #pragma unroll
  for (int ks = 0; ks < 10; ks++) {
    const float* src = (ks < 4) ? (pa0 + ks * 32) : (ks < 8) ? (pa1 + (ks - 4) * 32) : (pzn + (ks - 8) * 32);
    float4 lo = *reinterpret_cast<const float4*>(src);
    float4 hi = *reinterpret_cast<const float4*>(src + 4);
    bf16x8 af;
    af[0] = f2bf(lo.x); af[1] = f2bf(lo.y); af[2] = f2bf(lo.z); af[3] = f2bf(lo.w);
    af[4] = f2bf(hi.x); af[5] = f2bf(hi.y); af[6] = f2bf(hi.z); af[7] = f2bf(hi.w);
    #pragma unroll
    for (int nt = 0; nt < 4; nt++) {
      bf16x8 bfv = *reinterpret_cast<const bf16x8*>(&Blds[nt * 16 + c][ks * 32 + kq * 8]);
      acc[nt] = __builtin_amdgcn_mfma_f32_16x16x32_bf16(af, bfv, acc[nt], 0, 0, 0);
    }
  }

  float dp = Dp[i * 256 + h];
  size_t obase = (size_t)(b * 256 + h) * 1024;
  #pragma unroll
  for (int nt = 0; nt < 4; nt++) {
    #pragma unroll
    for (int r = 0; r < 4; r++) {
      int m = kq * 4 + r;
      int t = nt * 16 + c;
      size_t idx = obase + (size_t)m * 64 + t;
      float z = zn[idx];
      float v = fmaf(z, dp, acc[nt][r]);
      float gel = 0.5f * v * (1.f + erff(v * 0.70710678118f));
      ygbf[idx] = (unsigned short)f2bf(gel);
    }
  }
}

// ---------------- MFMA GEMM over [B,H,L]: C[o,l] = sum_k W[o,k] * act[k,l] ----------------
// EPI 0 (GATE): u = acc + bias1[o] + aux1(x)[b,o,l] + aux2(tt)[b,o]; g=(1-t)/(1+t^2), t=e^-u; -> outb bf16
// EPI 1 (RES):  o<256: out1(x)[b,o,l] += acc + bias1[o];  o>=256: out2(skips)[b,o-256,l] += acc + bias2[o-256]
// EPI 2 (RELU): out1(h1)[b,o,l] = relu(acc + bias1[o])
template <int EPI>
__global__ __launch_bounds__(256) void k_gemm(
    const unsigned short* __restrict__ Wbf, const float* __restrict__ bias1, const float* __restrict__ bias2,
    const unsigned short* __restrict__ act, float* __restrict__ out1, float* __restrict__ out2,
    unsigned short* __restrict__ outb, const float* __restrict__ aux1, const float* __restrict__ aux2) {
  int lt = blockIdx.x, ot = blockIdx.y, b = blockIdx.z;
  int tid = threadIdx.x;
  int l0 = lt * 128, o0 = ot * 64;
  __shared__ unsigned short Alds[128 * 40];  // [l][k] bf16, granule-rotated

  int wid = tid >> 6, lane = tid & 63;
  int wo = wid >> 1, wl = wid & 1;
  int c = lane & 15, kq = lane >> 4;

  // staging mapping
  int kq4 = tid >> 5;   // 0..7 -> k = kq4*4
  int lq = tid & 31;    // l = lq*4 + j
  const unsigned short* actb = act + (size_t)(b * 256) * 1024 + l0 + lq * 4;

  f32x4 acc[2][4];
  #pragma unroll
  for (int mo = 0; mo < 2; mo++)
    #pragma unroll
    for (int nl = 0; nl < 4; nl++) acc[mo][nl] = (f32x4){0.f, 0.f, 0.f, 0.f};

  ushort4 m0, m1, m2, m3;
  {
    const unsigned short* p = actb + (size_t)(kq4 * 4) * 1024;
    m0 = *reinterpret_cast<const ushort4*>(p);
    m1 = *reinterpret_cast<const ushort4*>(p + 1024);
    m2 = *reinterpret_cast<const ushort4*>(p + 2048);
    m3 = *reinterpret_cast<const ushort4*>(p + 3072);
  }

  for (int kc = 0; kc < 256; kc += 32) {
    // store staged micro-tile (transposed, granule-rotated)
    {
      int g0 = kq4 >> 1, hh = (kq4 & 1) * 4;
      int rot = (g0 + lq) & 3;
      unsigned short* wp = &Alds[(lq * 4) * 40 + rot * 8 + hh];
      ushort4 w;
      w = make_ushort4(m0.x, m1.x, m2.x, m3.x); *reinterpret_cast<ushort4*>(wp) = w;
      w = make_ushort4(m0.y, m1.y, m2.y, m3.y); *reinterpret_cast<ushort4*>(wp + 40) = w;
      w = make_ushort4(m0.z, m1.z, m2.z, m3.z); *reinterpret_cast<ushort4*>(wp + 80) = w;
      w = make_ushort4(m0.w, m1.w, m2.w, m3.w); *reinterpret_cast<ushort4*>(wp + 120) = w;
    }
    __syncthreads();
    // prefetch next K-step (wraps harmlessly on last iter)
    {
      int kcn = (kc + 32) & 255;
      const unsigned short* p = actb + (size_t)(kcn + kq4 * 4) * 1024;
      m0 = *reinterpret_cast<const ushort4*>(p);
      m1 = *reinterpret_cast<const ushort4*>(p + 1024);
      m2 = *reinterpret_cast<const ushort4*>(p + 2048);
      m3 = *reinterpret_cast<const ushort4*>(p + 3072);
    }
    // A frags from global (bf16 weights, L2-hot)
    bf16x8 af[2];
    #pragma unroll
    for (int mo = 0; mo < 2; mo++) {
      const unsigned short* wp = Wbf + (size_t)(o0 + wo * 32 + mo * 16 + c) * 256 + kc + kq * 8;
      af[mo] = *reinterpret_cast<const bf16x8*>(wp);
    }
    // B frags from LDS
    bf16x8 bfr[4];
    #pragma unroll
    for (int nl = 0; nl < 4; nl++) {
      int l = wl * 64 + nl * 16 + c;
      int rot = (kq + (l >> 2)) & 3;
      bfr[nl] = *reinterpret_cast<const bf16x8*>(&Alds[l * 40 + rot * 8]);
    }
    #pragma unroll
    for (int mo = 0; mo < 2; mo++)
      #pragma unroll
      for (int nl = 0; nl < 4; nl++)
        acc[mo][nl] = __builtin_amdgcn_mfma_f32_16x16x32_bf16(af[mo], bfr[nl], acc[mo][nl], 0, 0, 0);
    __syncthreads();
  }

  // epilogue
  #pragma unroll
  for (int mo = 0; mo < 2; mo++) {
    #pragma unroll
    for (int nl = 0; nl < 4; nl++) {
      #pragma unroll
      for (int r = 0; r < 4; r++) {
        float a = acc[mo][nl][r];
        int o = o0 + wo * 32 + mo * 16 + kq * 4 + r;
        int l = l0 + wl * 64 + nl * 16 + c;
        if constexpr (EPI == 0) {
          size_t id = ((size_t)(b * 256 + o)) * 1024 + l;
          float u = a + bias1[o] + aux1[id] + aux2[b * 256 + o];
          float t = __expf(fminf(-u, 80.f));
          float gg = (1.f - t) / (1.f + t * t);
          outb[id] = (unsigned short)f2bf(gg);
        } else if constexpr (EPI == 1) {
          if (o < 256) {
            size_t id = ((size_t)(b * 256 + o)) * 1024 + l;
            out1[id] += a + bias1[o];
          } else {
            int o2 = o - 256;
            size_t id = ((size_t)(b * 256 + o2)) * 1024 + l;
            out2[id] += a + bias2[o2];
          }
        } else {
          size_t id = ((size_t)(b * 256 + o)) * 1024 + l;
          out1[id] = fmaxf(a + bias1[o], 0.f);
        }
      }
    }
  }
}

// ---------------- final: out[b,l,d] = h1[b,:,l]@Wo2 + bo2 + input ----------------
__global__ __launch_bounds__(256) void k_out(
    const float* __restrict__ h1, const float* __restrict__ Wo2, const float* __restrict__ bo2,
    const float* __restrict__ inp, float* __restrict__ outp) {
  int lt = blockIdx.x, b = blockIdx.y, tid = threadIdx.x;
  __shared__ float sa[32][132];
  __shared__ float sw2[32][68];
  int l0 = lt * 128;
  float acc[4][8];
  #pragma unroll
  for (int r = 0; r < 4; r++)
    #pragma unroll
    for (int c2 = 0; c2 < 8; c2++) acc[r][c2] = 0.f;
  int df = (tid & 7) * 8;
  int lf = (tid >> 3) * 4;
  for (int kc = 0; kc < 256; kc += 32) {
    for (int rep = 0; rep < 4; rep++) {
      int idx = rep * 256 + tid;
      int kk = idx >> 5;
      int l4 = (idx & 31) * 4;
      float4 v = *reinterpret_cast<const float4*>(h1 + (size_t)(b * 256 + kc + kk) * 1024 + l0 + l4);
      *reinterpret_cast<float4*>(&sa[kk][l4]) = v;
    }
    for (int rep = 0; rep < 8; rep++) {
      int idx = rep * 256 + tid;
      int kk = idx >> 6, d = idx & 63;
      sw2[kk][d] = Wo2[(size_t)(kc + kk) * 64 + d];
    }
    __syncthreads();
    for (int kk = 0; kk < 32; kk++) {
      float4 av = *reinterpret_cast<const float4*>(&sa[kk][lf]);
      float4 w1 = *reinterpret_cast<const float4*>(&sw2[kk][df]);
      float4 w2 = *reinterpret_cast<const float4*>(&sw2[kk][df + 4]);
      float avv[4] = {av.x, av.y, av.z, av.w};
      float wv[8] = {w1.x, w1.y, w1.z, w1.w, w2.x, w2.y, w2.z, w2.w};
      #pragma unroll
      for (int r = 0; r < 4; r++)
        #pragma unroll
        for (int c2 = 0; c2 < 8; c2++) acc[r][c2] = fmaf(avv[r], wv[c2], acc[r][c2]);
    }
    __syncthreads();
  }
  float bv[8];
  #pragma unroll
  for (int c2 = 0; c2 < 8; c2++) bv[c2] = bo2[df + c2];
  #pragma unroll
  for (int r = 0; r < 4; r++) {
    size_t base = (size_t)(b * 1024 + l0 + lf + r) * 64 + df;
    float4 i1 = *reinterpret_cast<const float4*>(inp + base);
    float4 i2 = *reinterpret_cast<const float4*>(inp + base + 4);
    float4 o1 = make_float4(acc[r][0] + bv[0] + i1.x, acc[r][1] + bv[1] + i1.y,
                            acc[r][2] + bv[2] + i1.z, acc[r][3] + bv[3] + i1.w);
    float4 o2 = make_float4(acc[r][4] + bv[4] + i2.x, acc[r][5] + bv[5] + i2.y,
                            acc[r][6] + bv[6] + i2.z, acc[r][7] + bv[7] + i2.w);
    *reinterpret_cast<float4*>(outp + base) = o1;
    *reinterpret_cast<float4*>(outp + base + 4) = o2;
  }
}

extern "C" void kernel_launch(void* const* d_in, const int* in_sizes, int n_in,
                              void* d_out, int out_size, void* d_ws, size_t ws_size,
                              hipStream_t stream) {
  const float* input   = (const float*)d_in[0];
  const float* t       = (const float*)d_in[1];
  const float* W_in    = (const float*)d_in[2];
  const float* b_in    = (const float*)d_in[3];
  const float* Wt1     = (const float*)d_in[4];
  const float* bt1     = (const float*)d_in[5];
  const float* Wt2     = (const float*)d_in[6];
  const float* bt2     = (const float*)d_in[7];
  const float* ln_g    = (const float*)d_in[8];
  const float* ln_b    = (const float*)d_in[9];
  const float* log_dt  = (const float*)d_in[10];
  const float* A_log_re= (const float*)d_in[11];
  const float* A_im    = (const float*)d_in[12];
  const float* C_re    = (const float*)d_in[13];
  const float* C_im    = (const float*)d_in[14];
  const float* Dp      = (const float*)d_in[15];
  const float* s4W     = (const float*)d_in[16];
  const float* s4b     = (const float*)d_in[17];
  const float* tW      = (const float*)d_in[18];
  const float* tb      = (const float*)d_in[19];
  const float* c1W     = (const float*)d_in[20];
  const float* c1b     = (const float*)d_in[21];
  const float* c2W     = (const float*)d_in[22];
  const float* c2b     = (const float*)d_in[23];
  const float* Wo1     = (const float*)d_in[24];
  const float* bo1     = (const float*)d_in[25];
  const float* Wo2     = (const float*)d_in[26];
  const float* bo2     = (const float*)d_in[27];

  float* ws = (float*)d_ws;
  size_t off = 0;
  float* x      = ws + off; off += 4194304;   // [B,H,L] fp32 (after loop: low half reused as skips_bf)
  float* zn     = ws + off; off += 4194304;   // [B,H,L] fp32 (after loop: h1)
  float* ygbuf  = ws + off; off += 4194304;   // [0,2M): yg_bf bf16; [2M,4M): g_bf bf16
  float* skips  = ws + off; off += 4194304;   // [B,H,L] fp32
  float* tv     = ws + off; off += 4096;
  float* tt_all = ws + off; off += 24576;
  float* wtab   = ws + off; off += 196608;
  float* wTtab  = ws + off; off += 196608;
  float* dCtab  = ws + off; off += 393216;
  float* Pt     = ws + off; off += 2097152;   // [H][64 t][128]
  float* Ktap   = ws + off; off += 32768;     // [2][H][64]
  float* Bl     = ws + off; off += 16777216;  // [2][B*H][16][128]
  unsigned short* s4Wbf  = (unsigned short*)(ws + off); off += 196608;  // 393216 bf16
  unsigned short* c12Wbf = (unsigned short*)(ws + off); off += 393216;  // 786432 bf16
  unsigned short* Wo1T   = (unsigned short*)(ws + off); off += 32768;   // 65536 bf16

  unsigned short* ygbf    = (unsigned short*)ygbuf;
  unsigned short* gbf     = (unsigned short*)(ygbuf + 2097152);
  unsigned short* skipsbf = (unsigned short*)x;
  float* h1 = zn;

  hipMemsetAsync(skips, 0, 4194304 * sizeof(float), stream);
  k_temb<<<16, 256, 0, stream>>>(t, Wt1, bt1, Wt2, bt2, tv);
  k_tt<<<dim3(6, 16), 256, 0, stream>>>(tv, tW, tb, tt_all);
  k_in<<<dim3(16, 16), 256, 0, stream>>>(input, W_in, b_in, x);
  k_tab<<<384, 256, 0, stream>>>(log_dt, A_log_re, A_im, C_re, C_im, wtab, wTtab, dCtab);
  k_prep<<<4864, 256, 0, stream>>>(s4W, c1W, c2W, Wo1, s4Wbf, c12Wbf, Wo1T);

  for (int i = 0; i < 6; i++) {
    k_ln<<<dim3(16, 16), 256, 0, stream>>>(x, tt_all, ln_g, ln_b, zn, i);
    k_pcar<<<64, 256, 0, stream>>>(wtab, Pt, i);
    k_ktap<<<128, 256, 0, stream>>>(dCtab, Pt, Ktap, i);
    k_bloc<<<4096, 128, 0, stream>>>(zn, wtab, Bl, i);
    k_scan<<<2048, 256, 0, stream>>>(Bl, wtab, wTtab, dCtab, i);
    k_apply<<<dim3(256, 2), 512, 0, stream>>>(zn, Bl, Pt, Ktap, Dp, ygbf, i);
    // g_bf = gate(s4W@yg + s4b + x + tt)
    k_gemm<0><<<dim3(8, 4, 16), 256, 0, stream>>>(s4Wbf + (size_t)i * 65536, s4b + i * 256, nullptr,
                                                  ygbf, nullptr, nullptr, gbf, x, tt_all + i * 4096);
    // x += c1W@g + c1b ; skips += c2W@g + c2b  (fused, M=512)
    k_gemm<1><<<dim3(8, 8, 16), 256, 0, stream>>>(c12Wbf + (size_t)i * 131072, c1b + i * 256, c2b + i * 256,
                                                  gbf, x, skips, nullptr, nullptr, nullptr);
  }
  k_conv<<<2048, 256, 0, stream>>>(skips, skipsbf);
  // h1 = relu(Wo1^T @ skips + bo1)
  k_gemm<2><<<dim3(8, 4, 16), 256, 0, stream>>>(Wo1T, bo1, nullptr,
                                                skipsbf, h1, nullptr, nullptr, nullptr, nullptr);
  k_out<<<dim3(8, 16), 256, 0, stream>>>(h1, Wo2, bo2, input, (float*)d_out);
}

// Round 5
// 729.532 us; speedup vs baseline: 7.3671x; 1.4532x over previous
//
#include <hip/hip_runtime.h>
#include <math.h>

// Problem sizes
// B=16, L=1024, DIN=64, H=256, N=64, TEMB=128, NB=6; chunk T=64, C=16

typedef __attribute__((ext_vector_type(8))) short bf16x8;
typedef __attribute__((ext_vector_type(4))) float f32x4;

__device__ __forceinline__ short f2bf(float f) {
  unsigned u = __builtin_bit_cast(unsigned, f);
  unsigned r = (u + 0x7FFFu + ((u >> 16) & 1u)) >> 16;
  return (short)r;
}
__device__ __forceinline__ float bf2f(unsigned short v) {
  unsigned u = ((unsigned)v) << 16;
  return __builtin_bit_cast(float, u);
}

// ---------------- t-embedding MLP:  tv[b,h] ----------------
__global__ __launch_bounds__(256) void k_temb(
    const float* __restrict__ t, const float* __restrict__ Wt1, const float* __restrict__ bt1,
    const float* __restrict__ Wt2, const float* __restrict__ bt2, float* __restrict__ tv) {
  int b = blockIdx.x, tid = threadIdx.x;
  __shared__ float emb[128];
  __shared__ float tv1[256];
  if (tid < 128) {
    int j = tid & 63;
    float f = expf(-logf(10000.f) / 63.f * (float)j);
    float a = t[b] * f;
    emb[tid] = (tid < 64) ? sinf(a) : cosf(a);
  }
  __syncthreads();
  float acc = bt1[tid];
  for (int k = 0; k < 128; k++) acc = fmaf(emb[k], Wt1[k * 256 + tid], acc);
  tv1[tid] = acc / (1.f + expf(-acc));
  __syncthreads();
  float acc2 = bt2[tid];
  for (int k = 0; k < 256; k++) acc2 = fmaf(tv1[k], Wt2[k * 256 + tid], acc2);
  tv[b * 256 + tid] = acc2 / (1.f + expf(-acc2));
}

// ---------------- tt_all[i,b,h] = tv[b]@tW[i] + tb[i] ----------------
__global__ __launch_bounds__(256) void k_tt(
    const float* __restrict__ tv, const float* __restrict__ tW, const float* __restrict__ tb,
    float* __restrict__ tt_all) {
  int i = blockIdx.x, b = blockIdx.y, h = threadIdx.x;
  __shared__ float s[256];
  s[h] = tv[b * 256 + h];
  __syncthreads();
  const float* W = tW + i * 256 * 256;
  float acc = tb[i * 256 + h];
  for (int k = 0; k < 256; k++) acc = fmaf(s[k], W[k * 256 + h], acc);
  tt_all[(i * 16 + b) * 256 + h] = acc;
}

// ---------------- input proj: x[b,h,l] = relu(input@W_in + b_in), transposed ----------------
__global__ __launch_bounds__(256) void k_in(
    const float* __restrict__ inp, const float* __restrict__ W, const float* __restrict__ bias,
    float* __restrict__ x) {
  int lt = blockIdx.x, b = blockIdx.y, h = threadIdx.x;
  __shared__ float si[64][68];
  int l0 = lt * 64;
  for (int rep = 0; rep < 16; rep++) {
    int idx = rep * 256 + h;
    int l = idx >> 6, d = idx & 63;
    si[l][d] = inp[(size_t)(b * 1024 + l0 + l) * 64 + d];
  }
  float wc[64];
  #pragma unroll
  for (int d = 0; d < 64; d++) wc[d] = W[d * 256 + h];
  float bh = bias[h];
  __syncthreads();
  float* xp = x + (size_t)(b * 256 + h) * 1024 + l0;
  for (int l4 = 0; l4 < 16; l4++) {
    float4 o;
    float* op = &o.x;
    #pragma unroll
    for (int j = 0; j < 4; j++) {
      int l = l4 * 4 + j;
      float a = bh;
      #pragma unroll
      for (int d4 = 0; d4 < 16; d4++) {
        float4 v = *reinterpret_cast<const float4*>(&si[l][d4 * 4]);
        a = fmaf(v.x, wc[d4 * 4 + 0], a);
        a = fmaf(v.y, wc[d4 * 4 + 1], a);
        a = fmaf(v.z, wc[d4 * 4 + 2], a);
        a = fmaf(v.w, wc[d4 * 4 + 3], a);
      }
      op[j] = fmaxf(a, 0.f);
    }
    *reinterpret_cast<float4*>(xp + l4 * 4) = o;
  }
}

// ---------------- per-mode tables: w, w^64, dC (all blocks) ----------------
__global__ __launch_bounds__(256) void k_tab(
    const float* __restrict__ log_dt, const float* __restrict__ A_log_re, const float* __restrict__ A_im,
    const float* __restrict__ C_re, const float* __restrict__ C_im,
    float* __restrict__ wtab, float* __restrict__ wTtab, float* __restrict__ dCtab) {
  int idx = blockIdx.x * 256 + threadIdx.x;  // over NB*H*N = 98304
  int i = idx / (256 * 64);
  int rem = idx % (256 * 64);
  int h = rem >> 6, n = rem & 63;
  float dt = expf(log_dt[i * 256 + h]);
  float Ar = -expf(A_log_re[idx]);
  float Ai = A_im[idx];
  float ar = dt * Ar, ai = dt * Ai;
  float ea = expf(ar);
  float wr = ea * cosf(ai), wi = ea * sinf(ai);
  float pr = wr, pi = wi;
  #pragma unroll
  for (int s = 0; s < 6; s++) { float nr = pr * pr - pi * pi; float ni = 2.f * pr * pi; pr = nr; pi = ni; }
  float den = Ar * Ar + Ai * Ai;
  float qr = ((wr - 1.f) * Ar + wi * Ai) / den;
  float qi = (wi * Ar - (wr - 1.f) * Ai) / den;
  wtab[idx * 2] = wr; wtab[idx * 2 + 1] = wi;
  wTtab[idx * 2] = pr; wTtab[idx * 2 + 1] = pi;
  #pragma unroll
  for (int s = 0; s < 2; s++) {
    float cr = C_re[((size_t)(i * 2 + s) * 256 + h) * 64 + n];
    float ci = C_im[((size_t)(i * 2 + s) * 256 + h) * 64 + n];
    dCtab[(((size_t)(i * 2 + s) * 256 + h) * 64 + n) * 2]     = cr * qr - ci * qi;
    dCtab[(((size_t)(i * 2 + s) * 256 + h) * 64 + n) * 2 + 1] = cr * qi + ci * qr;
  }
}

// ---------------- weight prep: bf16 conversions ----------------
__global__ __launch_bounds__(256) void k_prep(
    const float* __restrict__ s4W, const float* __restrict__ c1W, const float* __restrict__ c2W,
    const float* __restrict__ Wo1,
    unsigned short* __restrict__ s4Wbf, unsigned short* __restrict__ c12Wbf, unsigned short* __restrict__ Wo1T) {
  int idx = blockIdx.x * 256 + threadIdx.x;  // 4864*256 = 1245184
  if (idx < 393216) {
    s4Wbf[idx] = (unsigned short)f2bf(s4W[idx]);
  } else if (idx < 393216 + 786432) {
    int j = idx - 393216;
    int i = j / 131072, r = j % 131072;
    int o2 = r >> 8, k = r & 255;
    float v = (o2 < 256) ? c1W[(size_t)i * 65536 + o2 * 256 + k]
                         : c2W[(size_t)i * 65536 + (o2 - 256) * 256 + k];
    c12Wbf[j] = (unsigned short)f2bf(v);
  } else {
    int j = idx - 1179648;  // < 65536
    int o = j >> 8, k = j & 255;
    Wo1T[j] = (unsigned short)f2bf(Wo1[k * 256 + o]);
  }
}

// ---------------- skips fp32 -> bf16 ----------------
__global__ __launch_bounds__(256) void k_conv(const float* __restrict__ src, unsigned short* __restrict__ dst) {
  int idx = (blockIdx.x * 256 + threadIdx.x) * 8;
  float4 v0 = *reinterpret_cast<const float4*>(src + idx);
  float4 v1 = *reinterpret_cast<const float4*>(src + idx + 4);
  ushort4 a = make_ushort4((unsigned short)f2bf(v0.x), (unsigned short)f2bf(v0.y),
                           (unsigned short)f2bf(v0.z), (unsigned short)f2bf(v0.w));
  ushort4 b = make_ushort4((unsigned short)f2bf(v1.x), (unsigned short)f2bf(v1.y),
                           (unsigned short)f2bf(v1.z), (unsigned short)f2bf(v1.w));
  *reinterpret_cast<ushort4*>(dst + idx) = a;
  *reinterpret_cast<ushort4*>(dst + idx + 4) = b;
}

// ---------------- Pt[h][t][2n{+1}] = {Re, -Im}(w^t),  t=0..63 (per net-block i) ----------------
__global__ __launch_bounds__(256) void k_pcar(const float* __restrict__ wtab, float* __restrict__ Pt, int i) {
  int idx = blockIdx.x * 256 + threadIdx.x;  // h*64+n
  int h = idx >> 6, n = idx & 63;
  int gi = (i * 256 + h) * 64 + n;
  float wr = wtab[gi * 2], wi = wtab[gi * 2 + 1];
  float pr = 1.f, pi = 0.f;
  float* base = Pt + (size_t)h * 8192 + 2 * n;
  for (int t = 0; t < 64; t++) {
    *reinterpret_cast<float2*>(base + t * 128) = make_float2(pr, -pi);
    float nr2 = pr * wr - pi * wi, ni2 = pr * wi + pi * wr;
    pr = nr2; pi = ni2;
  }
}

// ---------------- Ktap[s][h][j] = 2 Re(sum_n dC_s w^j) ----------------
__global__ __launch_bounds__(256) void k_ktap(
    const float* __restrict__ dCtab, const float* __restrict__ Pt, float* __restrict__ Ktap, int i) {
  int idx = blockIdx.x * 256 + threadIdx.x;  // (s*256+h)*64+j, 32768
  int j = idx & 63;
  int sh = idx >> 6;
  int h = sh & 255, s = sh >> 8;
  const float* dc = dCtab + ((size_t)(i * 2 + s) * 256 + h) * 128;
  const float* P = Pt + (size_t)h * 8192 + j * 128;
  float acc = 0.f;
  for (int q = 0; q < 32; q++) {
    float4 d = *reinterpret_cast<const float4*>(dc + q * 4);
    float4 p = *reinterpret_cast<const float4*>(P + q * 4);
    acc = fmaf(d.x, p.x, fmaf(d.y, p.y, fmaf(d.z, p.z, fmaf(d.w, p.w, acc))));
  }
  Ktap[idx] = 2.f * acc;
}

// ---------------- LayerNorm over H with +tt, x[B,H,L] -> zn[B,H,L] ----------------
__global__ __launch_bounds__(256) void k_ln(
    const float* __restrict__ x, const float* __restrict__ tt_all,
    const float* __restrict__ g, const float* __restrict__ bta, float* __restrict__ zn, int i) {
  int ct = blockIdx.x, b = blockIdx.y, tid = threadIdx.x;
  __shared__ float tile[64][257];
  __shared__ float stt[256];
  __shared__ float red[8][64];
  __shared__ float mu_s[64], rs_s[64];
  stt[tid] = tt_all[(i * 16 + b) * 256 + tid];
  __syncthreads();
  int l0 = ct * 64;
  const float* xb = x + (size_t)(b * 256) * 1024 + l0;
  for (int rep = 0; rep < 16; rep++) {
    int idx = rep * 256 + tid;
    int h = idx >> 4;
    int l4 = (idx & 15) * 4;
    float4 v = *reinterpret_cast<const float4*>(xb + (size_t)h * 1024 + l4);
    float a = stt[h];
    tile[l4][h] = v.x + a; tile[l4 + 1][h] = v.y + a; tile[l4 + 2][h] = v.z + a; tile[l4 + 3][h] = v.w + a;
  }
  __syncthreads();
  int l = tid & 63, part = tid >> 6;
  float s1 = 0.f, s2 = 0.f;
  for (int k = 0; k < 64; k++) {
    float v = tile[l][part * 64 + k];
    s1 += v; s2 = fmaf(v, v, s2);
  }
  red[part][l] = s1; red[4 + part][l] = s2;
  __syncthreads();
  if (tid < 64) {
    float a = red[0][tid] + red[1][tid] + red[2][tid] + red[3][tid];
    float q = red[4][tid] + red[5][tid] + red[6][tid] + red[7][tid];
    float mu = a * (1.f / 256.f);
    float var = q * (1.f / 256.f) - mu * mu;
    mu_s[tid] = mu;
    rs_s[tid] = rsqrtf(var + 1e-5f);
  }
  __syncthreads();
  float* zb = zn + (size_t)(b * 256) * 1024 + l0;
  for (int rep = 0; rep < 16; rep++) {
    int idx = rep * 256 + tid;
    int h = idx >> 4;
    int l4 = (idx & 15) * 4;
    float gg = g[i * 256 + h], bb2 = bta[i * 256 + h];
    float4 o;
    o.x = (tile[l4][h]     - mu_s[l4])     * rs_s[l4]     * gg + bb2;
    o.y = (tile[l4 + 1][h] - mu_s[l4 + 1]) * rs_s[l4 + 1] * gg + bb2;
    o.z = (tile[l4 + 2][h] - mu_s[l4 + 2]) * rs_s[l4 + 2] * gg + bb2;
    o.w = (tile[l4 + 3][h] - mu_s[l4 + 3]) * rs_s[l4 + 3] * gg + bb2;
    *reinterpret_cast<float4*>(zb + (size_t)h * 1024 + l4) = o;
  }
}

// ---------------- B_loc via MFMA: Bl[dir][(b,h)][c][2n{+1}] (bf16) ----------------
// Per h: C[(b,c) rows][256 cols] = zn[(b,c)][64 t] x P[64 t][256 cols]
// cols = dir*128 + 2n + comp;  P fwd col: w^{63-t}, bwd col: w^t (re/im from Pt with sign flip on odd).
__global__ __launch_bounds__(512, 4) void k_blocm(
    const float* __restrict__ zn, const float* __restrict__ Pt, unsigned short* __restrict__ Bl, int i) {
  int h = blockIdx.x;
  int tid = threadIdx.x;
  __shared__ float Ps[64][130];            // fp32 stage of Pt[h]
  __shared__ unsigned short Bp[256][72];   // bf16 B-panel [col][t]
  // stage Pt[h] (coalesced)
  {
    const float* src = Pt + (size_t)h * 8192;
    #pragma unroll
    for (int rep = 0; rep < 4; rep++) {
      int idx = rep * 512 + tid;  // 2048 float4
      int t = idx >> 5, k4 = (idx & 31) * 4;
      float4 v = *reinterpret_cast<const float4*>(src + t * 128 + k4);
      *reinterpret_cast<float4*>(&Ps[t][k4]) = v;
    }
  }
  __syncthreads();
  // build B-panel: t-parallel writes (conflict-free)
  {
    int t = tid & 63;
    int colblk = tid >> 6;  // 8 blocks of 32 cols
    #pragma unroll
    for (int cc = 0; cc < 32; cc++) {
      int col = colblk * 32 + cc;
      int k = col & 127;
      float v = (col < 128) ? Ps[63 - t][k] : Ps[t][k];
      if (k & 1) v = -v;
      Bp[col][t] = (unsigned short)f2bf(v);
    }
  }
  __syncthreads();

  int wid = tid >> 6, lane = tid & 63;
  int b = blockIdx.y * 8 + wid;          // one batch per wave
  int c = lane & 15, kq = lane >> 4;
  const float* pzn = zn + ((size_t)(b * 256 + h)) * 1024 + c * 64 + kq * 8;

  // A-frags: zn chunks (bf16)
  bf16x8 af[2];
  #pragma unroll
  for (int ks = 0; ks < 2; ks++) {
    float4 lo = *reinterpret_cast<const float4*>(pzn + ks * 32);
    float4 hi = *reinterpret_cast<const float4*>(pzn + ks * 32 + 4);
    af[ks][0] = f2bf(lo.x); af[ks][1] = f2bf(lo.y); af[ks][2] = f2bf(lo.z); af[ks][3] = f2bf(lo.w);
    af[ks][4] = f2bf(hi.x); af[ks][5] = f2bf(hi.y); af[ks][6] = f2bf(hi.z); af[ks][7] = f2bf(hi.w);
  }

  f32x4 acc[16];
  #pragma unroll
  for (int nt = 0; nt < 16; nt++) acc[nt] = (f32x4){0.f, 0.f, 0.f, 0.f};
  #pragma unroll
  for (int ks = 0; ks < 2; ks++) {
    #pragma unroll
    for (int nt = 0; nt < 16; nt++) {
      bf16x8 bfv = *reinterpret_cast<const bf16x8*>(&Bp[nt * 16 + c][ks * 32 + kq * 8]);
      acc[nt] = __builtin_amdgcn_mfma_f32_16x16x32_bf16(af[ks], bfv, acc[nt], 0, 0, 0);
    }
  }

  // write out: chunk = kq*4+r, col = nt*16+c
  #pragma unroll
  for (int nt = 0; nt < 16; nt++) {
    int col = nt * 16 + c;
    int dir = col >> 7, ncomp = col & 127;
    unsigned short* dst = Bl + ((size_t)(dir * 4096 + b * 256 + h)) * 2048 + ncomp;
    #pragma unroll
    for (int r = 0; r < 4; r++) {
      int chunk = kq * 4 + r;
      dst[chunk * 128] = (unsigned short)f2bf(acc[nt][r]);
    }
  }
}

// ---------------- chunk scan (bf16 Bl); in-place replace B_loc with S' ----------------
__global__ __launch_bounds__(256) void k_scan(
    unsigned short* __restrict__ Bl, const float* __restrict__ wtab, const float* __restrict__ wTtab,
    const float* __restrict__ dCtab, int i) {
  int gid = blockIdx.x * 256 + threadIdx.x;  // 2*16*256*64
  int dir = gid >> 18;
  int r = gid & 262143;
  int b = r >> 14;
  int r2 = r & 16383;
  int h = r2 >> 6, n = r2 & 63;
  int gi = (i * 256 + h) * 64 + n;
  float wTr = wTtab[gi * 2], wTi = wTtab[gi * 2 + 1];
  float dcr = dCtab[((size_t)(i * 2 + dir) * 256 + h) * 128 + 2 * n];
  float dci = dCtab[((size_t)(i * 2 + dir) * 256 + h) * 128 + 2 * n + 1];
  float mr, mi;
  if (dir == 0) {  // fold w: S'_f = 2*dC0*w*S_enter
    float wr = wtab[gi * 2], wi = wtab[gi * 2 + 1];
    mr = 2.f * (dcr * wr - dci * wi); mi = 2.f * (dcr * wi + dci * wr);
  } else {
    mr = 2.f * dcr; mi = 2.f * dci;
  }
  size_t base = ((size_t)dir * 4096 + b * 256 + h) * 2048 + 2 * n;
  float sr = 0.f, si = 0.f;
  if (dir == 0) {
    for (int c = 0; c < 16; c++) {
      ushort2* p = reinterpret_cast<ushort2*>(Bl + base + c * 128);
      ushort2 v = *p;
      float vr = bf2f(v.x), vi = bf2f(v.y);
      *p = make_ushort2((unsigned short)f2bf(mr * sr - mi * si), (unsigned short)f2bf(mr * si + mi * sr));
      float nr2 = fmaf(wTr, sr, fmaf(-wTi, si, vr));
      float ni2 = fmaf(wTr, si, fmaf(wTi, sr, vi));
      sr = nr2; si = ni2;
    }
  } else {
    for (int c = 15; c >= 0; c--) {
      ushort2* p = reinterpret_cast<ushort2*>(Bl + base + c * 128);
      ushort2 v = *p;
      float vr = bf2f(v.x), vi = bf2f(v.y);
      *p = make_ushort2((unsigned short)f2bf(mr * sr - mi * si), (unsigned short)f2bf(mr * si + mi * sr));
      float nr2 = fmaf(wTr, sr, fmaf(-wTi, si, vr));
      float ni2 = fmaf(wTr, si, fmaf(wTi, sr, vi));
      sr = nr2; si = ni2;
    }
  }
}

// ---------------- apply (MFMA): y = carry + local-Toeplitz + zn*Dp, gelu -> yg_bf (bf16) ----------------
__global__ __launch_bounds__(512) void k_apply(
    const float* __restrict__ zn, const unsigned short* __restrict__ Bl, const float* __restrict__ Pt,
    const float* __restrict__ Ktap, const float* __restrict__ Dp, unsigned short* __restrict__ ygbf, int i) {
  int h = blockIdx.x;
  int tid = threadIdx.x;
  __shared__ short Blds[64][344];
  __shared__ float k0s[64], k1s[64];
  if (tid < 64) k0s[tid] = Ktap[(0 * 256 + h) * 64 + tid];
  else if (tid < 128) k1s[tid - 64] = Ktap[(1 * 256 + h) * 64 + (tid - 64)];
  __syncthreads();
  {
    int trow = tid >> 6, klane = tid & 63;
    const float* Pth = Pt + (size_t)h * 8192;
    #pragma unroll
    for (int ti = 0; ti < 8; ti++) {
      int t = ti * 8 + trow;
      #pragma unroll
      for (int kc = 0; kc < 5; kc++) {
        int k = kc * 64 + klane;
        float v;
        if (kc < 2)      v = Pth[t * 128 + k];
        else if (kc < 4) v = Pth[(63 - t) * 128 + (k - 128)];
        else {
          int tp = klane;
          v = (t >= tp) ? k0s[t - tp] : k1s[tp - t - 1];
        }
        Blds[t][k] = f2bf(v);
      }
    }
  }
  __syncthreads();

  int wid = tid >> 6, lane = tid & 63;
  int b = blockIdx.y * 8 + wid;
  int c = lane & 15, kq = lane >> 4;
  const unsigned short* pa0 = Bl + ((size_t)(b * 256 + h)) * 2048 + c * 128 + kq * 8;
  const unsigned short* pa1 = pa0 + (size_t)4096 * 2048;
  const float* pzn = zn + ((size_t)(b * 256 + h)) * 1024 + c * 64 + kq * 8;

  f32x4 acc[4];
  #pragma unroll
  for (int nt = 0; nt < 4; nt++) acc[nt] = (f32x4){0.f, 0.f, 0.f, 0.f};

  #pragma unroll
  for (int ks = 0; ks < 10; ks++) {
    bf16x8 af;
    if (ks < 8) {
      const unsigned short* src = (ks < 4) ? (pa0 + ks * 32) : (pa1 + (ks - 4) * 32);
      af = *reinterpret_cast<const bf16x8*>(src);
    } else {
      const float* src = pzn + (ks - 8) * 32;
      float4 lo = *reinterpret_cast<const float4*>(src);
      float4 hi = *reinterpret_cast<const float4*>(src + 4);
      af[0] = f2bf(lo.x); af[1] = f2bf(lo.y); af[2] = f2bf(lo.z); af[3] = f2bf(lo.w);
      af[4] = f2bf(hi.x); af[5] = f2bf(hi.y); af[6] = f2bf(hi.z); af[7] = f2bf(hi.w);
    }
    #pragma unroll
    for (int nt = 0; nt < 4; nt++) {
      bf16x8 bfv = *reinterpret_cast<const bf16x8*>(&Blds[nt * 16 + c][ks * 32 + kq * 8]);
      acc[nt] = __builtin_amdgcn_mfma_f32_16x16x32_bf16(af, bfv, acc[nt], 0, 0, 0);
    }
  }

  float dp = Dp[i * 256 + h];
  size_t obase = (size_t)(b * 256 + h) * 1024;
  #pragma unroll
  for (int nt = 0; nt < 4; nt++) {
    #pragma unroll
    for (int r = 0; r < 4; r++) {
      int m = kq * 4 + r;
      int t = nt * 16 + c;
      size_t idx = obase + (size_t)m * 64 + t;
      float z = zn[idx];
      float v = fmaf(z, dp, acc[nt][r]);
      float gel = 0.5f * v * (1.f + erff(v * 0.70710678118f));
      ygbf[idx] = (unsigned short)f2bf(gel);
    }
  }
}

// ---------------- MFMA GEMM over [B,H,L]: C[o,l] = sum_k W[o,k] * act[k,l] ----------------
// EPI 0 (GATE): u = acc + bias1[o] + aux1(x)[b,o,l] + aux2(tt)[b,o]; g=(1-t)/(1+t^2), t=e^-u; -> outb bf16
// EPI 1 (RES):  o<256: out1(x)[b,o,l] += acc + bias1[o];  o>=256: out2(skips)[b,o-256,l] += acc + bias2[o-256]
// EPI 2 (RELU): out1(h1)[b,o,l] = relu(acc + bias1[o])
template <int EPI>
__global__ __launch_bounds__(256) void k_gemm(
    const unsigned short* __restrict__ Wbf, const float* __restrict__ bias1, const float* __restrict__ bias2,
    const unsigned short* __restrict__ act, float* __restrict__ out1, float* __restrict__ out2,
    unsigned short* __restrict__ outb, const float* __restrict__ aux1, const float* __restrict__ aux2) {
  int lt = blockIdx.x, ot = blockIdx.y, b = blockIdx.z;
  int tid = threadIdx.x;
  int l0 = lt * 128, o0 = ot * 64;
  __shared__ unsigned short Alds[128 * 40];  // [l][k] bf16, granule-rotated

  int wid = tid >> 6, lane = tid & 63;
  int wo = wid >> 1, wl = wid & 1;
  int c = lane & 15, kq = lane >> 4;

  int kq4 = tid >> 5;   // 0..7 -> k = kq4*4
  int lq = tid & 31;    // l = lq*4 + j
  const unsigned short* actb = act + (size_t)(b * 256) * 1024 + l0 + lq * 4;

  f32x4 acc[2][4];
  #pragma unroll
  for (int mo = 0; mo < 2; mo++)
    #pragma unroll
    for (int nl = 0; nl < 4; nl++) acc[mo][nl] = (f32x4){0.f, 0.f, 0.f, 0.f};

  ushort4 m0, m1, m2, m3;
  {
    const unsigned short* p = actb + (size_t)(kq4 * 4) * 1024;
    m0 = *reinterpret_cast<const ushort4*>(p);
    m1 = *reinterpret_cast<const ushort4*>(p + 1024);
    m2 = *reinterpret_cast<const ushort4*>(p + 2048);
    m3 = *reinterpret_cast<const ushort4*>(p + 3072);
  }

  for (int kc = 0; kc < 256; kc += 32) {
    {
      int g0 = kq4 >> 1, hh = (kq4 & 1) * 4;
      int rot = (g0 + lq) & 3;
      unsigned short* wp = &Alds[(lq * 4) * 40 + rot * 8 + hh];
      ushort4 w;
      w = make_ushort4(m0.x, m1.x, m2.x, m3.x); *reinterpret_cast<ushort4*>(wp) = w;
      w = make_ushort4(m0.y, m1.y, m2.y, m3.y); *reinterpret_cast<ushort4*>(wp + 40) = w;
      w = make_ushort4(m0.z, m1.z, m2.z, m3.z); *reinterpret_cast<ushort4*>(wp + 80) = w;
      w = make_ushort4(m0.w, m1.w, m2.w, m3.w); *reinterpret_cast<ushort4*>(wp + 120) = w;
    }
    __syncthreads();
    {
      int kcn = (kc + 32) & 255;
      const unsigned short* p = actb + (size_t)(kcn + kq4 * 4) * 1024;
      m0 = *reinterpret_cast<const ushort4*>(p);
      m1 = *reinterpret_cast<const ushort4*>(p + 1024);
      m2 = *reinterpret_cast<const ushort4*>(p + 2048);
      m3 = *reinterpret_cast<const ushort4*>(p + 3072);
    }
    bf16x8 af[2];
    #pragma unroll
    for (int mo = 0; mo < 2; mo++) {
      const unsigned short* wp = Wbf + (size_t)(o0 + wo * 32 + mo * 16 + c) * 256 + kc + kq * 8;
      af[mo] = *reinterpret_cast<const bf16x8*>(wp);
    }
    bf16x8 bfr[4];
    #pragma unroll
    for (int nl = 0; nl < 4; nl++) {
      int l = wl * 64 + nl * 16 + c;
      int rot = (kq + (l >> 2)) & 3;
      bfr[nl] = *reinterpret_cast<const bf16x8*>(&Alds[l * 40 + rot * 8]);
    }
    #pragma unroll
    for (int mo = 0; mo < 2; mo++)
      #pragma unroll
      for (int nl = 0; nl < 4; nl++)
        acc[mo][nl] = __builtin_amdgcn_mfma_f32_16x16x32_bf16(af[mo], bfr[nl], acc[mo][nl], 0, 0, 0);
    __syncthreads();
  }

  #pragma unroll
  for (int mo = 0; mo < 2; mo++) {
    #pragma unroll
    for (int nl = 0; nl < 4; nl++) {
      #pragma unroll
      for (int r = 0; r < 4; r++) {
        float a = acc[mo][nl][r];
        int o = o0 + wo * 32 + mo * 16 + kq * 4 + r;
        int l = l0 + wl * 64 + nl * 16 + c;
        if constexpr (EPI == 0) {
          size_t id = ((size_t)(b * 256 + o)) * 1024 + l;
          float u = a + bias1[o] + aux1[id] + aux2[b * 256 + o];
          float t = __expf(fminf(-u, 80.f));
          float gg = (1.f - t) / (1.f + t * t);
          outb[id] = (unsigned short)f2bf(gg);
        } else if constexpr (EPI == 1) {
          if (o < 256) {
            size_t id = ((size_t)(b * 256 + o)) * 1024 + l;
            out1[id] += a + bias1[o];
          } else {
            int o2 = o - 256;
            size_t id = ((size_t)(b * 256 + o2)) * 1024 + l;
            out2[id] += a + bias2[o2];
          }
        } else {
          size_t id = ((size_t)(b * 256 + o)) * 1024 + l;
          out1[id] = fmaxf(a + bias1[o], 0.f);
        }
      }
    }
  }
}

// ---------------- final: out[b,l,d] = h1[b,:,l]@Wo2 + bo2 + input ----------------
__global__ __launch_bounds__(256) void k_out(
    const float* __restrict__ h1, const float* __restrict__ Wo2, const float* __restrict__ bo2,
    const float* __restrict__ inp, float* __restrict__ outp) {
  int lt = blockIdx.x, b = blockIdx.y, tid = threadIdx.x;
  __shared__ float sa[32][132];
  __shared__ float sw2[32][68];
  int l0 = lt * 128;
  float acc[4][8];
  #pragma unroll
  for (int r = 0; r < 4; r++)
    #pragma unroll
    for (int c2 = 0; c2 < 8; c2++) acc[r][c2] = 0.f;
  int df = (tid & 7) * 8;
  int lf = (tid >> 3) * 4;
  for (int kc = 0; kc < 256; kc += 32) {
    for (int rep = 0; rep < 4; rep++) {
      int idx = rep * 256 + tid;
      int kk = idx >> 5;
      int l4 = (idx & 31) * 4;
      float4 v = *reinterpret_cast<const float4*>(h1 + (size_t)(b * 256 + kc + kk) * 1024 + l0 + l4);
      *reinterpret_cast<float4*>(&sa[kk][l4]) = v;
    }
    for (int rep = 0; rep < 8; rep++) {
      int idx = rep * 256 + tid;
      int kk = idx >> 6, d = idx & 63;
      sw2[kk][d] = Wo2[(size_t)(kc + kk) * 64 + d];
    }
    __syncthreads();
    for (int kk = 0; kk < 32; kk++) {
      float4 av = *reinterpret_cast<const float4*>(&sa[kk][lf]);
      float4 w1 = *reinterpret_cast<const float4*>(&sw2[kk][df]);
      float4 w2 = *reinterpret_cast<const float4*>(&sw2[kk][df + 4]);
      float avv[4] = {av.x, av.y, av.z, av.w};
      float wv[8] = {w1.x, w1.y, w1.z, w1.w, w2.x, w2.y, w2.z, w2.w};
      #pragma unroll
      for (int r = 0; r < 4; r++)
        #pragma unroll
        for (int c2 = 0; c2 < 8; c2++) acc[r][c2] = fmaf(avv[r], wv[c2], acc[r][c2]);
    }
    __syncthreads();
  }
  float bv[8];
  #pragma unroll
  for (int c2 = 0; c2 < 8; c2++) bv[c2] = bo2[df + c2];
  #pragma unroll
  for (int r = 0; r < 4; r++) {
    size_t base = (size_t)(b * 1024 + l0 + lf + r) * 64 + df;
    float4 i1 = *reinterpret_cast<const float4*>(inp + base);
    float4 i2 = *reinterpret_cast<const float4*>(inp + base + 4);
    float4 o1 = make_float4(acc[r][0] + bv[0] + i1.x, acc[r][1] + bv[1] + i1.y,
                            acc[r][2] + bv[2] + i1.z, acc[r][3] + bv[3] + i1.w);
    float4 o2 = make_float4(acc[r][4] + bv[4] + i2.x, acc[r][5] + bv[5] + i2.y,
                            acc[r][6] + bv[6] + i2.z, acc[r][7] + bv[7] + i2.w);
    *reinterpret_cast<float4*>(outp + base) = o1;
    *reinterpret_cast<float4*>(outp + base + 4) = o2;
  }
}

extern "C" void kernel_launch(void* const* d_in, const int* in_sizes, int n_in,
                              void* d_out, int out_size, void* d_ws, size_t ws_size,
                              hipStream_t stream) {
  const float* input   = (const float*)d_in[0];
  const float* t       = (const float*)d_in[1];
  const float* W_in    = (const float*)d_in[2];
  const float* b_in    = (const float*)d_in[3];
  const float* Wt1     = (const float*)d_in[4];
  const float* bt1     = (const float*)d_in[5];
  const float* Wt2     = (const float*)d_in[6];
  const float* bt2     = (const float*)d_in[7];
  const float* ln_g    = (const float*)d_in[8];
  const float* ln_b    = (const float*)d_in[9];
  const float* log_dt  = (const float*)d_in[10];
  const float* A_log_re= (const float*)d_in[11];
  const float* A_im    = (const float*)d_in[12];
  const float* C_re    = (const float*)d_in[13];
  const float* C_im    = (const float*)d_in[14];
  const float* Dp      = (const float*)d_in[15];
  const float* s4W     = (const float*)d_in[16];
  const float* s4b     = (const float*)d_in[17];
  const float* tW      = (const float*)d_in[18];
  const float* tb      = (const float*)d_in[19];
  const float* c1W     = (const float*)d_in[20];
  const float* c1b     = (const float*)d_in[21];
  const float* c2W     = (const float*)d_in[22];
  const float* c2b     = (const float*)d_in[23];
  const float* Wo1     = (const float*)d_in[24];
  const float* bo1     = (const float*)d_in[25];
  const float* Wo2     = (const float*)d_in[26];
  const float* bo2     = (const float*)d_in[27];

  float* ws = (float*)d_ws;
  size_t off = 0;
  float* x      = ws + off; off += 4194304;   // [B,H,L] fp32 (after loop: low half reused as skips_bf)
  float* zn     = ws + off; off += 4194304;   // [B,H,L] fp32 (after loop: h1)
  float* ygbuf  = ws + off; off += 4194304;   // [0,2M): yg_bf bf16; [2M,4M): g_bf bf16
  float* skips  = ws + off; off += 4194304;   // [B,H,L] fp32
  float* tv     = ws + off; off += 4096;
  float* tt_all = ws + off; off += 24576;
  float* wtab   = ws + off; off += 196608;
  float* wTtab  = ws + off; off += 196608;
  float* dCtab  = ws + off; off += 393216;
  float* Pt     = ws + off; off += 2097152;   // [H][64 t][128]
  float* Ktap   = ws + off; off += 32768;     // [2][H][64]
  float* Bl     = ws + off; off += 16777216;  // bf16 [2][B*H][16][128] (uses half)
  unsigned short* s4Wbf  = (unsigned short*)(ws + off); off += 196608;  // 393216 bf16
  unsigned short* c12Wbf = (unsigned short*)(ws + off); off += 393216;  // 786432 bf16
  unsigned short* Wo1T   = (unsigned short*)(ws + off); off += 32768;   // 65536 bf16

  unsigned short* Blb     = (unsigned short*)Bl;
  unsigned short* ygbf    = (unsigned short*)ygbuf;
  unsigned short* gbf     = (unsigned short*)(ygbuf + 2097152);
  unsigned short* skipsbf = (unsigned short*)x;
  float* h1 = zn;

  hipMemsetAsync(skips, 0, 4194304 * sizeof(float), stream);
  k_temb<<<16, 256, 0, stream>>>(t, Wt1, bt1, Wt2, bt2, tv);
  k_tt<<<dim3(6, 16), 256, 0, stream>>>(tv, tW, tb, tt_all);
  k_in<<<dim3(16, 16), 256, 0, stream>>>(input, W_in, b_in, x);
  k_tab<<<384, 256, 0, stream>>>(log_dt, A_log_re, A_im, C_re, C_im, wtab, wTtab, dCtab);
  k_prep<<<4864, 256, 0, stream>>>(s4W, c1W, c2W, Wo1, s4Wbf, c12Wbf, Wo1T);

  for (int i = 0; i < 6; i++) {
    k_ln<<<dim3(16, 16), 256, 0, stream>>>(x, tt_all, ln_g, ln_b, zn, i);
    k_pcar<<<64, 256, 0, stream>>>(wtab, Pt, i);
    k_ktap<<<128, 256, 0, stream>>>(dCtab, Pt, Ktap, i);
    k_blocm<<<dim3(256, 2), 512, 0, stream>>>(zn, Pt, Blb, i);
    k_scan<<<2048, 256, 0, stream>>>(Blb, wtab, wTtab, dCtab, i);
    k_apply<<<dim3(256, 2), 512, 0, stream>>>(zn, Blb, Pt, Ktap, Dp, ygbf, i);
    // g_bf = gate(s4W@yg + s4b + x + tt)
    k_gemm<0><<<dim3(8, 4, 16), 256, 0, stream>>>(s4Wbf + (size_t)i * 65536, s4b + i * 256, nullptr,
                                                  ygbf, nullptr, nullptr, gbf, x, tt_all + i * 4096);
    // x += c1W@g + c1b ; skips += c2W@g + c2b  (fused, M=512)
    k_gemm<1><<<dim3(8, 8, 16), 256, 0, stream>>>(c12Wbf + (size_t)i * 131072, c1b + i * 256, c2b + i * 256,
                                                  gbf, x, skips, nullptr, nullptr, nullptr);
  }
  k_conv<<<2048, 256, 0, stream>>>(skips, skipsbf);
  // h1 = relu(Wo1^T @ skips + bo1)
  k_gemm<2><<<dim3(8, 4, 16), 256, 0, stream>>>(Wo1T, bo1, nullptr,
                                                skipsbf, h1, nullptr, nullptr, nullptr, nullptr);
  k_out<<<dim3(8, 16), 256, 0, stream>>>(h1, Wo2, bo2, input, (float*)d_out);
}

// Round 6
// 597.825 us; speedup vs baseline: 8.9901x; 1.2203x over previous
//
#include <hip/hip_runtime.h>
#include <math.h>

// Problem sizes
// B=16, L=1024, DIN=64, H=256, N=64, TEMB=128, NB=6; chunk T=64, C=16

typedef __attribute__((ext_vector_type(8))) short bf16x8;
typedef __attribute__((ext_vector_type(4))) float f32x4;

__device__ __forceinline__ short f2bf(float f) {
  unsigned u = __builtin_bit_cast(unsigned, f);
  unsigned r = (u + 0x7FFFu + ((u >> 16) & 1u)) >> 16;
  return (short)r;
}
__device__ __forceinline__ float bf2f(unsigned short v) {
  unsigned u = ((unsigned)v) << 16;
  return __builtin_bit_cast(float, u);
}

// ---------------- t-embedding MLP:  tv[b,h] ----------------
__global__ __launch_bounds__(256) void k_temb(
    const float* __restrict__ t, const float* __restrict__ Wt1, const float* __restrict__ bt1,
    const float* __restrict__ Wt2, const float* __restrict__ bt2, float* __restrict__ tv) {
  int b = blockIdx.x, tid = threadIdx.x;
  __shared__ float emb[128];
  __shared__ float tv1[256];
  if (tid < 128) {
    int j = tid & 63;
    float f = expf(-logf(10000.f) / 63.f * (float)j);
    float a = t[b] * f;
    emb[tid] = (tid < 64) ? sinf(a) : cosf(a);
  }
  __syncthreads();
  float acc = bt1[tid];
  for (int k = 0; k < 128; k++) acc = fmaf(emb[k], Wt1[k * 256 + tid], acc);
  tv1[tid] = acc / (1.f + expf(-acc));
  __syncthreads();
  float acc2 = bt2[tid];
  for (int k = 0; k < 256; k++) acc2 = fmaf(tv1[k], Wt2[k * 256 + tid], acc2);
  tv[b * 256 + tid] = acc2 / (1.f + expf(-acc2));
}

// ---------------- tt_all[i,b,h] = tv[b]@tW[i] + tb[i] ----------------
__global__ __launch_bounds__(256) void k_tt(
    const float* __restrict__ tv, const float* __restrict__ tW, const float* __restrict__ tb,
    float* __restrict__ tt_all) {
  int i = blockIdx.x, b = blockIdx.y, h = threadIdx.x;
  __shared__ float s[256];
  s[h] = tv[b * 256 + h];
  __syncthreads();
  const float* W = tW + i * 256 * 256;
  float acc = tb[i * 256 + h];
  for (int k = 0; k < 256; k++) acc = fmaf(s[k], W[k * 256 + h], acc);
  tt_all[(i * 16 + b) * 256 + h] = acc;
}

// ---------------- input proj: x[b,h,l] = relu(input@W_in + b_in), transposed ----------------
__global__ __launch_bounds__(256) void k_in(
    const float* __restrict__ inp, const float* __restrict__ W, const float* __restrict__ bias,
    float* __restrict__ x) {
  int lt = blockIdx.x, b = blockIdx.y, h = threadIdx.x;
  __shared__ float si[64][68];
  int l0 = lt * 64;
  for (int rep = 0; rep < 16; rep++) {
    int idx = rep * 256 + h;
    int l = idx >> 6, d = idx & 63;
    si[l][d] = inp[(size_t)(b * 1024 + l0 + l) * 64 + d];
  }
  float wc[64];
  #pragma unroll
  for (int d = 0; d < 64; d++) wc[d] = W[d * 256 + h];
  float bh = bias[h];
  __syncthreads();
  float* xp = x + (size_t)(b * 256 + h) * 1024 + l0;
  for (int l4 = 0; l4 < 16; l4++) {
    float4 o;
    float* op = &o.x;
    #pragma unroll
    for (int j = 0; j < 4; j++) {
      int l = l4 * 4 + j;
      float a = bh;
      #pragma unroll
      for (int d4 = 0; d4 < 16; d4++) {
        float4 v = *reinterpret_cast<const float4*>(&si[l][d4 * 4]);
        a = fmaf(v.x, wc[d4 * 4 + 0], a);
        a = fmaf(v.y, wc[d4 * 4 + 1], a);
        a = fmaf(v.z, wc[d4 * 4 + 2], a);
        a = fmaf(v.w, wc[d4 * 4 + 3], a);
      }
      op[j] = fmaxf(a, 0.f);
    }
    *reinterpret_cast<float4*>(xp + l4 * 4) = o;
  }
}

// ---------------- per-mode tables: w, w^64, dC (all blocks) ----------------
__global__ __launch_bounds__(256) void k_tab(
    const float* __restrict__ log_dt, const float* __restrict__ A_log_re, const float* __restrict__ A_im,
    const float* __restrict__ C_re, const float* __restrict__ C_im,
    float* __restrict__ wtab, float* __restrict__ wTtab, float* __restrict__ dCtab) {
  int idx = blockIdx.x * 256 + threadIdx.x;  // over NB*H*N = 98304
  int i = idx / (256 * 64);
  int rem = idx % (256 * 64);
  int h = rem >> 6, n = rem & 63;
  float dt = expf(log_dt[i * 256 + h]);
  float Ar = -expf(A_log_re[idx]);
  float Ai = A_im[idx];
  float ar = dt * Ar, ai = dt * Ai;
  float ea = expf(ar);
  float wr = ea * cosf(ai), wi = ea * sinf(ai);
  float pr = wr, pi = wi;
  #pragma unroll
  for (int s = 0; s < 6; s++) { float nr = pr * pr - pi * pi; float ni = 2.f * pr * pi; pr = nr; pi = ni; }
  float den = Ar * Ar + Ai * Ai;
  float qr = ((wr - 1.f) * Ar + wi * Ai) / den;
  float qi = (wi * Ar - (wr - 1.f) * Ai) / den;
  wtab[idx * 2] = wr; wtab[idx * 2 + 1] = wi;
  wTtab[idx * 2] = pr; wTtab[idx * 2 + 1] = pi;
  #pragma unroll
  for (int s = 0; s < 2; s++) {
    float cr = C_re[((size_t)(i * 2 + s) * 256 + h) * 64 + n];
    float ci = C_im[((size_t)(i * 2 + s) * 256 + h) * 64 + n];
    dCtab[(((size_t)(i * 2 + s) * 256 + h) * 64 + n) * 2]     = cr * qr - ci * qi;
    dCtab[(((size_t)(i * 2 + s) * 256 + h) * 64 + n) * 2 + 1] = cr * qi + ci * qr;
  }
}

// ---------------- weight prep: bf16 conversions ----------------
__global__ __launch_bounds__(256) void k_prep(
    const float* __restrict__ s4W, const float* __restrict__ c1W, const float* __restrict__ c2W,
    const float* __restrict__ Wo1,
    unsigned short* __restrict__ s4Wbf, unsigned short* __restrict__ c12Wbf, unsigned short* __restrict__ Wo1T) {
  int idx = blockIdx.x * 256 + threadIdx.x;  // 4864*256 = 1245184
  if (idx < 393216) {
    s4Wbf[idx] = (unsigned short)f2bf(s4W[idx]);
  } else if (idx < 393216 + 786432) {
    int j = idx - 393216;
    int i = j / 131072, r = j % 131072;
    int o2 = r >> 8, k = r & 255;
    float v = (o2 < 256) ? c1W[(size_t)i * 65536 + o2 * 256 + k]
                         : c2W[(size_t)i * 65536 + (o2 - 256) * 256 + k];
    c12Wbf[j] = (unsigned short)f2bf(v);
  } else {
    int j = idx - 1179648;  // < 65536
    int o = j >> 8, k = j & 255;
    Wo1T[j] = (unsigned short)f2bf(Wo1[k * 256 + o]);
  }
}

// ---------------- skips fp32 -> bf16 ----------------
__global__ __launch_bounds__(256) void k_conv(const float* __restrict__ src, unsigned short* __restrict__ dst) {
  int idx = (blockIdx.x * 256 + threadIdx.x) * 8;
  float4 v0 = *reinterpret_cast<const float4*>(src + idx);
  float4 v1 = *reinterpret_cast<const float4*>(src + idx + 4);
  ushort4 a = make_ushort4((unsigned short)f2bf(v0.x), (unsigned short)f2bf(v0.y),
                           (unsigned short)f2bf(v0.z), (unsigned short)f2bf(v0.w));
  ushort4 b = make_ushort4((unsigned short)f2bf(v1.x), (unsigned short)f2bf(v1.y),
                           (unsigned short)f2bf(v1.z), (unsigned short)f2bf(v1.w));
  *reinterpret_cast<ushort4*>(dst + idx) = a;
  *reinterpret_cast<ushort4*>(dst + idx + 4) = b;
}

// ---------------- Pt_all[i][h][t][2n{+1}] = {Re, -Im}(w^t), all blocks ----------------
__global__ __launch_bounds__(256) void k_pcar(const float* __restrict__ wtab, float* __restrict__ Pt) {
  int idx = blockIdx.x * 256 + threadIdx.x;  // i*16384 + h*64 + n, 98304
  int i = idx >> 14, h = (idx >> 6) & 255, n = idx & 63;
  float wr = wtab[idx * 2], wi = wtab[idx * 2 + 1];
  float pr = 1.f, pi = 0.f;
  float* base = Pt + (size_t)i * 2097152 + (size_t)h * 8192 + 2 * n;
  for (int t = 0; t < 64; t++) {
    *reinterpret_cast<float2*>(base + t * 128) = make_float2(pr, -pi);
    float nr2 = pr * wr - pi * wi, ni2 = pr * wi + pi * wr;
    pr = nr2; pi = ni2;
  }
}

// ---------------- Ktap_all[i][s][h][j] = 2 Re(sum_n dC_s w^j), all blocks ----------------
__global__ __launch_bounds__(256) void k_ktap(
    const float* __restrict__ dCtab, const float* __restrict__ Pt, float* __restrict__ Ktap) {
  int idx = blockIdx.x * 256 + threadIdx.x;  // ((i*2+s)*256+h)*64+j, 196608
  int j = idx & 63;
  int h = (idx >> 6) & 255;
  int i = idx >> 15;
  const float* dc = dCtab + (size_t)(idx >> 6) * 128;
  const float* P = Pt + (size_t)i * 2097152 + (size_t)h * 8192 + j * 128;
  float acc = 0.f;
  for (int q = 0; q < 32; q++) {
    float4 d = *reinterpret_cast<const float4*>(dc + q * 4);
    float4 p = *reinterpret_cast<const float4*>(P + q * 4);
    acc = fmaf(d.x, p.x, fmaf(d.y, p.y, fmaf(d.z, p.z, fmaf(d.w, p.w, acc))));
  }
  Ktap[idx] = 2.f * acc;
}

// ---------------- LayerNorm over H with +tt, x[B,H,L] -> zn bf16 [B,H,L] ----------------
__global__ __launch_bounds__(256) void k_ln(
    const float* __restrict__ x, const float* __restrict__ tt_all,
    const float* __restrict__ g, const float* __restrict__ bta, unsigned short* __restrict__ znbf, int i) {
  int ct = blockIdx.x, b = blockIdx.y, tid = threadIdx.x;
  __shared__ float tile[64][257];
  __shared__ float stt[256];
  __shared__ float red[8][64];
  __shared__ float mu_s[64], rs_s[64];
  stt[tid] = tt_all[(i * 16 + b) * 256 + tid];
  __syncthreads();
  int l0 = ct * 64;
  const float* xb = x + (size_t)(b * 256) * 1024 + l0;
  for (int rep = 0; rep < 16; rep++) {
    int idx = rep * 256 + tid;
    int h = idx >> 4;
    int l4 = (idx & 15) * 4;
    float4 v = *reinterpret_cast<const float4*>(xb + (size_t)h * 1024 + l4);
    float a = stt[h];
    tile[l4][h] = v.x + a; tile[l4 + 1][h] = v.y + a; tile[l4 + 2][h] = v.z + a; tile[l4 + 3][h] = v.w + a;
  }
  __syncthreads();
  int l = tid & 63, part = tid >> 6;
  float s1 = 0.f, s2 = 0.f;
  for (int k = 0; k < 64; k++) {
    float v = tile[l][part * 64 + k];
    s1 += v; s2 = fmaf(v, v, s2);
  }
  red[part][l] = s1; red[4 + part][l] = s2;
  __syncthreads();
  if (tid < 64) {
    float a = red[0][tid] + red[1][tid] + red[2][tid] + red[3][tid];
    float q = red[4][tid] + red[5][tid] + red[6][tid] + red[7][tid];
    float mu = a * (1.f / 256.f);
    float var = q * (1.f / 256.f) - mu * mu;
    mu_s[tid] = mu;
    rs_s[tid] = rsqrtf(var + 1e-5f);
  }
  __syncthreads();
  unsigned short* zb = znbf + (size_t)(b * 256) * 1024 + l0;
  for (int rep = 0; rep < 16; rep++) {
    int idx = rep * 256 + tid;
    int h = idx >> 4;
    int l4 = (idx & 15) * 4;
    float gg = g[i * 256 + h], bb2 = bta[i * 256 + h];
    float o0 = (tile[l4][h]     - mu_s[l4])     * rs_s[l4]     * gg + bb2;
    float o1 = (tile[l4 + 1][h] - mu_s[l4 + 1]) * rs_s[l4 + 1] * gg + bb2;
    float o2 = (tile[l4 + 2][h] - mu_s[l4 + 2]) * rs_s[l4 + 2] * gg + bb2;
    float o3 = (tile[l4 + 3][h] - mu_s[l4 + 3]) * rs_s[l4 + 3] * gg + bb2;
    ushort4 o4 = make_ushort4((unsigned short)f2bf(o0), (unsigned short)f2bf(o1),
                              (unsigned short)f2bf(o2), (unsigned short)f2bf(o3));
    *reinterpret_cast<ushort4*>(zb + (size_t)h * 1024 + l4) = o4;
  }
}

// ---------------- fused B_loc MFMA + in-wave chunk scan -> S' (bf16 Bl) ----------------
// GEMM cols: col = dir*128 + comp*64 + n  (comp-separated so complex math is lane-local).
// Then per lane: 4-chunk in-lane prefix + Hillis-Steele over kq groups (shfl 16/32), fold m,
// write S' in apply's layout Bl[dir][(b,h)][chunk][2n{+1}].
__global__ __launch_bounds__(512, 2) void k_bsc(
    const unsigned short* __restrict__ znbf, const float* __restrict__ Pt,
    const float* __restrict__ wtab, const float* __restrict__ wTtab, const float* __restrict__ dCtab,
    unsigned short* __restrict__ Bl, int i) {
  int h = blockIdx.x;
  int tid = threadIdx.x;
  __shared__ float Ps[64][130];            // fp32 stage of Pt[i][h]
  __shared__ unsigned short Bp[256][72];   // bf16 B-panel [col][t]
  {
    const float* src = Pt + (size_t)h * 8192;
    #pragma unroll
    for (int rep = 0; rep < 4; rep++) {
      int idx = rep * 512 + tid;
      int t = idx >> 5, k4 = (idx & 31) * 4;
      float4 v = *reinterpret_cast<const float4*>(src + t * 128 + k4);
      *reinterpret_cast<float4*>(&Ps[t][k4]) = v;
    }
  }
  __syncthreads();
  {
    int t = tid & 63;
    int colblk = tid >> 6;
    #pragma unroll
    for (int cc = 0; cc < 32; cc++) {
      int col = colblk * 32 + cc;
      int n = col & 63, comp = (col >> 6) & 1, dir = col >> 7;
      int k = 2 * n + comp;
      float v = dir ? Ps[t][k] : Ps[63 - t][k];
      if (comp) v = -v;   // Ps stores -Im; flip to +Im
      Bp[col][t] = (unsigned short)f2bf(v);
    }
  }
  __syncthreads();

  int wid = tid >> 6, lane = tid & 63;
  int b = blockIdx.y * 8 + wid;          // one batch per wave
  int c = lane & 15, kq = lane >> 4;
  const unsigned short* pzn = znbf + ((size_t)(b * 256 + h)) * 1024 + c * 64 + kq * 8;

  bf16x8 af[2];
  af[0] = *reinterpret_cast<const bf16x8*>(pzn);
  af[1] = *reinterpret_cast<const bf16x8*>(pzn + 32);

  f32x4 acc[16];
  #pragma unroll
  for (int nt = 0; nt < 16; nt++) acc[nt] = (f32x4){0.f, 0.f, 0.f, 0.f};
  #pragma unroll
  for (int ks = 0; ks < 2; ks++) {
    #pragma unroll
    for (int nt = 0; nt < 16; nt++) {
      bf16x8 bfv = *reinterpret_cast<const bf16x8*>(&Bp[nt * 16 + c][ks * 32 + kq * 8]);
      acc[nt] = __builtin_amdgcn_mfma_f32_16x16x32_bf16(af[ks], bfv, acc[nt], 0, 0, 0);
    }
  }

  // acc[j]/acc[j+4] = fwd re/im for n=j*16+c; acc[8+j]/acc[12+j] = bwd re/im. rows r = chunk kq*4+r.
  const int gib = (i * 256 + h) * 64;
  unsigned short* blf = Bl + ((size_t)(b * 256 + h)) * 2048;
  unsigned short* blb = blf + (size_t)4096 * 2048;

  #pragma unroll
  for (int j = 0; j < 4; j++) {
    int n = j * 16 + c;
    int gi = gib + n;
    float wTr = wTtab[gi * 2], wTi = wTtab[gi * 2 + 1];
    float w2r = wTr * wTr - wTi * wTi, w2i = 2.f * wTr * wTi;
    float w4r = w2r * w2r - w2i * w2i, w4i = 2.f * w2r * w2i;
    float w8r = w4r * w4r - w4i * w4i, w8i = 2.f * w4r * w4i;
    float wr = wtab[gi * 2], wi = wtab[gi * 2 + 1];
    float d0r = dCtab[((size_t)(i * 2 + 0) * 256 + h) * 128 + 2 * n];
    float d0i = dCtab[((size_t)(i * 2 + 0) * 256 + h) * 128 + 2 * n + 1];
    float d1r = dCtab[((size_t)(i * 2 + 1) * 256 + h) * 128 + 2 * n];
    float d1i = dCtab[((size_t)(i * 2 + 1) * 256 + h) * 128 + 2 * n + 1];
    float mfr = 2.f * (d0r * wr - d0i * wi), mfi = 2.f * (d0r * wi + d0i * wr);
    float mbr = 2.f * d1r, mbi = 2.f * d1i;

    // ---- forward ----
    {
      float er = 0.f, ei = 0.f, entr[4], enti[4];
      #pragma unroll
      for (int r = 0; r < 4; r++) {
        entr[r] = er; enti[r] = ei;
        float br = acc[j][r], bi = acc[j + 4][r];
        float t0 = er * wTr - ei * wTi + br;
        ei = er * wTi + ei * wTr + bi; er = t0;
      }
      float Gr = er, Gi = ei;
      float sr = __shfl_up(Gr, 16), si = __shfl_up(Gi, 16);
      if (kq >= 1) { Gr += sr * w4r - si * w4i; Gi += sr * w4i + si * w4r; }
      sr = __shfl_up(Gr, 32); si = __shfl_up(Gi, 32);
      if (kq >= 2) { Gr += sr * w8r - si * w8i; Gi += sr * w8i + si * w8r; }
      float Sgr = __shfl_up(Gr, 16), Sgi = __shfl_up(Gi, 16);
      if (kq == 0) { Sgr = 0.f; Sgi = 0.f; }
      float pr = 1.f, pi = 0.f;
      #pragma unroll
      for (int r = 0; r < 4; r++) {
        float scr = pr * Sgr - pi * Sgi + entr[r];
        float sci = pr * Sgi + pi * Sgr + enti[r];
        float opr = mfr * scr - mfi * sci;
        float opi = mfr * sci + mfi * scr;
        *reinterpret_cast<ushort2*>(blf + (size_t)(kq * 4 + r) * 128 + 2 * n) =
            make_ushort2((unsigned short)f2bf(opr), (unsigned short)f2bf(opi));
        float t0 = pr * wTr - pi * wTi; pi = pr * wTi + pi * wTr; pr = t0;
      }
    }
    // ---- backward ----
    {
      float er = 0.f, ei = 0.f, entr[4], enti[4];
      #pragma unroll
      for (int rr = 0; rr < 4; rr++) {
        int r = 3 - rr;
        entr[r] = er; enti[r] = ei;
        float br = acc[8 + j][r], bi = acc[12 + j][r];
        float t0 = er * wTr - ei * wTi + br;
        ei = er * wTi + ei * wTr + bi; er = t0;
      }
      float Gr = er, Gi = ei;
      float sr = __shfl_down(Gr, 16), si = __shfl_down(Gi, 16);
      if (kq <= 2) { Gr += sr * w4r - si * w4i; Gi += sr * w4i + si * w4r; }
      sr = __shfl_down(Gr, 32); si = __shfl_down(Gi, 32);
      if (kq <= 1) { Gr += sr * w8r - si * w8i; Gi += sr * w8i + si * w8r; }
      float Sgr = __shfl_down(Gr, 16), Sgi = __shfl_down(Gi, 16);
      if (kq == 3) { Sgr = 0.f; Sgi = 0.f; }
      float pr = 1.f, pi = 0.f;
      #pragma unroll
      for (int rr = 0; rr < 4; rr++) {
        int r = 3 - rr;  // wT^{3-r} = wT^{rr}
        float scr = pr * Sgr - pi * Sgi + entr[r];
        float sci = pr * Sgi + pi * Sgr + enti[r];
        float opr = mbr * scr - mbi * sci;
        float opi = mbr * sci + mbi * scr;
        *reinterpret_cast<ushort2*>(blb + (size_t)(kq * 4 + r) * 128 + 2 * n) =
            make_ushort2((unsigned short)f2bf(opr), (unsigned short)f2bf(opi));
        float t0 = pr * wTr - pi * wTi; pi = pr * wTi + pi * wTr; pr = t0;
      }
    }
  }
}

// ---------------- apply (MFMA): y = carry + local-Toeplitz + zn*Dp, gelu -> yg_bf (bf16) ----------------
__global__ __launch_bounds__(512) void k_apply(
    const unsigned short* __restrict__ znbf, const unsigned short* __restrict__ Bl,
    const float* __restrict__ Pt, const float* __restrict__ Ktap, const float* __restrict__ Dp,
    unsigned short* __restrict__ ygbf, int i) {
  int h = blockIdx.x;
  int tid = threadIdx.x;
  __shared__ short Blds[64][344];
  __shared__ float k0s[64], k1s[64];
  if (tid < 64) k0s[tid] = Ktap[(0 * 256 + h) * 64 + tid];
  else if (tid < 128) k1s[tid - 64] = Ktap[(1 * 256 + h) * 64 + (tid - 64)];
  __syncthreads();
  {
    int trow = tid >> 6, klane = tid & 63;
    const float* Pth = Pt + (size_t)h * 8192;
    #pragma unroll
    for (int ti = 0; ti < 8; ti++) {
      int t = ti * 8 + trow;
      #pragma unroll
      for (int kc = 0; kc < 5; kc++) {
        int k = kc * 64 + klane;
        float v;
        if (kc < 2)      v = Pth[t * 128 + k];
        else if (kc < 4) v = Pth[(63 - t) * 128 + (k - 128)];
        else {
          int tp = klane;
          v = (t >= tp) ? k0s[t - tp] : k1s[tp - t - 1];
        }
        Blds[t][k] = f2bf(v);
      }
    }
  }
  __syncthreads();

  int wid = tid >> 6, lane = tid & 63;
  int b = blockIdx.y * 8 + wid;
  int c = lane & 15, kq = lane >> 4;
  const unsigned short* pa0 = Bl + ((size_t)(b * 256 + h)) * 2048 + c * 128 + kq * 8;
  const unsigned short* pa1 = pa0 + (size_t)4096 * 2048;
  const unsigned short* pzn = znbf + ((size_t)(b * 256 + h)) * 1024 + c * 64 + kq * 8;

  f32x4 acc[4];
  #pragma unroll
  for (int nt = 0; nt < 4; nt++) acc[nt] = (f32x4){0.f, 0.f, 0.f, 0.f};

  #pragma unroll
  for (int ks = 0; ks < 10; ks++) {
    bf16x8 af;
    if (ks < 4)       af = *reinterpret_cast<const bf16x8*>(pa0 + ks * 32);
    else if (ks < 8)  af = *reinterpret_cast<const bf16x8*>(pa1 + (ks - 4) * 32);
    else              af = *reinterpret_cast<const bf16x8*>(pzn + (ks - 8) * 32);
    #pragma unroll
    for (int nt = 0; nt < 4; nt++) {
      bf16x8 bfv = *reinterpret_cast<const bf16x8*>(&Blds[nt * 16 + c][ks * 32 + kq * 8]);
      acc[nt] = __builtin_amdgcn_mfma_f32_16x16x32_bf16(af, bfv, acc[nt], 0, 0, 0);
    }
  }

  float dp = Dp[i * 256 + h];
  size_t obase = (size_t)(b * 256 + h) * 1024;
  #pragma unroll
  for (int nt = 0; nt < 4; nt++) {
    #pragma unroll
    for (int r = 0; r < 4; r++) {
      int m = kq * 4 + r;
      int t = nt * 16 + c;
      size_t idx = obase + (size_t)m * 64 + t;
      float z = bf2f(znbf[idx]);
      float v = fmaf(z, dp, acc[nt][r]);
      float gel = 0.5f * v * (1.f + erff(v * 0.70710678118f));
      ygbf[idx] = (unsigned short)f2bf(gel);
    }
  }
}

// ---------------- MFMA GEMM over [B,H,L]: C[o,l] = sum_k W[o,k] * act[k,l] ----------------
// EPI 0 (GATE): u = acc + bias1[o] + aux1(x)[b,o,l] + aux2(tt)[b,o] -> gate -> outb bf16
// EPI 1 (RES):  o<256: x += ...; o>=256: skips += ...
// EPI 2 (RELU): out1 = relu(acc + bias1)
// EPI 4 (RES0): o<256: x += ...; o>=256: skips = ... (first block, skips uninitialized)
template <int EPI>
__global__ __launch_bounds__(256) void k_gemm(
    const unsigned short* __restrict__ Wbf, const float* __restrict__ bias1, const float* __restrict__ bias2,
    const unsigned short* __restrict__ act, float* __restrict__ out1, float* __restrict__ out2,
    unsigned short* __restrict__ outb, const float* __restrict__ aux1, const float* __restrict__ aux2) {
  int lt = blockIdx.x, ot = blockIdx.y, b = blockIdx.z;
  int tid = threadIdx.x;
  int l0 = lt * 128, o0 = ot * 64;
  __shared__ unsigned short Alds[128 * 40];  // [l][k] bf16, granule-rotated

  int wid = tid >> 6, lane = tid & 63;
  int wo = wid >> 1, wl = wid & 1;
  int c = lane & 15, kq = lane >> 4;

  int kq4 = tid >> 5;   // 0..7 -> k = kq4*4
  int lq = tid & 31;    // l = lq*4 + j
  const unsigned short* actb = act + (size_t)(b * 256) * 1024 + l0 + lq * 4;

  f32x4 acc[2][4];
  #pragma unroll
  for (int mo = 0; mo < 2; mo++)
    #pragma unroll
    for (int nl = 0; nl < 4; nl++) acc[mo][nl] = (f32x4){0.f, 0.f, 0.f, 0.f};

  ushort4 m0, m1, m2, m3;
  {
    const unsigned short* p = actb + (size_t)(kq4 * 4) * 1024;
    m0 = *reinterpret_cast<const ushort4*>(p);
    m1 = *reinterpret_cast<const ushort4*>(p + 1024);
    m2 = *reinterpret_cast<const ushort4*>(p + 2048);
    m3 = *reinterpret_cast<const ushort4*>(p + 3072);
  }

  for (int kc = 0; kc < 256; kc += 32) {
    {
      int g0 = kq4 >> 1, hh = (kq4 & 1) * 4;
      int rot = (g0 + lq) & 3;
      unsigned short* wp = &Alds[(lq * 4) * 40 + rot * 8 + hh];
      ushort4 w;
      w = make_ushort4(m0.x, m1.x, m2.x, m3.x); *reinterpret_cast<ushort4*>(wp) = w;
      w = make_ushort4(m0.y, m1.y, m2.y, m3.y); *reinterpret_cast<ushort4*>(wp + 40) = w;
      w = make_ushort4(m0.z, m1.z, m2.z, m3.z); *reinterpret_cast<ushort4*>(wp + 80) = w;
      w = make_ushort4(m0.w, m1.w, m2.w, m3.w); *reinterpret_cast<ushort4*>(wp + 120) = w;
    }
    __syncthreads();
    {
      int kcn = (kc + 32) & 255;
      const unsigned short* p = actb + (size_t)(kcn + kq4 * 4) * 1024;
      m0 = *reinterpret_cast<const ushort4*>(p);
      m1 = *reinterpret_cast<const ushort4*>(p + 1024);
      m2 = *reinterpret_cast<const ushort4*>(p + 2048);
      m3 = *reinterpret_cast<const ushort4*>(p + 3072);
    }
    bf16x8 af[2];
    #pragma unroll
    for (int mo = 0; mo < 2; mo++) {
      const unsigned short* wp = Wbf + (size_t)(o0 + wo * 32 + mo * 16 + c) * 256 + kc + kq * 8;
      af[mo] = *reinterpret_cast<const bf16x8*>(wp);
    }
    bf16x8 bfr[4];
    #pragma unroll
    for (int nl = 0; nl < 4; nl++) {
      int l = wl * 64 + nl * 16 + c;
      int rot = (kq + (l >> 2)) & 3;
      bfr[nl] = *reinterpret_cast<const bf16x8*>(&Alds[l * 40 + rot * 8]);
    }
    #pragma unroll
    for (int mo = 0; mo < 2; mo++)
      #pragma unroll
      for (int nl = 0; nl < 4; nl++)
        acc[mo][nl] = __builtin_amdgcn_mfma_f32_16x16x32_bf16(af[mo], bfr[nl], acc[mo][nl], 0, 0, 0);
    __syncthreads();
  }

  #pragma unroll
  for (int mo = 0; mo < 2; mo++) {
    #pragma unroll
    for (int nl = 0; nl < 4; nl++) {
      #pragma unroll
      for (int r = 0; r < 4; r++) {
        float a = acc[mo][nl][r];
        int o = o0 + wo * 32 + mo * 16 + kq * 4 + r;
        int l = l0 + wl * 64 + nl * 16 + c;
        if constexpr (EPI == 0) {
          size_t id = ((size_t)(b * 256 + o)) * 1024 + l;
          float u = a + bias1[o] + aux1[id] + aux2[b * 256 + o];
          float t = __expf(fminf(-u, 80.f));
          float gg = (1.f - t) / (1.f + t * t);
          outb[id] = (unsigned short)f2bf(gg);
        } else if constexpr (EPI == 1 || EPI == 4) {
          if (o < 256) {
            size_t id = ((size_t)(b * 256 + o)) * 1024 + l;
            out1[id] += a + bias1[o];
          } else {
            int o2 = o - 256;
            size_t id = ((size_t)(b * 256 + o2)) * 1024 + l;
            if constexpr (EPI == 4) out2[id] = a + bias2[o2];
            else                    out2[id] += a + bias2[o2];
          }
        } else {
          size_t id = ((size_t)(b * 256 + o)) * 1024 + l;
          out1[id] = fmaxf(a + bias1[o], 0.f);
        }
      }
    }
  }
}

// ---------------- final: out[b,l,d] = h1[b,:,l]@Wo2 + bo2 + input ----------------
__global__ __launch_bounds__(256) void k_out(
    const float* __restrict__ h1, const float* __restrict__ Wo2, const float* __restrict__ bo2,
    const float* __restrict__ inp, float* __restrict__ outp) {
  int lt = blockIdx.x, b = blockIdx.y, tid = threadIdx.x;
  __shared__ float sa[32][132];
  __shared__ float sw2[32][68];
  int l0 = lt * 128;
  float acc[4][8];
  #pragma unroll
  for (int r = 0; r < 4; r++)
    #pragma unroll
    for (int c2 = 0; c2 < 8; c2++) acc[r][c2] = 0.f;
  int df = (tid & 7) * 8;
  int lf = (tid >> 3) * 4;
  for (int kc = 0; kc < 256; kc += 32) {
    for (int rep = 0; rep < 4; rep++) {
      int idx = rep * 256 + tid;
      int kk = idx >> 5;
      int l4 = (idx & 31) * 4;
      float4 v = *reinterpret_cast<const float4*>(h1 + (size_t)(b * 256 + kc + kk) * 1024 + l0 + l4);
      *reinterpret_cast<float4*>(&sa[kk][l4]) = v;
    }
    for (int rep = 0; rep < 8; rep++) {
      int idx = rep * 256 + tid;
      int kk = idx >> 6, d = idx & 63;
      sw2[kk][d] = Wo2[(size_t)(kc + kk) * 64 + d];
    }
    __syncthreads();
    for (int kk = 0; kk < 32; kk++) {
      float4 av = *reinterpret_cast<const float4*>(&sa[kk][lf]);
      float4 w1 = *reinterpret_cast<const float4*>(&sw2[kk][df]);
      float4 w2 = *reinterpret_cast<const float4*>(&sw2[kk][df + 4]);
      float avv[4] = {av.x, av.y, av.z, av.w};
      float wv[8] = {w1.x, w1.y, w1.z, w1.w, w2.x, w2.y, w2.z, w2.w};
      #pragma unroll
      for (int r = 0; r < 4; r++)
        #pragma unroll
        for (int c2 = 0; c2 < 8; c2++) acc[r][c2] = fmaf(avv[r], wv[c2], acc[r][c2]);
    }
    __syncthreads();
  }
  float bv[8];
  #pragma unroll
  for (int c2 = 0; c2 < 8; c2++) bv[c2] = bo2[df + c2];
  #pragma unroll
  for (int r = 0; r < 4; r++) {
    size_t base = (size_t)(b * 1024 + l0 + lf + r) * 64 + df;
    float4 i1 = *reinterpret_cast<const float4*>(inp + base);
    float4 i2 = *reinterpret_cast<const float4*>(inp + base + 4);
    float4 o1 = make_float4(acc[r][0] + bv[0] + i1.x, acc[r][1] + bv[1] + i1.y,
                            acc[r][2] + bv[2] + i1.z, acc[r][3] + bv[3] + i1.w);
    float4 o2 = make_float4(acc[r][4] + bv[4] + i2.x, acc[r][5] + bv[5] + i2.y,
                            acc[r][6] + bv[6] + i2.z, acc[r][7] + bv[7] + i2.w);
    *reinterpret_cast<float4*>(outp + base) = o1;
    *reinterpret_cast<float4*>(outp + base + 4) = o2;
  }
}

extern "C" void kernel_launch(void* const* d_in, const int* in_sizes, int n_in,
                              void* d_out, int out_size, void* d_ws, size_t ws_size,
                              hipStream_t stream) {
  const float* input   = (const float*)d_in[0];
  const float* t       = (const float*)d_in[1];
  const float* W_in    = (const float*)d_in[2];
  const float* b_in    = (const float*)d_in[3];
  const float* Wt1     = (const float*)d_in[4];
  const float* bt1     = (const float*)d_in[5];
  const float* Wt2     = (const float*)d_in[6];
  const float* bt2     = (const float*)d_in[7];
  const float* ln_g    = (const float*)d_in[8];
  const float* ln_b    = (const float*)d_in[9];
  const float* log_dt  = (const float*)d_in[10];
  const float* A_log_re= (const float*)d_in[11];
  const float* A_im    = (const float*)d_in[12];
  const float* C_re    = (const float*)d_in[13];
  const float* C_im    = (const float*)d_in[14];
  const float* Dp      = (const float*)d_in[15];
  const float* s4W     = (const float*)d_in[16];
  const float* s4b     = (const float*)d_in[17];
  const float* tW      = (const float*)d_in[18];
  const float* tb      = (const float*)d_in[19];
  const float* c1W     = (const float*)d_in[20];
  const float* c1b     = (const float*)d_in[21];
  const float* c2W     = (const float*)d_in[22];
  const float* c2b     = (const float*)d_in[23];
  const float* Wo1     = (const float*)d_in[24];
  const float* bo1     = (const float*)d_in[25];
  const float* Wo2     = (const float*)d_in[26];
  const float* bo2     = (const float*)d_in[27];

  float* ws = (float*)d_ws;
  size_t off = 0;
  float* x      = ws + off; off += 4194304;   // fp32 [B,H,L] (after loop: low half = skips_bf)
  float* zn     = ws + off; off += 4194304;   // bf16 zn in low half (after loop: h1 fp32)
  float* ygbuf  = ws + off; off += 4194304;   // [0,2M): yg_bf; [2M,4M): g_bf
  float* skips  = ws + off; off += 4194304;   // fp32
  float* tv     = ws + off; off += 4096;
  float* tt_all = ws + off; off += 24576;
  float* wtab   = ws + off; off += 196608;
  float* wTtab  = ws + off; off += 196608;
  float* dCtab  = ws + off; off += 393216;
  float* Pt     = ws + off; off += 12582912;  // [6][H][64][128] fp32
  float* Ktap   = ws + off; off += 196608;    // [6][2][H][64]
  float* Bl     = ws + off; off += 8388608;   // bf16 [2][B*H][16][128]
  unsigned short* s4Wbf  = (unsigned short*)(ws + off); off += 196608;
  unsigned short* c12Wbf = (unsigned short*)(ws + off); off += 393216;
  unsigned short* Wo1T   = (unsigned short*)(ws + off); off += 32768;

  unsigned short* Blb     = (unsigned short*)Bl;
  unsigned short* znbf    = (unsigned short*)zn;
  unsigned short* ygbf    = (unsigned short*)ygbuf;
  unsigned short* gbf     = (unsigned short*)(ygbuf + 2097152);
  unsigned short* skipsbf = (unsigned short*)x;
  float* h1 = zn;

  k_temb<<<16, 256, 0, stream>>>(t, Wt1, bt1, Wt2, bt2, tv);
  k_tt<<<dim3(6, 16), 256, 0, stream>>>(tv, tW, tb, tt_all);
  k_in<<<dim3(16, 16), 256, 0, stream>>>(input, W_in, b_in, x);
  k_tab<<<384, 256, 0, stream>>>(log_dt, A_log_re, A_im, C_re, C_im, wtab, wTtab, dCtab);
  k_prep<<<4864, 256, 0, stream>>>(s4W, c1W, c2W, Wo1, s4Wbf, c12Wbf, Wo1T);
  k_pcar<<<384, 256, 0, stream>>>(wtab, Pt);
  k_ktap<<<768, 256, 0, stream>>>(dCtab, Pt, Ktap);

  for (int i = 0; i < 6; i++) {
    k_ln<<<dim3(16, 16), 256, 0, stream>>>(x, tt_all, ln_g, ln_b, znbf, i);
    k_bsc<<<dim3(256, 2), 512, 0, stream>>>(znbf, Pt + (size_t)i * 2097152, wtab, wTtab, dCtab, Blb, i);
    k_apply<<<dim3(256, 2), 512, 0, stream>>>(znbf, Blb, Pt + (size_t)i * 2097152,
                                              Ktap + (size_t)i * 32768, Dp, ygbf, i);
    // g_bf = gate(s4W@yg + s4b + x + tt)
    k_gemm<0><<<dim3(8, 4, 16), 256, 0, stream>>>(s4Wbf + (size_t)i * 65536, s4b + i * 256, nullptr,
                                                  ygbf, nullptr, nullptr, gbf, x, tt_all + i * 4096);
    // x += c1W@g + c1b ; skips (+)= c2W@g + c2b  (fused, M=512; first block writes skips)
    if (i == 0)
      k_gemm<4><<<dim3(8, 8, 16), 256, 0, stream>>>(c12Wbf, c1b, c2b, gbf, x, skips,
                                                    nullptr, nullptr, nullptr);
    else
      k_gemm<1><<<dim3(8, 8, 16), 256, 0, stream>>>(c12Wbf + (size_t)i * 131072, c1b + i * 256,
                                                    c2b + i * 256, gbf, x, skips,
                                                    nullptr, nullptr, nullptr);
  }
  k_conv<<<2048, 256, 0, stream>>>(skips, skipsbf);
  // h1 = relu(Wo1^T @ skips + bo1)
  k_gemm<2><<<dim3(8, 4, 16), 256, 0, stream>>>(Wo1T, bo1, nullptr,
                                                skipsbf, h1, nullptr, nullptr, nullptr, nullptr);
  k_out<<<dim3(8, 16), 256, 0, stream>>>(h1, Wo2, bo2, input, (float*)d_out);
}

// Round 7
// 580.159 us; speedup vs baseline: 9.2638x; 1.0305x over previous
//
#include <hip/hip_runtime.h>
#include <math.h>

// Problem sizes
// B=16, L=1024, DIN=64, H=256, N=64, TEMB=128, NB=6; chunk T=64, C=16

typedef __attribute__((ext_vector_type(8))) short bf16x8;
typedef __attribute__((ext_vector_type(4))) float f32x4;

__device__ __forceinline__ short f2bf(float f) {
  unsigned u = __builtin_bit_cast(unsigned, f);
  unsigned r = (u + 0x7FFFu + ((u >> 16) & 1u)) >> 16;
  return (short)r;
}
__device__ __forceinline__ float bf2f(unsigned short v) {
  unsigned u = ((unsigned)v) << 16;
  return __builtin_bit_cast(float, u);
}

// ---------------- t-embedding MLP:  tv[b,h] ----------------
__global__ __launch_bounds__(256) void k_temb(
    const float* __restrict__ t, const float* __restrict__ Wt1, const float* __restrict__ bt1,
    const float* __restrict__ Wt2, const float* __restrict__ bt2, float* __restrict__ tv) {
  int b = blockIdx.x, tid = threadIdx.x;
  __shared__ float emb[128];
  __shared__ float tv1[256];
  if (tid < 128) {
    int j = tid & 63;
    float f = expf(-logf(10000.f) / 63.f * (float)j);
    float a = t[b] * f;
    emb[tid] = (tid < 64) ? sinf(a) : cosf(a);
  }
  __syncthreads();
  float acc = bt1[tid];
  for (int k = 0; k < 128; k++) acc = fmaf(emb[k], Wt1[k * 256 + tid], acc);
  tv1[tid] = acc / (1.f + expf(-acc));
  __syncthreads();
  float acc2 = bt2[tid];
  for (int k = 0; k < 256; k++) acc2 = fmaf(tv1[k], Wt2[k * 256 + tid], acc2);
  tv[b * 256 + tid] = acc2 / (1.f + expf(-acc2));
}

// ---------------- tt_all[i,b,h] = tv[b]@tW[i] + tb[i] ----------------
__global__ __launch_bounds__(256) void k_tt(
    const float* __restrict__ tv, const float* __restrict__ tW, const float* __restrict__ tb,
    float* __restrict__ tt_all) {
  int i = blockIdx.x, b = blockIdx.y, h = threadIdx.x;
  __shared__ float s[256];
  s[h] = tv[b * 256 + h];
  __syncthreads();
  const float* W = tW + i * 256 * 256;
  float acc = tb[i * 256 + h];
  for (int k = 0; k < 256; k++) acc = fmaf(s[k], W[k * 256 + h], acc);
  tt_all[(i * 16 + b) * 256 + h] = acc;
}

// ---------------- input proj: x[b,h,l] = relu(input@W_in + b_in), transposed ----------------
__global__ __launch_bounds__(256) void k_in(
    const float* __restrict__ inp, const float* __restrict__ W, const float* __restrict__ bias,
    float* __restrict__ x) {
  int lt = blockIdx.x, b = blockIdx.y, h = threadIdx.x;
  __shared__ float si[64][68];
  int l0 = lt * 64;
  for (int rep = 0; rep < 16; rep++) {
    int idx = rep * 256 + h;
    int l = idx >> 6, d = idx & 63;
    si[l][d] = inp[(size_t)(b * 1024 + l0 + l) * 64 + d];
  }
  float wc[64];
  #pragma unroll
  for (int d = 0; d < 64; d++) wc[d] = W[d * 256 + h];
  float bh = bias[h];
  __syncthreads();
  float* xp = x + (size_t)(b * 256 + h) * 1024 + l0;
  for (int l4 = 0; l4 < 16; l4++) {
    float4 o;
    float* op = &o.x;
    #pragma unroll
    for (int j = 0; j < 4; j++) {
      int l = l4 * 4 + j;
      float a = bh;
      #pragma unroll
      for (int d4 = 0; d4 < 16; d4++) {
        float4 v = *reinterpret_cast<const float4*>(&si[l][d4 * 4]);
        a = fmaf(v.x, wc[d4 * 4 + 0], a);
        a = fmaf(v.y, wc[d4 * 4 + 1], a);
        a = fmaf(v.z, wc[d4 * 4 + 2], a);
        a = fmaf(v.w, wc[d4 * 4 + 3], a);
      }
      op[j] = fmaxf(a, 0.f);
    }
    *reinterpret_cast<float4*>(xp + l4 * 4) = o;
  }
}

// ---------------- per-mode tables: w, w^64, dC (all blocks) ----------------
__global__ __launch_bounds__(256) void k_tab(
    const float* __restrict__ log_dt, const float* __restrict__ A_log_re, const float* __restrict__ A_im,
    const float* __restrict__ C_re, const float* __restrict__ C_im,
    float* __restrict__ wtab, float* __restrict__ wTtab, float* __restrict__ dCtab) {
  int idx = blockIdx.x * 256 + threadIdx.x;  // over NB*H*N = 98304
  int i = idx / (256 * 64);
  int rem = idx % (256 * 64);
  int h = rem >> 6, n = rem & 63;
  float dt = expf(log_dt[i * 256 + h]);
  float Ar = -expf(A_log_re[idx]);
  float Ai = A_im[idx];
  float ar = dt * Ar, ai = dt * Ai;
  float ea = expf(ar);
  float wr = ea * cosf(ai), wi = ea * sinf(ai);
  float pr = wr, pi = wi;
  #pragma unroll
  for (int s = 0; s < 6; s++) { float nr = pr * pr - pi * pi; float ni = 2.f * pr * pi; pr = nr; pi = ni; }
  float den = Ar * Ar + Ai * Ai;
  float qr = ((wr - 1.f) * Ar + wi * Ai) / den;
  float qi = (wi * Ar - (wr - 1.f) * Ai) / den;
  wtab[idx * 2] = wr; wtab[idx * 2 + 1] = wi;
  wTtab[idx * 2] = pr; wTtab[idx * 2 + 1] = pi;
  #pragma unroll
  for (int s = 0; s < 2; s++) {
    float cr = C_re[((size_t)(i * 2 + s) * 256 + h) * 64 + n];
    float ci = C_im[((size_t)(i * 2 + s) * 256 + h) * 64 + n];
    dCtab[(((size_t)(i * 2 + s) * 256 + h) * 64 + n) * 2]     = cr * qr - ci * qi;
    dCtab[(((size_t)(i * 2 + s) * 256 + h) * 64 + n) * 2 + 1] = cr * qi + ci * qr;
  }
}

// ---------------- weight prep: bf16 conversions ----------------
__global__ __launch_bounds__(256) void k_prep(
    const float* __restrict__ s4W, const float* __restrict__ c1W, const float* __restrict__ c2W,
    const float* __restrict__ Wo1,
    unsigned short* __restrict__ s4Wbf, unsigned short* __restrict__ c12Wbf, unsigned short* __restrict__ Wo1T) {
  int idx = blockIdx.x * 256 + threadIdx.x;  // 4864*256 = 1245184
  if (idx < 393216) {
    s4Wbf[idx] = (unsigned short)f2bf(s4W[idx]);
  } else if (idx < 393216 + 786432) {
    int j = idx - 393216;
    int i = j / 131072, r = j % 131072;
    int o2 = r >> 8, k = r & 255;
    float v = (o2 < 256) ? c1W[(size_t)i * 65536 + o2 * 256 + k]
                         : c2W[(size_t)i * 65536 + (o2 - 256) * 256 + k];
    c12Wbf[j] = (unsigned short)f2bf(v);
  } else {
    int j = idx - 1179648;  // < 65536
    int o = j >> 8, k = j & 255;
    Wo1T[j] = (unsigned short)f2bf(Wo1[k * 256 + o]);
  }
}

// ---------------- skips fp32 -> bf16 ----------------
__global__ __launch_bounds__(256) void k_conv(const float* __restrict__ src, unsigned short* __restrict__ dst) {
  int idx = (blockIdx.x * 256 + threadIdx.x) * 8;
  float4 v0 = *reinterpret_cast<const float4*>(src + idx);
  float4 v1 = *reinterpret_cast<const float4*>(src + idx + 4);
  ushort4 a = make_ushort4((unsigned short)f2bf(v0.x), (unsigned short)f2bf(v0.y),
                           (unsigned short)f2bf(v0.z), (unsigned short)f2bf(v0.w));
  ushort4 b = make_ushort4((unsigned short)f2bf(v1.x), (unsigned short)f2bf(v1.y),
                           (unsigned short)f2bf(v1.z), (unsigned short)f2bf(v1.w));
  *reinterpret_cast<ushort4*>(dst + idx) = a;
  *reinterpret_cast<ushort4*>(dst + idx + 4) = b;
}

// ---------------- Pt_all[i][h][t][2n{+1}] = {Re, -Im}(w^t), all blocks ----------------
__global__ __launch_bounds__(256) void k_pcar(const float* __restrict__ wtab, float* __restrict__ Pt) {
  int idx = blockIdx.x * 256 + threadIdx.x;  // i*16384 + h*64 + n, 98304
  int i = idx >> 14, h = (idx >> 6) & 255, n = idx & 63;
  float wr = wtab[idx * 2], wi = wtab[idx * 2 + 1];
  float pr = 1.f, pi = 0.f;
  float* base = Pt + (size_t)i * 2097152 + (size_t)h * 8192 + 2 * n;
  for (int t = 0; t < 64; t++) {
    *reinterpret_cast<float2*>(base + t * 128) = make_float2(pr, -pi);
    float nr2 = pr * wr - pi * wi, ni2 = pr * wi + pi * wr;
    pr = nr2; pi = ni2;
  }
}

// ---------------- Ktap_all[i][s][h][j] = 2 Re(sum_n dC_s w^j), all blocks ----------------
__global__ __launch_bounds__(256) void k_ktap(
    const float* __restrict__ dCtab, const float* __restrict__ Pt, float* __restrict__ Ktap) {
  int idx = blockIdx.x * 256 + threadIdx.x;  // ((i*2+s)*256+h)*64+j, 196608
  int j = idx & 63;
  int h = (idx >> 6) & 255;
  int i = idx >> 15;
  const float* dc = dCtab + (size_t)(idx >> 6) * 128;
  const float* P = Pt + (size_t)i * 2097152 + (size_t)h * 8192 + j * 128;
  float acc = 0.f;
  for (int q = 0; q < 32; q++) {
    float4 d = *reinterpret_cast<const float4*>(dc + q * 4);
    float4 p = *reinterpret_cast<const float4*>(P + q * 4);
    acc = fmaf(d.x, p.x, fmaf(d.y, p.y, fmaf(d.z, p.z, fmaf(d.w, p.w, acc))));
  }
  Ktap[idx] = 2.f * acc;
}

// ---------------- LayerNorm over H with +tt, x[B,H,L] -> zn bf16 [B,H,L] ----------------
__global__ __launch_bounds__(256) void k_ln(
    const float* __restrict__ x, const float* __restrict__ tt_all,
    const float* __restrict__ g, const float* __restrict__ bta, unsigned short* __restrict__ znbf, int i) {
  int ct = blockIdx.x, b = blockIdx.y, tid = threadIdx.x;
  __shared__ float tile[64][257];
  __shared__ float stt[256];
  __shared__ float red[8][64];
  __shared__ float mu_s[64], rs_s[64];
  stt[tid] = tt_all[(i * 16 + b) * 256 + tid];
  __syncthreads();
  int l0 = ct * 64;
  const float* xb = x + (size_t)(b * 256) * 1024 + l0;
  for (int rep = 0; rep < 16; rep++) {
    int idx = rep * 256 + tid;
    int h = idx >> 4;
    int l4 = (idx & 15) * 4;
    float4 v = *reinterpret_cast<const float4*>(xb + (size_t)h * 1024 + l4);
    float a = stt[h];
    tile[l4][h] = v.x + a; tile[l4 + 1][h] = v.y + a; tile[l4 + 2][h] = v.z + a; tile[l4 + 3][h] = v.w + a;
  }
  __syncthreads();
  int l = tid & 63, part = tid >> 6;
  float s1 = 0.f, s2 = 0.f;
  for (int k = 0; k < 64; k++) {
    float v = tile[l][part * 64 + k];
    s1 += v; s2 = fmaf(v, v, s2);
  }
  red[part][l] = s1; red[4 + part][l] = s2;
  __syncthreads();
  if (tid < 64) {
    float a = red[0][tid] + red[1][tid] + red[2][tid] + red[3][tid];
    float q = red[4][tid] + red[5][tid] + red[6][tid] + red[7][tid];
    float mu = a * (1.f / 256.f);
    float var = q * (1.f / 256.f) - mu * mu;
    mu_s[tid] = mu;
    rs_s[tid] = rsqrtf(var + 1e-5f);
  }
  __syncthreads();
  unsigned short* zb = znbf + (size_t)(b * 256) * 1024 + l0;
  for (int rep = 0; rep < 16; rep++) {
    int idx = rep * 256 + tid;
    int h = idx >> 4;
    int l4 = (idx & 15) * 4;
    float gg = g[i * 256 + h], bb2 = bta[i * 256 + h];
    float o0 = (tile[l4][h]     - mu_s[l4])     * rs_s[l4]     * gg + bb2;
    float o1 = (tile[l4 + 1][h] - mu_s[l4 + 1]) * rs_s[l4 + 1] * gg + bb2;
    float o2 = (tile[l4 + 2][h] - mu_s[l4 + 2]) * rs_s[l4 + 2] * gg + bb2;
    float o3 = (tile[l4 + 3][h] - mu_s[l4 + 3]) * rs_s[l4 + 3] * gg + bb2;
    ushort4 o4 = make_ushort4((unsigned short)f2bf(o0), (unsigned short)f2bf(o1),
                              (unsigned short)f2bf(o2), (unsigned short)f2bf(o3));
    *reinterpret_cast<ushort4*>(zb + (size_t)h * 1024 + l4) = o4;
  }
}

// ---------------- FUSED S4: bloc MFMA + in-wave scan + carry/Toeplitz MFMA + gelu ----------------
// One block per (h, 8 batches); one batch per wave. S' passes through LDS (never global).
// Phases: stage Psb -> build Bp -> bloc MFMA (acc[16]) -> rebuild region as Blds ->
//         register scan -> write S' to Sw (wave-private) -> apply MFMA -> gelu -> ygbf.
__global__ __launch_bounds__(512, 1) void k_s4(
    const unsigned short* __restrict__ znbf, const float* __restrict__ Pt,
    const float* __restrict__ wtab, const float* __restrict__ wTtab, const float* __restrict__ dCtab,
    const float* __restrict__ Ktap, const float* __restrict__ Dp,
    unsigned short* __restrict__ ygbf, int i) {
  int h = blockIdx.x;
  int tid = threadIdx.x;
  __shared__ unsigned short Psb[64][130];        // 16640 B  bf16 {re,-im}(w^t)
  __shared__ unsigned short XR[22016];           // 44032 B: Bp[256][72] then Blds[64][344]
  __shared__ unsigned short Sw[8][2][16][136];   // 69632 B  per-wave S'
  __shared__ float k0s[64], k1s[64];

  if (tid < 64) k0s[tid] = Ktap[h * 64 + tid];
  else if (tid < 128) k1s[tid - 64] = Ktap[16384 + h * 64 + (tid - 64)];

  // stage Psb (bf16)
  {
    const float* src = Pt + (size_t)h * 8192;
    #pragma unroll
    for (int rep = 0; rep < 4; rep++) {
      int idx = rep * 512 + tid;  // 2048 float4
      int t = idx >> 5, k4 = (idx & 31) * 4;
      float4 v = *reinterpret_cast<const float4*>(src + t * 128 + k4);
      ushort2 a = make_ushort2((unsigned short)f2bf(v.x), (unsigned short)f2bf(v.y));
      ushort2 bq = make_ushort2((unsigned short)f2bf(v.z), (unsigned short)f2bf(v.w));
      *reinterpret_cast<ushort2*>(&Psb[t][k4]) = a;
      *reinterpret_cast<ushort2*>(&Psb[t][k4 + 2]) = bq;
    }
  }
  __syncthreads();
  // build Bp[col][t], col = dir*128 + comp*64 + n  (comp-separated)
  {
    int t = tid & 63;
    int colblk = tid >> 6;
    #pragma unroll
    for (int cc = 0; cc < 32; cc++) {
      int col = colblk * 32 + cc;
      int n = col & 63, comp = (col >> 6) & 1, dir = col >> 7;
      int k = 2 * n + comp;
      unsigned short v = dir ? Psb[t][k] : Psb[63 - t][k];
      if (comp) v ^= 0x8000u;  // stored -im -> +im
      XR[col * 72 + t] = v;
    }
  }
  __syncthreads();

  int wid = tid >> 6, lane = tid & 63;
  int b = blockIdx.y * 8 + wid;          // one batch per wave
  int c = lane & 15, kq = lane >> 4;
  const unsigned short* pzn = znbf + ((size_t)(b * 256 + h)) * 1024 + c * 64 + kq * 8;

  bf16x8 af0 = *reinterpret_cast<const bf16x8*>(pzn);
  bf16x8 af1 = *reinterpret_cast<const bf16x8*>(pzn + 32);

  f32x4 acc[16];
  #pragma unroll
  for (int nt = 0; nt < 16; nt++) acc[nt] = (f32x4){0.f, 0.f, 0.f, 0.f};
  #pragma unroll
  for (int nt = 0; nt < 16; nt++) {
    bf16x8 b0 = *reinterpret_cast<const bf16x8*>(&XR[(nt * 16 + c) * 72 + kq * 8]);
    acc[nt] = __builtin_amdgcn_mfma_f32_16x16x32_bf16(af0, b0, acc[nt], 0, 0, 0);
  }
  #pragma unroll
  for (int nt = 0; nt < 16; nt++) {
    bf16x8 b1 = *reinterpret_cast<const bf16x8*>(&XR[(nt * 16 + c) * 72 + 32 + kq * 8]);
    acc[nt] = __builtin_amdgcn_mfma_f32_16x16x32_bf16(af1, b1, acc[nt], 0, 0, 0);
  }
  __syncthreads();  // Bp dead

  // rebuild region as Blds[64][344]: [t][k], k<128: fwd {re,-im}; k<256: bwd reversed; k<320: Toeplitz
  {
    int trow = tid >> 6, klane = tid & 63;
    #pragma unroll
    for (int ti = 0; ti < 8; ti++) {
      int t = ti * 8 + trow;
      #pragma unroll
      for (int kc = 0; kc < 5; kc++) {
        int k = kc * 64 + klane;
        unsigned short v;
        if (kc < 2)      v = Psb[t][k];
        else if (kc < 4) v = Psb[63 - t][k - 128];
        else {
          int tp = klane;
          float f = (t >= tp) ? k0s[t - tp] : k1s[tp - t - 1];
          v = (unsigned short)f2bf(f);
        }
        XR[t * 344 + k] = v;
      }
    }
  }

  // ---- register scan -> S' into Sw (wave-private) ----
  unsigned short* swf = &Sw[wid][0][0][0];
  unsigned short* swb = &Sw[wid][1][0][0];
  const int gib = (i * 256 + h) * 64;
  #pragma unroll
  for (int j = 0; j < 4; j++) {
    int n = j * 16 + c;
    int gi = gib + n;
    float wTr = wTtab[gi * 2], wTi = wTtab[gi * 2 + 1];
    float w2r = wTr * wTr - wTi * wTi, w2i = 2.f * wTr * wTi;
    float w4r = w2r * w2r - w2i * w2i, w4i = 2.f * w2r * w2i;
    float w8r = w4r * w4r - w4i * w4i, w8i = 2.f * w4r * w4i;
    float wr = wtab[gi * 2], wi = wtab[gi * 2 + 1];
    float d0r = dCtab[((size_t)(i * 2 + 0) * 256 + h) * 128 + 2 * n];
    float d0i = dCtab[((size_t)(i * 2 + 0) * 256 + h) * 128 + 2 * n + 1];
    float d1r = dCtab[((size_t)(i * 2 + 1) * 256 + h) * 128 + 2 * n];
    float d1i = dCtab[((size_t)(i * 2 + 1) * 256 + h) * 128 + 2 * n + 1];
    float mfr = 2.f * (d0r * wr - d0i * wi), mfi = 2.f * (d0r * wi + d0i * wr);
    float mbr = 2.f * d1r, mbi = 2.f * d1i;

    // forward
    {
      float er = 0.f, ei = 0.f, entr[4], enti[4];
      #pragma unroll
      for (int r = 0; r < 4; r++) {
        entr[r] = er; enti[r] = ei;
        float br = acc[j][r], bi = acc[j + 4][r];
        float t0 = er * wTr - ei * wTi + br;
        ei = er * wTi + ei * wTr + bi; er = t0;
      }
      float Gr = er, Gi = ei;
      float sr = __shfl_up(Gr, 16), si = __shfl_up(Gi, 16);
      if (kq >= 1) { Gr += sr * w4r - si * w4i; Gi += sr * w4i + si * w4r; }
      sr = __shfl_up(Gr, 32); si = __shfl_up(Gi, 32);
      if (kq >= 2) { Gr += sr * w8r - si * w8i; Gi += sr * w8i + si * w8r; }
      float Sgr = __shfl_up(Gr, 16), Sgi = __shfl_up(Gi, 16);
      if (kq == 0) { Sgr = 0.f; Sgi = 0.f; }
      float pr = 1.f, pi = 0.f;
      #pragma unroll
      for (int r = 0; r < 4; r++) {
        float scr = pr * Sgr - pi * Sgi + entr[r];
        float sci = pr * Sgi + pi * Sgr + enti[r];
        float opr = mfr * scr - mfi * sci;
        float opi = mfr * sci + mfi * scr;
        *reinterpret_cast<ushort2*>(swf + (kq * 4 + r) * 136 + 2 * n) =
            make_ushort2((unsigned short)f2bf(opr), (unsigned short)f2bf(opi));
        float t0 = pr * wTr - pi * wTi; pi = pr * wTi + pi * wTr; pr = t0;
      }
    }
    // backward
    {
      float er = 0.f, ei = 0.f, entr[4], enti[4];
      #pragma unroll
      for (int rr = 0; rr < 4; rr++) {
        int r = 3 - rr;
        entr[r] = er; enti[r] = ei;
        float br = acc[8 + j][r], bi = acc[12 + j][r];
        float t0 = er * wTr - ei * wTi + br;
        ei = er * wTi + ei * wTr + bi; er = t0;
      }
      float Gr = er, Gi = ei;
      float sr = __shfl_down(Gr, 16), si = __shfl_down(Gi, 16);
      if (kq <= 2) { Gr += sr * w4r - si * w4i; Gi += sr * w4i + si * w4r; }
      sr = __shfl_down(Gr, 32); si = __shfl_down(Gi, 32);
      if (kq <= 1) { Gr += sr * w8r - si * w8i; Gi += sr * w8i + si * w8r; }
      float Sgr = __shfl_down(Gr, 16), Sgi = __shfl_down(Gi, 16);
      if (kq == 3) { Sgr = 0.f; Sgi = 0.f; }
      float pr = 1.f, pi = 0.f;
      #pragma unroll
      for (int rr = 0; rr < 4; rr++) {
        int r = 3 - rr;  // wT^{3-r} = wT^{rr}
        float scr = pr * Sgr - pi * Sgi + entr[r];
        float sci = pr * Sgi + pi * Sgr + enti[r];
        float opr = mbr * scr - mbi * sci;
        float opi = mbr * sci + mbi * scr;
        *reinterpret_cast<ushort2*>(swb + (kq * 4 + r) * 136 + 2 * n) =
            make_ushort2((unsigned short)f2bf(opr), (unsigned short)f2bf(opi));
        float t0 = pr * wTr - pi * wTi; pi = pr * wTi + pi * wTr; pr = t0;
      }
    }
  }
  __syncthreads();  // Blds complete; Sw writes drained

  // ---- apply: C[chunk=c][t] over K=320 ----
  f32x4 acc2[4];
  #pragma unroll
  for (int nt = 0; nt < 4; nt++) acc2[nt] = (f32x4){0.f, 0.f, 0.f, 0.f};
  #pragma unroll
  for (int ks = 0; ks < 10; ks++) {
    bf16x8 af;
    if (ks < 4)       af = *reinterpret_cast<const bf16x8*>(swf + c * 136 + ks * 32 + kq * 8);
    else if (ks < 8)  af = *reinterpret_cast<const bf16x8*>(swb + c * 136 + (ks - 4) * 32 + kq * 8);
    else              af = *reinterpret_cast<const bf16x8*>(pzn + (ks - 8) * 32);
    #pragma unroll
    for (int nt = 0; nt < 4; nt++) {
      bf16x8 bfv = *reinterpret_cast<const bf16x8*>(&XR[(nt * 16 + c) * 344 + ks * 32 + kq * 8]);
      acc2[nt] = __builtin_amdgcn_mfma_f32_16x16x32_bf16(af, bfv, acc2[nt], 0, 0, 0);
    }
  }

  float dp = Dp[i * 256 + h];
  size_t obase = (size_t)(b * 256 + h) * 1024;
  #pragma unroll
  for (int nt = 0; nt < 4; nt++) {
    #pragma unroll
    for (int r = 0; r < 4; r++) {
      int m = kq * 4 + r;
      int t = nt * 16 + c;
      size_t idx = obase + (size_t)m * 64 + t;
      float z = bf2f(znbf[idx]);
      float v = fmaf(z, dp, acc2[nt][r]);
      float gel = 0.5f * v * (1.f + erff(v * 0.70710678118f));
      ygbf[idx] = (unsigned short)f2bf(gel);
    }
  }
}

// ---------------- MFMA GEMM over [B,H,L]: C[o,l] = sum_k W[o,k] * act[k,l] ----------------
// EPI 0 (GATE): u = acc + bias1[o] + aux1(x)[b,o,l] + aux2(tt)[b,o] -> gate -> outb bf16
// EPI 1 (RES):  o<256: x += ...; o>=256: skips += ...
// EPI 2 (RELU): out1 = relu(acc + bias1)
// EPI 4 (RES0): o<256: x += ...; o>=256: skips = ... (first block)
template <int EPI>
__global__ __launch_bounds__(256) void k_gemm(
    const unsigned short* __restrict__ Wbf, const float* __restrict__ bias1, const float* __restrict__ bias2,
    const unsigned short* __restrict__ act, float* __restrict__ out1, float* __restrict__ out2,
    unsigned short* __restrict__ outb, const float* __restrict__ aux1, const float* __restrict__ aux2) {
  int lt = blockIdx.x, ot = blockIdx.y, b = blockIdx.z;
  int tid = threadIdx.x;
  int l0 = lt * 128, o0 = ot * 64;
  __shared__ unsigned short Alds[128 * 40];  // [l][k] bf16, granule-rotated

  int wid = tid >> 6, lane = tid & 63;
  int wo = wid >> 1, wl = wid & 1;
  int c = lane & 15, kq = lane >> 4;

  int kq4 = tid >> 5;   // 0..7 -> k = kq4*4
  int lq = tid & 31;    // l = lq*4 + j
  const unsigned short* actb = act + (size_t)(b * 256) * 1024 + l0 + lq * 4;

  f32x4 acc[2][4];
  #pragma unroll
  for (int mo = 0; mo < 2; mo++)
    #pragma unroll
    for (int nl = 0; nl < 4; nl++) acc[mo][nl] = (f32x4){0.f, 0.f, 0.f, 0.f};

  ushort4 m0, m1, m2, m3;
  {
    const unsigned short* p = actb + (size_t)(kq4 * 4) * 1024;
    m0 = *reinterpret_cast<const ushort4*>(p);
    m1 = *reinterpret_cast<const ushort4*>(p + 1024);
    m2 = *reinterpret_cast<const ushort4*>(p + 2048);
    m3 = *reinterpret_cast<const ushort4*>(p + 3072);
  }

  for (int kc = 0; kc < 256; kc += 32) {
    {
      int g0 = kq4 >> 1, hh = (kq4 & 1) * 4;
      int rot = (g0 + lq) & 3;
      unsigned short* wp = &Alds[(lq * 4) * 40 + rot * 8 + hh];
      ushort4 w;
      w = make_ushort4(m0.x, m1.x, m2.x, m3.x); *reinterpret_cast<ushort4*>(wp) = w;
      w = make_ushort4(m0.y, m1.y, m2.y, m3.y); *reinterpret_cast<ushort4*>(wp + 40) = w;
      w = make_ushort4(m0.z, m1.z, m2.z, m3.z); *reinterpret_cast<ushort4*>(wp + 80) = w;
      w = make_ushort4(m0.w, m1.w, m2.w, m3.w); *reinterpret_cast<ushort4*>(wp + 120) = w;
    }
    __syncthreads();
    {
      int kcn = (kc + 32) & 255;
      const unsigned short* p = actb + (size_t)(kcn + kq4 * 4) * 1024;
      m0 = *reinterpret_cast<const ushort4*>(p);
      m1 = *reinterpret_cast<const ushort4*>(p + 1024);
      m2 = *reinterpret_cast<const ushort4*>(p + 2048);
      m3 = *reinterpret_cast<const ushort4*>(p + 3072);
    }
    bf16x8 af[2];
    #pragma unroll
    for (int mo = 0; mo < 2; mo++) {
      const unsigned short* wp = Wbf + (size_t)(o0 + wo * 32 + mo * 16 + c) * 256 + kc + kq * 8;
      af[mo] = *reinterpret_cast<const bf16x8*>(wp);
    }
    bf16x8 bfr[4];
    #pragma unroll
    for (int nl = 0; nl < 4; nl++) {
      int l = wl * 64 + nl * 16 + c;
      int rot = (kq + (l >> 2)) & 3;
      bfr[nl] = *reinterpret_cast<const bf16x8*>(&Alds[l * 40 + rot * 8]);
    }
    #pragma unroll
    for (int mo = 0; mo < 2; mo++)
      #pragma unroll
      for (int nl = 0; nl < 4; nl++)
        acc[mo][nl] = __builtin_amdgcn_mfma_f32_16x16x32_bf16(af[mo], bfr[nl], acc[mo][nl], 0, 0, 0);
    __syncthreads();
  }

  #pragma unroll
  for (int mo = 0; mo < 2; mo++) {
    #pragma unroll
    for (int nl = 0; nl < 4; nl++) {
      #pragma unroll
      for (int r = 0; r < 4; r++) {
        float a = acc[mo][nl][r];
        int o = o0 + wo * 32 + mo * 16 + kq * 4 + r;
        int l = l0 + wl * 64 + nl * 16 + c;
        if constexpr (EPI == 0) {
          size_t id = ((size_t)(b * 256 + o)) * 1024 + l;
          float u = a + bias1[o] + aux1[id] + aux2[b * 256 + o];
          float t = __expf(fminf(-u, 80.f));
          float gg = (1.f - t) / (1.f + t * t);
          outb[id] = (unsigned short)f2bf(gg);
        } else if constexpr (EPI == 1 || EPI == 4) {
          if (o < 256) {
            size_t id = ((size_t)(b * 256 + o)) * 1024 + l;
            out1[id] += a + bias1[o];
          } else {
            int o2 = o - 256;
            size_t id = ((size_t)(b * 256 + o2)) * 1024 + l;
            if constexpr (EPI == 4) out2[id] = a + bias2[o2];
            else                    out2[id] += a + bias2[o2];
          }
        } else {
          size_t id = ((size_t)(b * 256 + o)) * 1024 + l;
          out1[id] = fmaxf(a + bias1[o], 0.f);
        }
      }
    }
  }
}

// ---------------- final: out[b,l,d] = h1[b,:,l]@Wo2 + bo2 + input ----------------
__global__ __launch_bounds__(256) void k_out(
    const float* __restrict__ h1, const float* __restrict__ Wo2, const float* __restrict__ bo2,
    const float* __restrict__ inp, float* __restrict__ outp) {
  int lt = blockIdx.x, b = blockIdx.y, tid = threadIdx.x;
  __shared__ float sa[32][132];
  __shared__ float sw2[32][68];
  int l0 = lt * 128;
  float acc[4][8];
  #pragma unroll
  for (int r = 0; r < 4; r++)
    #pragma unroll
    for (int c2 = 0; c2 < 8; c2++) acc[r][c2] = 0.f;
  int df = (tid & 7) * 8;
  int lf = (tid >> 3) * 4;
  for (int kc = 0; kc < 256; kc += 32) {
    for (int rep = 0; rep < 4; rep++) {
      int idx = rep * 256 + tid;
      int kk = idx >> 5;
      int l4 = (idx & 31) * 4;
      float4 v = *reinterpret_cast<const float4*>(h1 + (size_t)(b * 256 + kc + kk) * 1024 + l0 + l4);
      *reinterpret_cast<float4*>(&sa[kk][l4]) = v;
    }
    for (int rep = 0; rep < 8; rep++) {
      int idx = rep * 256 + tid;
      int kk = idx >> 6, d = idx & 63;
      sw2[kk][d] = Wo2[(size_t)(kc + kk) * 64 + d];
    }
    __syncthreads();
    for (int kk = 0; kk < 32; kk++) {
      float4 av = *reinterpret_cast<const float4*>(&sa[kk][lf]);
      float4 w1 = *reinterpret_cast<const float4*>(&sw2[kk][df]);
      float4 w2 = *reinterpret_cast<const float4*>(&sw2[kk][df + 4]);
      float avv[4] = {av.x, av.y, av.z, av.w};
      float wv[8] = {w1.x, w1.y, w1.z, w1.w, w2.x, w2.y, w2.z, w2.w};
      #pragma unroll
      for (int r = 0; r < 4; r++)
        #pragma unroll
        for (int c2 = 0; c2 < 8; c2++) acc[r][c2] = fmaf(avv[r], wv[c2], acc[r][c2]);
    }
    __syncthreads();
  }
  float bv[8];
  #pragma unroll
  for (int c2 = 0; c2 < 8; c2++) bv[c2] = bo2[df + c2];
  #pragma unroll
  for (int r = 0; r < 4; r++) {
    size_t base = (size_t)(b * 1024 + l0 + lf + r) * 64 + df;
    float4 i1 = *reinterpret_cast<const float4*>(inp + base);
    float4 i2 = *reinterpret_cast<const float4*>(inp + base + 4);
    float4 o1 = make_float4(acc[r][0] + bv[0] + i1.x, acc[r][1] + bv[1] + i1.y,
                            acc[r][2] + bv[2] + i1.z, acc[r][3] + bv[3] + i1.w);
    float4 o2 = make_float4(acc[r][4] + bv[4] + i2.x, acc[r][5] + bv[5] + i2.y,
                            acc[r][6] + bv[6] + i2.z, acc[r][7] + bv[7] + i2.w);
    *reinterpret_cast<float4*>(outp + base) = o1;
    *reinterpret_cast<float4*>(outp + base + 4) = o2;
  }
}

extern "C" void kernel_launch(void* const* d_in, const int* in_sizes, int n_in,
                              void* d_out, int out_size, void* d_ws, size_t ws_size,
                              hipStream_t stream) {
  const float* input   = (const float*)d_in[0];
  const float* t       = (const float*)d_in[1];
  const float* W_in    = (const float*)d_in[2];
  const float* b_in    = (const float*)d_in[3];
  const float* Wt1     = (const float*)d_in[4];
  const float* bt1     = (const float*)d_in[5];
  const float* Wt2     = (const float*)d_in[6];
  const float* bt2     = (const float*)d_in[7];
  const float* ln_g    = (const float*)d_in[8];
  const float* ln_b    = (const float*)d_in[9];
  const float* log_dt  = (const float*)d_in[10];
  const float* A_log_re= (const float*)d_in[11];
  const float* A_im    = (const float*)d_in[12];
  const float* C_re    = (const float*)d_in[13];
  const float* C_im    = (const float*)d_in[14];
  const float* Dp      = (const float*)d_in[15];
  const float* s4W     = (const float*)d_in[16];
  const float* s4b     = (const float*)d_in[17];
  const float* tW      = (const float*)d_in[18];
  const float* tb      = (const float*)d_in[19];
  const float* c1W     = (const float*)d_in[20];
  const float* c1b     = (const float*)d_in[21];
  const float* c2W     = (const float*)d_in[22];
  const float* c2b     = (const float*)d_in[23];
  const float* Wo1     = (const float*)d_in[24];
  const float* bo1     = (const float*)d_in[25];
  const float* Wo2     = (const float*)d_in[26];
  const float* bo2     = (const float*)d_in[27];

  float* ws = (float*)d_ws;
  size_t off = 0;
  float* x      = ws + off; off += 4194304;   // fp32 [B,H,L] (after loop: low half = skips_bf)
  float* zn     = ws + off; off += 4194304;   // bf16 zn in low half (after loop: h1 fp32)
  float* ygbuf  = ws + off; off += 4194304;   // [0,2M): yg_bf; [2M,4M): g_bf
  float* skips  = ws + off; off += 4194304;   // fp32
  float* tv     = ws + off; off += 4096;
  float* tt_all = ws + off; off += 24576;
  float* wtab   = ws + off; off += 196608;
  float* wTtab  = ws + off; off += 196608;
  float* dCtab  = ws + off; off += 393216;
  float* Pt     = ws + off; off += 12582912;  // [6][H][64][128] fp32
  float* Ktap   = ws + off; off += 196608;    // [6][2][H][64]
  unsigned short* s4Wbf  = (unsigned short*)(ws + off); off += 196608;
  unsigned short* c12Wbf = (unsigned short*)(ws + off); off += 393216;
  unsigned short* Wo1T   = (unsigned short*)(ws + off); off += 32768;

  unsigned short* znbf    = (unsigned short*)zn;
  unsigned short* ygbf    = (unsigned short*)ygbuf;
  unsigned short* gbf     = (unsigned short*)(ygbuf + 2097152);
  unsigned short* skipsbf = (unsigned short*)x;
  float* h1 = zn;

  k_temb<<<16, 256, 0, stream>>>(t, Wt1, bt1, Wt2, bt2, tv);
  k_tt<<<dim3(6, 16), 256, 0, stream>>>(tv, tW, tb, tt_all);
  k_in<<<dim3(16, 16), 256, 0, stream>>>(input, W_in, b_in, x);
  k_tab<<<384, 256, 0, stream>>>(log_dt, A_log_re, A_im, C_re, C_im, wtab, wTtab, dCtab);
  k_prep<<<4864, 256, 0, stream>>>(s4W, c1W, c2W, Wo1, s4Wbf, c12Wbf, Wo1T);
  k_pcar<<<384, 256, 0, stream>>>(wtab, Pt);
  k_ktap<<<768, 256, 0, stream>>>(dCtab, Pt, Ktap);

  for (int i = 0; i < 6; i++) {
    k_ln<<<dim3(16, 16), 256, 0, stream>>>(x, tt_all, ln_g, ln_b, znbf, i);
    k_s4<<<dim3(256, 2), 512, 0, stream>>>(znbf, Pt + (size_t)i * 2097152, wtab, wTtab, dCtab,
                                           Ktap + (size_t)i * 32768, Dp, ygbf, i);
    // g_bf = gate(s4W@yg + s4b + x + tt)
    k_gemm<0><<<dim3(8, 4, 16), 256, 0, stream>>>(s4Wbf + (size_t)i * 65536, s4b + i * 256, nullptr,
                                                  ygbf, nullptr, nullptr, gbf, x, tt_all + i * 4096);
    // x += c1W@g + c1b ; skips (+)= c2W@g + c2b  (fused, M=512; first block writes skips)
    if (i == 0)
      k_gemm<4><<<dim3(8, 8, 16), 256, 0, stream>>>(c12Wbf, c1b, c2b, gbf, x, skips,
                                                    nullptr, nullptr, nullptr);
    else
      k_gemm<1><<<dim3(8, 8, 16), 256, 0, stream>>>(c12Wbf + (size_t)i * 131072, c1b + i * 256,
                                                    c2b + i * 256, gbf, x, skips,
                                                    nullptr, nullptr, nullptr);
  }
  k_conv<<<2048, 256, 0, stream>>>(skips, skipsbf);
  // h1 = relu(Wo1^T @ skips + bo1)
  k_gemm<2><<<dim3(8, 4, 16), 256, 0, stream>>>(Wo1T, bo1, nullptr,
                                                skipsbf, h1, nullptr, nullptr, nullptr, nullptr);
  k_out<<<dim3(8, 16), 256, 0, stream>>>(h1, Wo2, bo2, input, (float*)d_out);
}